// Round 9
// baseline (4897.647 us; speedup 1.0000x reference)
//
#include <hip/hip_runtime.h>
#include <hip/hip_bf16.h>
#include <math.h>

#define NN 10000
#define NE 160000
#define DIM 480
#define NSH 9
#define NBASIS 128
#define NHEAD 4
#define HDIM 120
#define NL 6
#define NG 256
#define NS 128
#define FCH 64
#define CUTOFF 5.0f

typedef __attribute__((ext_vector_type(8))) short bf8v;
typedef __attribute__((ext_vector_type(4))) float f4v;

__device__ __forceinline__ float silu_f(float v) { return v / (1.0f + __expf(-v)); }
__device__ __forceinline__ float bf2f(ushort u) { return __uint_as_float(((unsigned)u) << 16); }
__device__ __forceinline__ ushort f2bfu(float f) {
  __hip_bfloat16 h = __float2bfloat16(f);
  return *reinterpret_cast<ushort*>(&h);
}

struct bf16x4 { __hip_bfloat16 v[4]; };

// ---------------- CSR build ----------------
__global__ void k_zero_int(int* p, int n)
{
  int i = blockIdx.x * 256 + threadIdx.x;
  if (i < n) p[i] = 0;
}

__global__ void k_count(const int* __restrict__ edst, int* __restrict__ cnt)
{
  int e = blockIdx.x * 256 + threadIdx.x;
  if (e < NE) atomicAdd(&cnt[edst[e]], 1);
}

__global__ __launch_bounds__(1024)
void k_scan(const int* __restrict__ cnt, int* __restrict__ row_ptr)
{
  __shared__ int part[1024];
  int tid = threadIdx.x;
  const int per = 10;
  int base = tid * per;
  int s = 0;
  for (int i = 0; i < per; i++) { int idx = base + i; if (idx < NN) s += cnt[idx]; }
  part[tid] = s; __syncthreads();
  for (int off = 1; off < 1024; off <<= 1) {
    int v = (tid >= off) ? part[tid - off] : 0;
    __syncthreads();
    part[tid] += v;
    __syncthreads();
  }
  int run = (tid > 0) ? part[tid - 1] : 0;
  for (int i = 0; i < per; i++) {
    int idx = base + i;
    if (idx < NN) { row_ptr[idx] = run; run += cnt[idx]; }
  }
  if (tid == 1023) row_ptr[NN] = part[1023];
}

__global__ void k_fill(const int* __restrict__ edst, const int* __restrict__ row_ptr,
                       int* __restrict__ cursor, int* __restrict__ csr)
{
  int e = blockIdx.x * 256 + threadIdx.x;
  if (e >= NE) return;
  int d = edst[e];
  int p = atomicAdd(&cursor[d], 1);
  csr[row_ptr[d] + p] = e;
}

// ---------------- geometry in permuted (CSR) order; sh as bf16 [NE][16] padded ----
__global__ void k_geom_p(const float* __restrict__ pos, const int* __restrict__ esrc,
                         const int* __restrict__ edst, const int* __restrict__ csr,
                         __hip_bfloat16* __restrict__ shb, float* __restrict__ distp,
                         int* __restrict__ esrcp, int* __restrict__ edstp)
{
  int j = blockIdx.x * 256 + threadIdx.x;
  if (j >= NE) return;
  int e = csr[j];
  int s = esrc[e], d = edst[e];
  esrcp[j] = s;
  edstp[j] = d;
  float vx = pos[s*3+0] - pos[d*3+0];
  float vy = pos[s*3+1] - pos[d*3+1];
  float vz = pos[s*3+2] - pos[d*3+2];
  float r = sqrtf(vx*vx + vy*vy + vz*vz);
  distp[j] = r;
  float inv = 1.0f / (r + 1e-9f);
  float x = vx*inv, y = vy*inv, z = vz*inv;
  const float s3 = 1.7320508075688772f;
  const float s15 = 3.872983346207417f;
  const float s5 = 2.23606797749979f;
  float sv[9];
  sv[0] = 1.0f;
  sv[1] = s3*x; sv[2] = s3*y; sv[3] = s3*z;
  sv[4] = s15*x*y; sv[5] = s15*y*z; sv[6] = 0.5f*s5*(3.0f*z*z - 1.0f);
  sv[7] = s15*x*z; sv[8] = 0.5f*s15*(x*x - y*y);
  __hip_bfloat16* o = shb + (size_t)j * 16;
#pragma unroll
  for (int q = 0; q < 9; q++) o[q] = __float2bfloat16(sv[q]);
#pragma unroll
  for (int q = 9; q < 16; q++) o[q] = __float2bfloat16(0.f);
}

// ---------------- prep: w3T [7][512][64] bf16 ----------------
__global__ void k_prep(const float* __restrict__ deg_w3, const float* __restrict__ rad_w3,
                       __hip_bfloat16* __restrict__ w3T)
{
  int i = blockIdx.x * 256 + threadIdx.x;
  if (i >= 7*512*64) return;
  int l = i / (512*64); int r = i - l*512*64; int col = r >> 6; int k = r & 63;
  float v = 0.f;
  if (col < DIM) {
    const float* src = (l == 0) ? deg_w3 : rad_w3 + (size_t)(l-1)*FCH*DIM;
    v = src[k*DIM + col];
  }
  w3T[i] = __float2bfloat16(v);
}

// ---------------- prep: node-GEMM weights transposed bf16 ----------------
// layout: [Wv(6) Wo(6) f1(6) f2(6)] each [512][480], then h1T,h2T [128][128]
__global__ void k_prepw(const float* __restrict__ Wv, const float* __restrict__ Wo,
                        const float* __restrict__ f1, const float* __restrict__ f2,
                        const float* __restrict__ h1, const float* __restrict__ h2w,
                        __hip_bfloat16* __restrict__ WT)
{
  int i = blockIdx.x * 256 + threadIdx.x;
  const int big = 24*512*480;
  if (i < big) {
    int m = i / (512*480); int r = i - m*(512*480); int col = r / 480; int k = r - col*480;
    int l = m % 6; int t = m / 6;
    const float* src = (t==0 ? Wv : t==1 ? Wo : t==2 ? f1 : f2) + (size_t)l*DIM*DIM;
    float v = (col < DIM) ? src[k*DIM + col] : 0.f;
    WT[i] = __float2bfloat16(v);
  } else if (i < big + 2*128*128) {
    int j = i - big; int m = j / (128*128); int r = j - m*(128*128);
    int col = r >> 7; int k = r & 127;
    const float* src = m ? h2w : h1;
    WT[i] = __float2bfloat16(src[k*128 + col]);
  }
}

// ---------------- radial MLP -> h2 bf16 [E,64] ----------------
__global__ __launch_bounds__(256)
void k_radial(const float* __restrict__ dist, const float* __restrict__ w1,
              const float* __restrict__ w2, __hip_bfloat16* __restrict__ h2out)
{
  __shared__ float rbs[NBASIS][65];
  __shared__ float wsm[NBASIS * FCH];
  __shared__ float ds[64];
  int tid = threadIdx.x;
  int e0 = blockIdx.x * 64;
  if (tid < 64) ds[tid] = dist[e0 + tid];
  for (int i = tid; i < NBASIS * FCH; i += 256) wsm[i] = w1[i];
  __syncthreads();
  const float invw = (float)NBASIS / CUTOFF;
  for (int i = tid; i < NBASIS * 64; i += 256) {
    int k = i >> 6, e = i & 63;
    float c = k * (CUTOFF / 127.0f);
    float tt = (ds[e] - c) * invw;
    rbs[k][e] = __expf(-0.5f * tt * tt);
  }
  __syncthreads();
  int ty = tid >> 4, tx = tid & 15;
  float acc1[4][4] = {};
  for (int k = 0; k < NBASIS; k++) {
    float b[4];
#pragma unroll
    for (int j = 0; j < 4; j++) b[j] = wsm[k*FCH + tx*4 + j];
#pragma unroll
    for (int i = 0; i < 4; i++) {
      float a = rbs[k][ty*4 + i];
#pragma unroll
      for (int j = 0; j < 4; j++) acc1[i][j] = fmaf(a, b[j], acc1[i][j]);
    }
  }
  __syncthreads();
#pragma unroll
  for (int i = 0; i < 4; i++)
#pragma unroll
    for (int j = 0; j < 4; j++)
      rbs[tx*4 + j][ty*4 + i] = silu_f(acc1[i][j]);
  for (int i = tid; i < FCH * FCH; i += 256) wsm[i] = w2[i];
  __syncthreads();
  float acc2[4][4] = {};
  for (int k = 0; k < FCH; k++) {
    float b[4];
#pragma unroll
    for (int j = 0; j < 4; j++) b[j] = wsm[k*FCH + tx*4 + j];
#pragma unroll
    for (int i = 0; i < 4; i++) {
      float a = rbs[k][ty*4 + i];
#pragma unroll
      for (int j = 0; j < 4; j++) acc2[i][j] = fmaf(a, b[j], acc2[i][j]);
    }
  }
#pragma unroll
  for (int i = 0; i < 4; i++) {
    int e = e0 + ty*4 + i;
    bf16x4 p;
#pragma unroll
    for (int j = 0; j < 4; j++) p.v[j] = __float2bfloat16(silu_f(acc2[i][j]));
    *(bf16x4*)(h2out + (size_t)e*FCH + tx*4) = p;
  }
}

// ---------------- per-row LN stats (mu, rstd) ----------------
__global__ __launch_bounds__(256)
void k_stats(const float* __restrict__ in, float* __restrict__ st,
             int n, int cols, int stride)
{
  int row = blockIdx.x * 4 + (threadIdx.x >> 6);
  int lane = threadIdx.x & 63;
  if (row >= n) return;
  const float* r = in + (size_t)row * stride;
  float s = 0.f, ss = 0.f;
  for (int c = lane; c < cols; c += 64) { float v = r[c]; s += v; ss += v*v; }
  for (int off = 32; off > 0; off >>= 1) { s += __shfl_down(s, off); ss += __shfl_down(ss, off); }
  if (lane == 0) {
    float mu = s / cols;
    float var = ss / cols - mu * mu;
    st[row*2]   = mu;
    st[row*2+1] = rsqrtf(fmaxf(var, 0.f) + 1e-5f);
  }
}

// ---------------- MFMA node GEMM: C = (silu?)((LN?)A @ B), optional +=, bf16 out opt ---
// A [M,K] f32 (lda), BT [col][k] bf16 pre-transposed (ldbT=K), tile 128x128, BK=32.
// NOTE: no min-waves in launch_bounds — forcing occupancy caused scratch spills (round 7).
template<int ADD, int SILU, int LNA, int OBF16>
__global__ __launch_bounds__(256)
void k_gemmm(const float* __restrict__ A, const __hip_bfloat16* __restrict__ BT,
             float* __restrict__ C, __hip_bfloat16* __restrict__ Cb,
             const float* __restrict__ st, int M, int K, int Nc, int lda)
{
  __shared__ __align__(16) char smA[8192];   // [128][32] bf16, XOR-swizzled
  __shared__ __align__(16) char smB[8192];
  __shared__ float smu[128], srs[128];
  int tid = threadIdx.x;
  int lane = tid & 63;
  int wv = tid >> 6;
  int l15 = lane & 15, l4 = lane >> 4;
  int row0 = blockIdx.x * 128;
  int col0 = blockIdx.y * 128;
  if (LNA && tid < 128) {
    int gr = row0 + tid;
    float m2 = 0.f, r2 = 1.f;
    if (gr < M) { m2 = st[gr*2]; r2 = st[gr*2+1]; }
    smu[tid] = m2; srs[tid] = r2;
  }
  f4v z4 = {0.f,0.f,0.f,0.f};
  f4v acc[2][8];
#pragma unroll
  for (int rt = 0; rt < 2; rt++)
#pragma unroll
  for (int ct = 0; ct < 8; ct++) acc[rt][ct] = z4;

  int sr = tid >> 1;               // row handled by this thread in staging
  int skq = (tid & 1) * 16;        // k offset (16 elems)
  for (int k0 = 0; k0 < K; k0 += 32) {
    __syncthreads();
    {   // stage A (f32 -> LN -> bf16)
      int grow = row0 + sr;
      float f[16];
      if (grow < M) {
        const float* ap = A + (size_t)grow * lda + k0 + skq;
#pragma unroll
        for (int q = 0; q < 4; q++) {
          float4 v = *(const float4*)(ap + q*4);
          f[q*4+0]=v.x; f[q*4+1]=v.y; f[q*4+2]=v.z; f[q*4+3]=v.w;
        }
      } else {
#pragma unroll
        for (int q = 0; q < 16; q++) f[q] = 0.f;
      }
      if (LNA) {
        float mu = smu[sr], rs = srs[sr];
#pragma unroll
        for (int q = 0; q < 16; q++) f[q] = (f[q] - mu) * rs;
      }
      unsigned u[8];
#pragma unroll
      for (int q = 0; q < 8; q++)
        u[q] = (unsigned)f2bfu(f[2*q]) | ((unsigned)f2bfu(f[2*q+1]) << 16);
      int base = sr*64 + skq*2;
      *(uint4*)(smA + (base ^ ((sr&7)<<4))) = make_uint4(u[0],u[1],u[2],u[3]);
      *(uint4*)(smA + ((base+16) ^ ((sr&7)<<4))) = make_uint4(u[4],u[5],u[6],u[7]);
    }
    {   // stage B from pre-transposed bf16
      const ushort* bp = (const ushort*)BT + (size_t)(col0 + sr) * K + k0 + skq;
      uint4 v0 = *(const uint4*)bp;
      uint4 v1 = *(const uint4*)(bp + 8);
      int base = sr*64 + skq*2;
      *(uint4*)(smB + (base ^ ((sr&7)<<4))) = v0;
      *(uint4*)(smB + ((base+16) ^ ((sr&7)<<4))) = v1;
    }
    __syncthreads();
    int r0 = wv*32 + l15, r1 = r0 + 16;
    bf8v a0 = *(const bf8v*)(smA + ((r0*64 + l4*16) ^ ((r0&7)<<4)));
    bf8v a1 = *(const bf8v*)(smA + ((r1*64 + l4*16) ^ ((r1&7)<<4)));
#pragma unroll
    for (int ct = 0; ct < 8; ct++) {
      int cc = ct*16 + l15;
      bf8v b = *(const bf8v*)(smB + ((cc*64 + l4*16) ^ ((cc&7)<<4)));
      acc[0][ct] = __builtin_amdgcn_mfma_f32_16x16x32_bf16(a0, b, acc[0][ct], 0, 0, 0);
      acc[1][ct] = __builtin_amdgcn_mfma_f32_16x16x32_bf16(a1, b, acc[1][ct], 0, 0, 0);
    }
  }
  // epilogue
#pragma unroll
  for (int rt = 0; rt < 2; rt++)
#pragma unroll
  for (int ct = 0; ct < 8; ct++)
#pragma unroll
  for (int e = 0; e < 4; e++) {
    int row = row0 + wv*32 + rt*16 + l4*4 + e;
    int col = col0 + ct*16 + l15;
    if (row < M && col < Nc) {
      float v = acc[rt][ct][e];
      if (SILU) v = silu_f(v);
      if (OBF16) Cb[(size_t)row * Nc + col] = __float2bfloat16(v);
      else {
        float* p = C + (size_t)row * Nc + col;
        if (ADD) *p += v; else *p = v;
      }
    }
  }
}

// ---------------- MFMA msg kernel ----------------
// MODE 0: logits partials (plain stores). MODE 1: alpha-weighted segment-sum -> agg.
// MODE 2: (1/16)-weighted segment-sum -> x.
// GEMM1 (MFMA): gate = h2 @ w3 (K=64). sw = sh @ wsh via VALU (9 FMA/elem).
// y-tile is staged into LDS (reusing sm_ab) with coalesced loads — round 8's
// 64 scalar 2B gathers/thread were the latency bottleneck.
// GEMM3 (MODE>=1, MFMA): part = S^T @ M.
template<int MODE>
__global__ __launch_bounds__(256)
void k_msgm(const __hip_bfloat16* __restrict__ h2, const __hip_bfloat16* __restrict__ shb,
            const int* __restrict__ esrcp, const int* __restrict__ edstp,
            const __hip_bfloat16* __restrict__ w3T, const float* __restrict__ wsh,
            const float* __restrict__ aa, const __hip_bfloat16* __restrict__ y,
            const float* __restrict__ alpha, float* __restrict__ outbuf,
            float* __restrict__ logitsP)
{
  __shared__ __align__(16) char sm_ab[32768];    // h2s+w3T operands; then y-tile; then MT
  __shared__ float shs[128][10];
  __shared__ float wshs[9][128];
  __shared__ int srcs[128];
  __shared__ int dsts[128];
  __shared__ int segidL[128];
  __shared__ int seg_dstL[32];
  __shared__ __align__(16) float alsL[(MODE==1)?128:1][4];
  __shared__ int cnt0s;

  int bid = blockIdx.x;
  int swzb = (bid & 7) * 625 + (bid >> 3);       // 5000 = 8 XCD chunks x 625
  int e0   = (swzb >> 2) * 128;
  int col0 = (swzb & 3) * 128;
  int tid = threadIdx.x;
  int lane = tid & 63;
  int wv = tid >> 6;
  int l15 = lane & 15, l4 = lane >> 4;
  int wrow0 = wv * 32;

  for (int c = tid; c < 1024; c += 256) {
    int r = c >> 3, s = c & 7;
    uint4 v = *(const uint4*)((const char*)h2 + (size_t)(e0 + r) * 128 + s * 16);
    *(uint4*)(sm_ab + ((r * 128 + s * 16) ^ ((r & 7) << 4))) = v;
  }
  for (int c = tid; c < 1024; c += 256) {
    int r = c >> 3, s = c & 7;
    uint4 v = *(const uint4*)((const char*)w3T + (size_t)(col0 + r) * 128 + s * 16);
    *(uint4*)(sm_ab + 16384 + ((r * 128 + s * 16) ^ ((r & 7) << 4))) = v;
  }
  for (int idx = tid; idx < 128*9; idx += 256) {
    int r = idx / 9, q = idx - r*9;
    shs[r][q] = bf2f(((const ushort*)shb)[(size_t)(e0 + r) * 16 + q]);
  }
  for (int idx = tid; idx < 9*128; idx += 256) {
    int q = idx >> 7, c = idx & 127;
    int col = col0 + c;
    wshs[q][c] = (col < DIM) ? wsh[q*DIM + col] : 0.f;
  }
  if (tid < 128) {
    if (MODE <= 1) srcs[tid] = esrcp[e0 + tid];
    if (MODE >= 1) dsts[tid] = edstp[e0 + tid];
    if (MODE == 1) *(float4*)&alsL[tid][0] = *(const float4*)(alpha + (size_t)(e0 + tid) * 4);
  }
  __syncthreads();

  // ballot-based segment scan over the 128 dst-sorted edges
  int nseg = 0;
  bool flag = false;
  if (MODE >= 1) {
    if (tid < 128) {
      flag = (tid == 0) || (dsts[tid] != dsts[tid - 1]);
      unsigned long long m = __ballot(flag ? 1 : 0);
      if (tid == 0) cnt0s = __popcll(m);
      unsigned long long below = m & (~0ull >> (63 - (tid & 63)));
      segidL[tid] = __popcll(below);
    }
    __syncthreads();
    if (tid < 128) {
      int sg = segidL[tid] - 1 + (tid >= 64 ? cnt0s : 0);
      segidL[tid] = sg;
      if (flag && sg < 32) seg_dstL[sg] = dsts[tid];
    }
    __syncthreads();
    nseg = segidL[127] + 1;
  }

  f4v z4 = {0.f, 0.f, 0.f, 0.f};
  f4v g[2][8];
#pragma unroll
  for (int rt = 0; rt < 2; rt++)
#pragma unroll
  for (int ct = 0; ct < 8; ct++) g[rt][ct] = z4;

  // GEMM1: gate = h2 @ w3
#pragma unroll
  for (int ks = 0; ks < 2; ks++) {
    int k0b = (ks * 32 + l4 * 8) * 2;
    int r0 = wrow0 + l15;
    int r1 = r0 + 16;
    bf8v a0 = *(const bf8v*)(sm_ab + ((r0 * 128 + k0b) ^ ((r0 & 7) << 4)));
    bf8v a1 = *(const bf8v*)(sm_ab + ((r1 * 128 + k0b) ^ ((r1 & 7) << 4)));
#pragma unroll
    for (int ct = 0; ct < 8; ct++) {
      int cc = ct * 16 + l15;
      bf8v b = *(const bf8v*)(sm_ab + 16384 + ((cc * 128 + k0b) ^ ((cc & 7) << 4)));
      g[0][ct] = __builtin_amdgcn_mfma_f32_16x16x32_bf16(a0, b, g[0][ct], 0, 0, 0);
      g[1][ct] = __builtin_amdgcn_mfma_f32_16x16x32_bf16(a1, b, g[1][ct], 0, 0, 0);
    }
  }

  // stage y-tile into LDS (coalesced), reusing sm_ab (operands dead after GEMM1)
  if (MODE <= 1) {
    __syncthreads();
    for (int c = tid; c < 2048; c += 256) {
      int el = c >> 4, q = c & 15;
      int col = col0 + q * 8;
      uint4 v = make_uint4(0u,0u,0u,0u);
      if (col < DIM)
        v = *(const uint4*)((const ushort*)y + (size_t)srcs[el] * DIM + col);
      *(uint4*)(sm_ab + ((el * 256 + q * 16) ^ ((el & 7) << 4))) = v;
    }
    __syncthreads();
  }

  // m = y * (sh@wsh) * gate  (sw via VALU; y from LDS), + alpha / scale
#pragma unroll
  for (int rt = 0; rt < 2; rt++)
#pragma unroll
  for (int e = 0; e < 4; e++) {
    int rl = wrow0 + rt * 16 + l4 * 4 + e;
    float4 al = make_float4(0.f, 0.f, 0.f, 0.f);
    if (MODE == 1) al = *(const float4*)&alsL[rl][0];
    float sh9[9];
#pragma unroll
    for (int q = 0; q < 9; q++) sh9[q] = shs[rl][q];
#pragma unroll
    for (int ct = 0; ct < 8; ct++) {
      int colL = ct * 16 + l15;
      int col = col0 + colL;
      float swv = 0.f;
#pragma unroll
      for (int q = 0; q < 9; q++) swv = fmaf(sh9[q], wshs[q][colL], swv);
      float yv;
      if (MODE == 2) yv = 1.f;
      else yv = (col < DIM)
          ? bf2f(*(const ushort*)(sm_ab + ((rl * 256 + colL * 2) ^ ((rl & 7) << 4))))
          : 0.f;
      float mv = yv * swv * g[rt][ct][e];
      if (MODE == 1) {
        float av = (col < 120) ? al.x : (col < 240) ? al.y : (col < 360) ? al.z : al.w;
        mv *= av;
      }
      if (MODE == 2) mv *= (1.0f / 16.0f);
      g[rt][ct][e] = mv;
    }
  }

  if (MODE == 0) {
    int hA = col0 / 120;
    float aav[8];
#pragma unroll
    for (int ct = 0; ct < 8; ct++) {
      int col = col0 + ct * 16 + l15;
      aav[ct] = (col < DIM) ? aa[col] : 0.f;
    }
#pragma unroll
    for (int rt = 0; rt < 2; rt++)
#pragma unroll
    for (int e = 0; e < 4; e++) {
      float sA = 0.f, sB = 0.f;
#pragma unroll
      for (int ct = 0; ct < 8; ct++) {
        int col = col0 + ct * 16 + l15;
        float mv = g[rt][ct][e];
        float lv = (mv > 0.f) ? mv : 0.2f * mv;
        float c = lv * aav[ct];
        if (col / 120 == hA) sA += c; else sB += c;
      }
#pragma unroll
      for (int off = 1; off < 16; off <<= 1) {
        sA += __shfl_xor(sA, off, 16);
        sB += __shfl_xor(sB, off, 16);
      }
      if (l15 == 0) {
        int row = e0 + wrow0 + rt * 16 + l4 * 4 + e;
        logitsP[((size_t)row * NHEAD + hA) * 2] = sA;
        if (hA < 3) logitsP[((size_t)row * NHEAD + hA + 1) * 2 + 1] = sB;
      }
    }
    return;
  }

  // overflow fallback (rare): direct atomics
  if (nseg > 32) {
#pragma unroll
    for (int rt = 0; rt < 2; rt++)
#pragma unroll
    for (int e = 0; e < 4; e++) {
      int rl = wrow0 + rt * 16 + l4 * 4 + e;
      int dd = dsts[rl];
#pragma unroll
      for (int ct = 0; ct < 8; ct++) {
        int col = col0 + ct * 16 + l15;
        if (col < DIM) atomicAdd(&outbuf[(size_t)dd * DIM + col], g[rt][ct][e]);
      }
    }
    return;
  }

  // write M^T [col][edge] bf16 into sm_ab (overwrites y-tile)
  __syncthreads();
#pragma unroll
  for (int rt = 0; rt < 2; rt++)
#pragma unroll
  for (int ct = 0; ct < 8; ct++) {
    int cc = ct * 16 + l15;
    int ebase = wrow0 + rt * 16 + l4 * 4;
    ushort4 pk;
    pk.x = f2bfu(g[rt][ct][0]); pk.y = f2bfu(g[rt][ct][1]);
    pk.z = f2bfu(g[rt][ct][2]); pk.w = f2bfu(g[rt][ct][3]);
    *(ushort4*)(sm_ab + ((cc * 256 + ebase * 2) ^ ((cc & 7) << 4))) = pk;
  }
  __syncthreads();

  // GEMM3: part[seg][col] = S^T @ M ; wave wv owns cols [wv*32, wv*32+32)
  f4v p[2][2];
  p[0][0] = z4; p[0][1] = z4; p[1][0] = z4; p[1][1] = z4;
#pragma unroll
  for (int ks = 0; ks < 4; ks++) {
    int k0 = ks * 32 + l4 * 8;
    bf8v a0, a1;
#pragma unroll
    for (int e2 = 0; e2 < 8; e2++) {
      int sg = segidL[k0 + e2];
      a0[e2] = (sg == l15)      ? (short)0x3F80 : (short)0;
      a1[e2] = (sg == l15 + 16) ? (short)0x3F80 : (short)0;
    }
#pragma unroll
    for (int c2 = 0; c2 < 2; c2++) {
      int cc = (wv * 2 + c2) * 16 + l15;
      bf8v bm = *(const bf8v*)(sm_ab + ((cc * 256 + k0 * 2) ^ ((cc & 7) << 4)));
      p[0][c2] = __builtin_amdgcn_mfma_f32_16x16x32_bf16(a0, bm, p[0][c2], 0, 0, 0);
      p[1][c2] = __builtin_amdgcn_mfma_f32_16x16x32_bf16(a1, bm, p[1][c2], 0, 0, 0);
    }
  }
#pragma unroll
  for (int rt = 0; rt < 2; rt++)
#pragma unroll
  for (int c2 = 0; c2 < 2; c2++)
#pragma unroll
  for (int e = 0; e < 4; e++) {
    int seg = rt * 16 + l4 * 4 + e;
    int col = col0 + (wv * 2 + c2) * 16 + l15;
    if (seg < nseg && col < DIM) {
      float v = p[rt][c2][e];
      float* ptr = outbuf + (size_t)seg_dstL[seg] * DIM + col;
      if (seg == 0 || seg == nseg - 1) atomicAdd(ptr, v);
      else if (MODE == 1) *ptr = v;
      else *ptr += v;
    }
  }
}

// ---------------- segment softmax (reads 2-slot logit partials) ----------------
__global__ void k_alpha(const int* __restrict__ row_ptr, const float* __restrict__ logitsP,
                        float* __restrict__ alpha)
{
  int i = blockIdx.x * 256 + threadIdx.x;
  if (i >= NN * NHEAD) return;
  int d = i >> 2, h = i & 3;
  int beg = row_ptr[d], end = row_ptr[d+1];
  if (beg == end) return;
  float m = -1e30f;
  for (int j = beg; j < end; j++) {
    float L = logitsP[((size_t)j*NHEAD + h)*2] + logitsP[((size_t)j*NHEAD + h)*2 + 1];
    m = fmaxf(m, L);
  }
  float s = 0.f;
  for (int j = beg; j < end; j++) {
    float L = logitsP[((size_t)j*NHEAD + h)*2] + logitsP[((size_t)j*NHEAD + h)*2 + 1];
    float ex = __expf(L - m);
    alpha[(size_t)j*NHEAD + h] = ex;
    s += ex;
  }
  float inv = 1.f / (s + 1e-9f);
  for (int j = beg; j < end; j++) alpha[(size_t)j*NHEAD + h] *= inv;
}

// ---------------- x init: atom embedding gather ----------------
__global__ void k_init_x(const int* __restrict__ z, const float* __restrict__ emb,
                         float* __restrict__ x)
{
  int i = blockIdx.x * 256 + threadIdx.x;
  if (i >= NN * DIM) return;
  int n = i / DIM, c = i - n * DIM;
  x[i] = emb[(size_t)z[n]*DIM + c];
}

// ---------------- final scatter over molecules ----------------
__global__ void k_scatter(const float* __restrict__ h, const int* __restrict__ batch,
                          float* __restrict__ out)
{
  int i = blockIdx.x * 256 + threadIdx.x;
  if (i >= NN * NS) return;
  int n = i >> 7;
  atomicAdd(&out[(size_t)batch[n]*NS + (i & 127)], h[i] * 0.23570226039551584f);
}

extern "C" void kernel_launch(void* const* d_in, const int* in_sizes, int n_in,
                              void* d_out, int out_size, void* d_ws, size_t ws_size,
                              hipStream_t stream)
{
  const int*   z        = (const int*)  d_in[0];
  const float* pos      = (const float*)d_in[1];
  const int*   batch    = (const int*)  d_in[2];
  const int*   esrc     = (const int*)  d_in[3];
  const int*   edst     = (const int*)  d_in[4];
  const float* atom_emb = (const float*)d_in[5];
  const float* W_deg_sh = (const float*)d_in[6];
  const float* deg_w1   = (const float*)d_in[7];
  const float* deg_w2   = (const float*)d_in[8];
  const float* deg_w3   = (const float*)d_in[9];
  const float* Wv       = (const float*)d_in[10];
  const float* Wsh      = (const float*)d_in[11];
  const float* rad_w1   = (const float*)d_in[12];
  const float* rad_w2   = (const float*)d_in[13];
  const float* rad_w3   = (const float*)d_in[14];
  const float* attn_a   = (const float*)d_in[15];
  const float* Wo       = (const float*)d_in[16];
  const float* ffn_w1   = (const float*)d_in[17];
  const float* ffn_w2   = (const float*)d_in[18];
  const float* head_w1  = (const float*)d_in[19];
  const float* head_w2  = (const float*)d_in[20];
  float* out = (float*)d_out;

  // workspace (~102 MB)
  float* x      = (float*)d_ws;                        // [NN][480]
  float* statsb = x      + (size_t)NN * DIM;           // [NN][2]
  float* agg    = statsb + (size_t)NN * 2;             // [NN][480]
  float* tmp    = agg    + (size_t)NN * DIM;           // [NN][128]
  float* distp  = tmp    + (size_t)NN * NS;            // [NE]
  float* logitsP= distp  + (size_t)NE;                 // [NE][4][2]
  float* alphab = logitsP+ (size_t)NE * NHEAD * 2;     // [NE][4]
  __hip_bfloat16* yb    = (__hip_bfloat16*)(alphab + (size_t)NE * NHEAD);  // [NN][480]
  __hip_bfloat16* h2b   = yb + (size_t)NN * DIM;       // [NE][64]
  __hip_bfloat16* shb16 = h2b + (size_t)NE * FCH;      // [NE][16]
  __hip_bfloat16* w3Tb  = shb16 + (size_t)NE * 16;     // [7][512][64]
  __hip_bfloat16* bigWT = w3Tb + (size_t)7 * 512 * 64; // [24][512][480] + [2][128][128]
  int* cnt      = (int*)(bigWT + (size_t)24*512*480 + 2*128*128);
  int* row_ptr  = cnt + NN;
  int* csr      = row_ptr + NN + 1;
  int* cursor   = csr + NE;
  int* esrcp    = cursor + NN;
  int* edstp    = esrcp + NE;

  dim3 b256(256);
  // CSR build (dst-sorted edge permutation)
  k_zero_int<<<(NN+255)/256, b256, 0, stream>>>(cnt, NN);
  k_count<<<(NE+255)/256, b256, 0, stream>>>(edst, cnt);
  k_scan<<<1, 1024, 0, stream>>>(cnt, row_ptr);
  k_zero_int<<<(NN+255)/256, b256, 0, stream>>>(cursor, NN);
  k_fill<<<(NE+255)/256, b256, 0, stream>>>(edst, row_ptr, cursor, csr);
  k_geom_p<<<(NE+255)/256, b256, 0, stream>>>(pos, esrc, edst, csr, shb16, distp, esrcp, edstp);
  k_prep<<<(7*512*64 + 255)/256, b256, 0, stream>>>(deg_w3, rad_w3, w3Tb);
  k_prepw<<<(24*512*480 + 2*128*128 + 255)/256, b256, 0, stream>>>(Wv, Wo, ffn_w1, ffn_w2,
      head_w1, head_w2, bigWT);
  hipMemsetAsync(logitsP, 0, (size_t)NE * NHEAD * 2 * sizeof(float), stream);

  // degree embedding: x = emb[z] + (1/16) * segsum(sw * gate)
  k_radial<<<NE/64, b256, 0, stream>>>(distp, deg_w1, deg_w2, h2b);
  k_init_x<<<(NN*DIM+255)/256, b256, 0, stream>>>(z, atom_emb, x);
  k_msgm<2><<<5000, b256, 0, stream>>>(h2b, shb16, esrcp, edstp, w3Tb, W_deg_sh,
      nullptr, nullptr, nullptr, x, nullptr);

  dim3 gemm_grid(79, 4);
  dim3 head_grid(79, 1);
  for (int l = 0; l < NL; l++) {
    const float* w1_l  = rad_w1 + (size_t)l*NBASIS*FCH;
    const float* w2_l  = rad_w2 + (size_t)l*FCH*FCH;
    const float* wsh_l = Wsh + (size_t)l*NSH*DIM;
    const float* aa_l  = attn_a + (size_t)l*NHEAD*HDIM;
    const __hip_bfloat16* w3T_l = w3Tb + (size_t)(l+1)*512*64;
    const __hip_bfloat16* WvT_l = bigWT + (size_t)(0+l)*512*480;
    const __hip_bfloat16* WoT_l = bigWT + (size_t)(6+l)*512*480;
    const __hip_bfloat16* F1T_l = bigWT + (size_t)(12+l)*512*480;
    const __hip_bfloat16* F2T_l = bigWT + (size_t)(18+l)*512*480;

    k_stats<<<(NN+3)/4, b256, 0, stream>>>(x, statsb, NN, DIM, DIM);
    k_gemmm<0,0,1,1><<<gemm_grid, b256, 0, stream>>>(x, WvT_l, nullptr, yb, statsb,
        NN, DIM, DIM, DIM);                             // yb = LN(x) @ Wv (bf16)
    k_radial<<<NE/64, b256, 0, stream>>>(distp, w1_l, w2_l, h2b);
    k_msgm<0><<<5000, b256, 0, stream>>>(h2b, shb16, esrcp, edstp, w3T_l, wsh_l,
        aa_l, yb, nullptr, nullptr, logitsP);
    k_alpha<<<(NN*NHEAD+255)/256, b256, 0, stream>>>(row_ptr, logitsP, alphab);
    hipMemsetAsync(agg, 0, (size_t)NN * DIM * sizeof(float), stream);
    k_msgm<1><<<5000, b256, 0, stream>>>(h2b, shb16, esrcp, edstp, w3T_l, wsh_l,
        nullptr, yb, alphab, agg, nullptr);
    k_gemmm<1,0,0,0><<<gemm_grid, b256, 0, stream>>>(agg, WoT_l, x, nullptr, nullptr,
        NN, DIM, DIM, DIM);                             // x += agg @ Wo
    k_stats<<<(NN+3)/4, b256, 0, stream>>>(x, statsb, NN, DIM, DIM);
    k_gemmm<0,1,1,0><<<gemm_grid, b256, 0, stream>>>(x, F1T_l, agg, nullptr, statsb,
        NN, DIM, DIM, DIM);                             // agg = silu(LN(x) @ W1)
    k_gemmm<1,0,0,0><<<gemm_grid, b256, 0, stream>>>(agg, F2T_l, x, nullptr, nullptr,
        NN, DIM, DIM, DIM);                             // x += agg @ W2
  }

  // output head
  const __hip_bfloat16* H1T = bigWT + (size_t)24*512*480;
  const __hip_bfloat16* H2T = H1T + 128*128;
  k_stats<<<(NN+3)/4, b256, 0, stream>>>(x, statsb, NN, NS, DIM);
  k_gemmm<0,1,1,0><<<head_grid, b256, 0, stream>>>(x, H1T, agg, nullptr, statsb,
      NN, NS, NS, DIM);
  k_gemmm<0,0,0,0><<<head_grid, b256, 0, stream>>>(agg, H2T, tmp, nullptr, nullptr,
      NN, NS, NS, NS);
  hipMemsetAsync(d_out, 0, (size_t)NG * NS * sizeof(float), stream);
  k_scatter<<<(NN*NS+255)/256, b256, 0, stream>>>(tmp, batch, out);
}

// Round 10
// 4485.583 us; speedup vs baseline: 1.0919x; 1.0919x over previous
//
#include <hip/hip_runtime.h>
#include <hip/hip_bf16.h>
#include <math.h>

#define NN 10000
#define NE 160000
#define DIM 480
#define NSH 9
#define NBASIS 128
#define NHEAD 4
#define HDIM 120
#define NL 6
#define NG 256
#define NS 128
#define FCH 64
#define CUTOFF 5.0f

typedef __attribute__((ext_vector_type(8))) short bf8v;
typedef __attribute__((ext_vector_type(4))) float f4v;

__device__ __forceinline__ float silu_f(float v) { return v / (1.0f + __expf(-v)); }
__device__ __forceinline__ float bf2f(ushort u) { return __uint_as_float(((unsigned)u) << 16); }
__device__ __forceinline__ ushort f2bfu(float f) {
  __hip_bfloat16 h = __float2bfloat16(f);
  return *reinterpret_cast<ushort*>(&h);
}

struct bf16x4 { __hip_bfloat16 v[4]; };

// ---------------- CSR build ----------------
__global__ void k_zero_int(int* p, int n)
{
  int i = blockIdx.x * 256 + threadIdx.x;
  if (i < n) p[i] = 0;
}

__global__ void k_count(const int* __restrict__ edst, int* __restrict__ cnt)
{
  int e = blockIdx.x * 256 + threadIdx.x;
  if (e < NE) atomicAdd(&cnt[edst[e]], 1);
}

__global__ __launch_bounds__(1024)
void k_scan(const int* __restrict__ cnt, int* __restrict__ row_ptr)
{
  __shared__ int part[1024];
  int tid = threadIdx.x;
  const int per = 10;
  int base = tid * per;
  int s = 0;
  for (int i = 0; i < per; i++) { int idx = base + i; if (idx < NN) s += cnt[idx]; }
  part[tid] = s; __syncthreads();
  for (int off = 1; off < 1024; off <<= 1) {
    int v = (tid >= off) ? part[tid - off] : 0;
    __syncthreads();
    part[tid] += v;
    __syncthreads();
  }
  int run = (tid > 0) ? part[tid - 1] : 0;
  for (int i = 0; i < per; i++) {
    int idx = base + i;
    if (idx < NN) { row_ptr[idx] = run; run += cnt[idx]; }
  }
  if (tid == 1023) row_ptr[NN] = part[1023];
}

__global__ void k_fill(const int* __restrict__ edst, const int* __restrict__ row_ptr,
                       int* __restrict__ cursor, int* __restrict__ csr)
{
  int e = blockIdx.x * 256 + threadIdx.x;
  if (e >= NE) return;
  int d = edst[e];
  int p = atomicAdd(&cursor[d], 1);
  csr[row_ptr[d] + p] = e;
}

// ---------------- geometry in permuted (CSR) order; sh as bf16 [NE][16] padded ----
__global__ void k_geom_p(const float* __restrict__ pos, const int* __restrict__ esrc,
                         const int* __restrict__ edst, const int* __restrict__ csr,
                         __hip_bfloat16* __restrict__ shb, float* __restrict__ distp,
                         int* __restrict__ esrcp, int* __restrict__ edstp)
{
  int j = blockIdx.x * 256 + threadIdx.x;
  if (j >= NE) return;
  int e = csr[j];
  int s = esrc[e], d = edst[e];
  esrcp[j] = s;
  edstp[j] = d;
  float vx = pos[s*3+0] - pos[d*3+0];
  float vy = pos[s*3+1] - pos[d*3+1];
  float vz = pos[s*3+2] - pos[d*3+2];
  float r = sqrtf(vx*vx + vy*vy + vz*vz);
  distp[j] = r;
  float inv = 1.0f / (r + 1e-9f);
  float x = vx*inv, y = vy*inv, z = vz*inv;
  const float s3 = 1.7320508075688772f;
  const float s15 = 3.872983346207417f;
  const float s5 = 2.23606797749979f;
  float sv[9];
  sv[0] = 1.0f;
  sv[1] = s3*x; sv[2] = s3*y; sv[3] = s3*z;
  sv[4] = s15*x*y; sv[5] = s15*y*z; sv[6] = 0.5f*s5*(3.0f*z*z - 1.0f);
  sv[7] = s15*x*z; sv[8] = 0.5f*s15*(x*x - y*y);
  __hip_bfloat16* o = shb + (size_t)j * 16;
#pragma unroll
  for (int q = 0; q < 9; q++) o[q] = __float2bfloat16(sv[q]);
#pragma unroll
  for (int q = 9; q < 16; q++) o[q] = __float2bfloat16(0.f);
}

// ---------------- prep: w3T [7][512][64] bf16 ----------------
__global__ void k_prep(const float* __restrict__ deg_w3, const float* __restrict__ rad_w3,
                       __hip_bfloat16* __restrict__ w3T)
{
  int i = blockIdx.x * 256 + threadIdx.x;
  if (i >= 7*512*64) return;
  int l = i / (512*64); int r = i - l*512*64; int col = r >> 6; int k = r & 63;
  float v = 0.f;
  if (col < DIM) {
    const float* src = (l == 0) ? deg_w3 : rad_w3 + (size_t)(l-1)*FCH*DIM;
    v = src[k*DIM + col];
  }
  w3T[i] = __float2bfloat16(v);
}

// ---------------- prep: node-GEMM weights transposed bf16 ----------------
// layout: [Wv(6) Wo(6) f1(6) f2(6)] each [512][480], then h1T,h2T [128][128]
__global__ void k_prepw(const float* __restrict__ Wv, const float* __restrict__ Wo,
                        const float* __restrict__ f1, const float* __restrict__ f2,
                        const float* __restrict__ h1, const float* __restrict__ h2w,
                        __hip_bfloat16* __restrict__ WT)
{
  int i = blockIdx.x * 256 + threadIdx.x;
  const int big = 24*512*480;
  if (i < big) {
    int m = i / (512*480); int r = i - m*(512*480); int col = r / 480; int k = r - col*480;
    int l = m % 6; int t = m / 6;
    const float* src = (t==0 ? Wv : t==1 ? Wo : t==2 ? f1 : f2) + (size_t)l*DIM*DIM;
    float v = (col < DIM) ? src[k*DIM + col] : 0.f;
    WT[i] = __float2bfloat16(v);
  } else if (i < big + 2*128*128) {
    int j = i - big; int m = j / (128*128); int r = j - m*(128*128);
    int col = r >> 7; int k = r & 127;
    const float* src = m ? h2w : h1;
    WT[i] = __float2bfloat16(src[k*128 + col]);
  }
}

// ---------------- radial MLP -> h2 bf16 [E,64] ----------------
__global__ __launch_bounds__(256)
void k_radial(const float* __restrict__ dist, const float* __restrict__ w1,
              const float* __restrict__ w2, __hip_bfloat16* __restrict__ h2out)
{
  __shared__ float rbs[NBASIS][65];
  __shared__ float wsm[NBASIS * FCH];
  __shared__ float ds[64];
  int tid = threadIdx.x;
  int e0 = blockIdx.x * 64;
  if (tid < 64) ds[tid] = dist[e0 + tid];
  for (int i = tid; i < NBASIS * FCH; i += 256) wsm[i] = w1[i];
  __syncthreads();
  const float invw = (float)NBASIS / CUTOFF;
  for (int i = tid; i < NBASIS * 64; i += 256) {
    int k = i >> 6, e = i & 63;
    float c = k * (CUTOFF / 127.0f);
    float tt = (ds[e] - c) * invw;
    rbs[k][e] = __expf(-0.5f * tt * tt);
  }
  __syncthreads();
  int ty = tid >> 4, tx = tid & 15;
  float acc1[4][4] = {};
  for (int k = 0; k < NBASIS; k++) {
    float b[4];
#pragma unroll
    for (int j = 0; j < 4; j++) b[j] = wsm[k*FCH + tx*4 + j];
#pragma unroll
    for (int i = 0; i < 4; i++) {
      float a = rbs[k][ty*4 + i];
#pragma unroll
      for (int j = 0; j < 4; j++) acc1[i][j] = fmaf(a, b[j], acc1[i][j]);
    }
  }
  __syncthreads();
#pragma unroll
  for (int i = 0; i < 4; i++)
#pragma unroll
    for (int j = 0; j < 4; j++)
      rbs[tx*4 + j][ty*4 + i] = silu_f(acc1[i][j]);
  for (int i = tid; i < FCH * FCH; i += 256) wsm[i] = w2[i];
  __syncthreads();
  float acc2[4][4] = {};
  for (int k = 0; k < FCH; k++) {
    float b[4];
#pragma unroll
    for (int j = 0; j < 4; j++) b[j] = wsm[k*FCH + tx*4 + j];
#pragma unroll
    for (int i = 0; i < 4; i++) {
      float a = rbs[k][ty*4 + i];
#pragma unroll
      for (int j = 0; j < 4; j++) acc2[i][j] = fmaf(a, b[j], acc2[i][j]);
    }
  }
#pragma unroll
  for (int i = 0; i < 4; i++) {
    int e = e0 + ty*4 + i;
    bf16x4 p;
#pragma unroll
    for (int j = 0; j < 4; j++) p.v[j] = __float2bfloat16(silu_f(acc2[i][j]));
    *(bf16x4*)(h2out + (size_t)e*FCH + tx*4) = p;
  }
}

// ---------------- per-row LN stats (mu, rstd) ----------------
__global__ __launch_bounds__(256)
void k_stats(const float* __restrict__ in, float* __restrict__ st,
             int n, int cols, int stride)
{
  int row = blockIdx.x * 4 + (threadIdx.x >> 6);
  int lane = threadIdx.x & 63;
  if (row >= n) return;
  const float* r = in + (size_t)row * stride;
  float s = 0.f, ss = 0.f;
  for (int c = lane; c < cols; c += 64) { float v = r[c]; s += v; ss += v*v; }
  for (int off = 32; off > 0; off >>= 1) { s += __shfl_down(s, off); ss += __shfl_down(ss, off); }
  if (lane == 0) {
    float mu = s / cols;
    float var = ss / cols - mu * mu;
    st[row*2]   = mu;
    st[row*2+1] = rsqrtf(fmaxf(var, 0.f) + 1e-5f);
  }
}

// ---------------- MFMA node GEMM: C = (silu?)((LN?)A @ B), optional +=, bf16 out opt ---
// A [M,K] f32 (lda), BT [col][k] bf16 pre-transposed (ldbT=K), tile 128x128, BK=32.
// NOTE: no min-waves in launch_bounds — forcing occupancy caused scratch spills (round 7).
template<int ADD, int SILU, int LNA, int OBF16>
__global__ __launch_bounds__(256)
void k_gemmm(const float* __restrict__ A, const __hip_bfloat16* __restrict__ BT,
             float* __restrict__ C, __hip_bfloat16* __restrict__ Cb,
             const float* __restrict__ st, int M, int K, int Nc, int lda)
{
  __shared__ __align__(16) char smA[8192];   // [128][32] bf16, XOR-swizzled
  __shared__ __align__(16) char smB[8192];
  __shared__ float smu[128], srs[128];
  int tid = threadIdx.x;
  int lane = tid & 63;
  int wv = tid >> 6;
  int l15 = lane & 15, l4 = lane >> 4;
  int row0 = blockIdx.x * 128;
  int col0 = blockIdx.y * 128;
  if (LNA && tid < 128) {
    int gr = row0 + tid;
    float m2 = 0.f, r2 = 1.f;
    if (gr < M) { m2 = st[gr*2]; r2 = st[gr*2+1]; }
    smu[tid] = m2; srs[tid] = r2;
  }
  f4v z4 = {0.f,0.f,0.f,0.f};
  f4v acc[2][8];
#pragma unroll
  for (int rt = 0; rt < 2; rt++)
#pragma unroll
  for (int ct = 0; ct < 8; ct++) acc[rt][ct] = z4;

  int sr = tid >> 1;               // row handled by this thread in staging
  int skq = (tid & 1) * 16;        // k offset (16 elems)
  for (int k0 = 0; k0 < K; k0 += 32) {
    __syncthreads();
    {   // stage A (f32 -> LN -> bf16)
      int grow = row0 + sr;
      float f[16];
      if (grow < M) {
        const float* ap = A + (size_t)grow * lda + k0 + skq;
#pragma unroll
        for (int q = 0; q < 4; q++) {
          float4 v = *(const float4*)(ap + q*4);
          f[q*4+0]=v.x; f[q*4+1]=v.y; f[q*4+2]=v.z; f[q*4+3]=v.w;
        }
      } else {
#pragma unroll
        for (int q = 0; q < 16; q++) f[q] = 0.f;
      }
      if (LNA) {
        float mu = smu[sr], rs = srs[sr];
#pragma unroll
        for (int q = 0; q < 16; q++) f[q] = (f[q] - mu) * rs;
      }
      unsigned u[8];
#pragma unroll
      for (int q = 0; q < 8; q++)
        u[q] = (unsigned)f2bfu(f[2*q]) | ((unsigned)f2bfu(f[2*q+1]) << 16);
      int base = sr*64 + skq*2;
      *(uint4*)(smA + (base ^ ((sr&7)<<4))) = make_uint4(u[0],u[1],u[2],u[3]);
      *(uint4*)(smA + ((base+16) ^ ((sr&7)<<4))) = make_uint4(u[4],u[5],u[6],u[7]);
    }
    {   // stage B from pre-transposed bf16
      const ushort* bp = (const ushort*)BT + (size_t)(col0 + sr) * K + k0 + skq;
      uint4 v0 = *(const uint4*)bp;
      uint4 v1 = *(const uint4*)(bp + 8);
      int base = sr*64 + skq*2;
      *(uint4*)(smB + (base ^ ((sr&7)<<4))) = v0;
      *(uint4*)(smB + ((base+16) ^ ((sr&7)<<4))) = v1;
    }
    __syncthreads();
    int r0 = wv*32 + l15, r1 = r0 + 16;
    bf8v a0 = *(const bf8v*)(smA + ((r0*64 + l4*16) ^ ((r0&7)<<4)));
    bf8v a1 = *(const bf8v*)(smA + ((r1*64 + l4*16) ^ ((r1&7)<<4)));
#pragma unroll
    for (int ct = 0; ct < 8; ct++) {
      int cc = ct*16 + l15;
      bf8v b = *(const bf8v*)(smB + ((cc*64 + l4*16) ^ ((cc&7)<<4)));
      acc[0][ct] = __builtin_amdgcn_mfma_f32_16x16x32_bf16(a0, b, acc[0][ct], 0, 0, 0);
      acc[1][ct] = __builtin_amdgcn_mfma_f32_16x16x32_bf16(a1, b, acc[1][ct], 0, 0, 0);
    }
  }
  // epilogue
#pragma unroll
  for (int rt = 0; rt < 2; rt++)
#pragma unroll
  for (int ct = 0; ct < 8; ct++)
#pragma unroll
  for (int e = 0; e < 4; e++) {
    int row = row0 + wv*32 + rt*16 + l4*4 + e;
    int col = col0 + ct*16 + l15;
    if (row < M && col < Nc) {
      float v = acc[rt][ct][e];
      if (SILU) v = silu_f(v);
      if (OBF16) Cb[(size_t)row * Nc + col] = __float2bfloat16(v);
      else {
        float* p = C + (size_t)row * Nc + col;
        if (ADD) *p += v; else *p = v;
      }
    }
  }
}

// ---------------- MFMA msg kernel ----------------
// MODE 0: logits partials (plain stores). MODE 1: alpha-weighted segment-sum -> agg.
// MODE 2: (1/16)-weighted segment-sum -> x.
// GEMM1 (MFMA): gate = h2 @ w3 (K=64). sw = sh @ wsh via VALU.
// GEMM3 (MODE>=1, MFMA): part = S^T @ M.
// LDS diet (<=40KB -> 4 blocks/CU): sh raw bf16, wsh bf16, alpha read direct
// (broadcast float4), mode-dead arrays compiled out. y gathered direct (round-8
// path; round-9 y-LDS-stage was a regression).
template<int MODE>
__global__ __launch_bounds__(256)
void k_msgm(const __hip_bfloat16* __restrict__ h2, const __hip_bfloat16* __restrict__ shb,
            const int* __restrict__ esrcp, const int* __restrict__ edstp,
            const __hip_bfloat16* __restrict__ w3T, const float* __restrict__ wsh,
            const float* __restrict__ aa, const __hip_bfloat16* __restrict__ y,
            const float* __restrict__ alpha, float* __restrict__ outbuf,
            float* __restrict__ logitsP)
{
  __shared__ __align__(16) char sm_ab[32768];     // h2s[128][64] + w3T[128][64] bf16; reused as MT
  __shared__ __align__(16) ushort shsu[128*16];   // 4KB raw sh bf16
  __shared__ ushort wshsu[9*128];                 // 2.25KB wsh bf16
  __shared__ int srcs[(MODE<=1)?128:1];
  __shared__ int dsts[(MODE>=1)?128:1];
  __shared__ int segidL[(MODE>=1)?128:1];
  __shared__ int seg_dstL[(MODE>=1)?32:1];
  __shared__ int cnt0s;

  int bid = blockIdx.x;
  int swzb = (bid & 7) * 625 + (bid >> 3);       // 5000 = 8 XCD chunks x 625
  int e0   = (swzb >> 2) * 128;
  int col0 = (swzb & 3) * 128;
  int tid = threadIdx.x;
  int lane = tid & 63;
  int wv = tid >> 6;
  int l15 = lane & 15, l4 = lane >> 4;
  int wrow0 = wv * 32;

  for (int c = tid; c < 1024; c += 256) {
    int r = c >> 3, s = c & 7;
    uint4 v = *(const uint4*)((const char*)h2 + (size_t)(e0 + r) * 128 + s * 16);
    *(uint4*)(sm_ab + ((r * 128 + s * 16) ^ ((r & 7) << 4))) = v;
  }
  for (int c = tid; c < 1024; c += 256) {
    int r = c >> 3, s = c & 7;
    uint4 v = *(const uint4*)((const char*)w3T + (size_t)(col0 + r) * 128 + s * 16);
    *(uint4*)(sm_ab + 16384 + ((r * 128 + s * 16) ^ ((r & 7) << 4))) = v;
  }
  {   // sh raw copy: 128 rows x 32B, one uint4 per thread
    int el = tid >> 1, half = tid & 1;
    *(uint4*)(shsu + el * 16 + half * 8) =
        *(const uint4*)((const ushort*)shb + (size_t)(e0 + el) * 16 + half * 8);
  }
  for (int idx = tid; idx < 9 * 128; idx += 256) {
    int q = idx >> 7, c = idx & 127;
    int col = col0 + c;
    wshsu[idx] = (col < DIM) ? f2bfu(wsh[q * DIM + col]) : (ushort)0;
  }
  if (tid < 128) {
    if (MODE <= 1) srcs[tid] = esrcp[e0 + tid];
    if (MODE >= 1) dsts[tid] = edstp[e0 + tid];
  }
  __syncthreads();

  // ballot-based segment scan over the 128 dst-sorted edges
  int nseg = 0;
  bool flag = false;
  if (MODE >= 1) {
    if (tid < 128) {
      flag = (tid == 0) || (dsts[tid] != dsts[tid - 1]);
      unsigned long long m = __ballot(flag ? 1 : 0);
      if (tid == 0) cnt0s = __popcll(m);
      unsigned long long below = m & (~0ull >> (63 - (tid & 63)));
      segidL[tid] = __popcll(below);
    }
    __syncthreads();
    if (tid < 128) {
      int sg = segidL[tid] - 1 + (tid >= 64 ? cnt0s : 0);
      segidL[tid] = sg;
      if (flag && sg < 32) seg_dstL[sg] = dsts[tid];
    }
    __syncthreads();
    nseg = segidL[127] + 1;
  }

  f4v z4 = {0.f, 0.f, 0.f, 0.f};
  f4v g[2][8];
#pragma unroll
  for (int rt = 0; rt < 2; rt++)
#pragma unroll
  for (int ct = 0; ct < 8; ct++) g[rt][ct] = z4;

  // GEMM1: gate = h2 @ w3
#pragma unroll
  for (int ks = 0; ks < 2; ks++) {
    int k0b = (ks * 32 + l4 * 8) * 2;
    int r0 = wrow0 + l15;
    int r1 = r0 + 16;
    bf8v a0 = *(const bf8v*)(sm_ab + ((r0 * 128 + k0b) ^ ((r0 & 7) << 4)));
    bf8v a1 = *(const bf8v*)(sm_ab + ((r1 * 128 + k0b) ^ ((r1 & 7) << 4)));
#pragma unroll
    for (int ct = 0; ct < 8; ct++) {
      int cc = ct * 16 + l15;
      bf8v b = *(const bf8v*)(sm_ab + 16384 + ((cc * 128 + k0b) ^ ((cc & 7) << 4)));
      g[0][ct] = __builtin_amdgcn_mfma_f32_16x16x32_bf16(a0, b, g[0][ct], 0, 0, 0);
      g[1][ct] = __builtin_amdgcn_mfma_f32_16x16x32_bf16(a1, b, g[1][ct], 0, 0, 0);
    }
  }

  // m = y * (sh@wsh) * gate  (sw via VALU; y direct gather), + alpha / scale
  const ushort* yus = (const ushort*)y;
#pragma unroll
  for (int rt = 0; rt < 2; rt++)
#pragma unroll
  for (int e = 0; e < 4; e++) {
    int rl = wrow0 + rt * 16 + l4 * 4 + e;
    int src = 0;
    if (MODE <= 1) src = srcs[rl];
    float4 al = make_float4(0.f, 0.f, 0.f, 0.f);
    if (MODE == 1) al = *(const float4*)(alpha + (size_t)(e0 + rl) * 4);
    float sh9[9];
#pragma unroll
    for (int q = 0; q < 9; q++) sh9[q] = bf2f(shsu[rl * 16 + q]);
#pragma unroll
    for (int ct = 0; ct < 8; ct++) {
      int colL = ct * 16 + l15;
      int col = col0 + colL;
      float swv = 0.f;
#pragma unroll
      for (int q = 0; q < 9; q++) swv = fmaf(sh9[q], bf2f(wshsu[q * 128 + colL]), swv);
      float yv;
      if (MODE == 2) yv = 1.f;
      else yv = (col < DIM) ? bf2f(yus[(size_t)src * DIM + col]) : 0.f;
      float mv = yv * swv * g[rt][ct][e];
      if (MODE == 1) {
        float av = (col < 120) ? al.x : (col < 240) ? al.y : (col < 360) ? al.z : al.w;
        mv *= av;
      }
      if (MODE == 2) mv *= (1.0f / 16.0f);
      g[rt][ct][e] = mv;
    }
  }

  if (MODE == 0) {
    int hA = col0 / 120;
    float aav[8];
#pragma unroll
    for (int ct = 0; ct < 8; ct++) {
      int col = col0 + ct * 16 + l15;
      aav[ct] = (col < DIM) ? aa[col] : 0.f;
    }
#pragma unroll
    for (int rt = 0; rt < 2; rt++)
#pragma unroll
    for (int e = 0; e < 4; e++) {
      float sA = 0.f, sB = 0.f;
#pragma unroll
      for (int ct = 0; ct < 8; ct++) {
        int col = col0 + ct * 16 + l15;
        float mv = g[rt][ct][e];
        float lv = (mv > 0.f) ? mv : 0.2f * mv;
        float c = lv * aav[ct];
        if (col / 120 == hA) sA += c; else sB += c;
      }
#pragma unroll
      for (int off = 1; off < 16; off <<= 1) {
        sA += __shfl_xor(sA, off, 16);
        sB += __shfl_xor(sB, off, 16);
      }
      if (l15 == 0) {
        int row = e0 + wrow0 + rt * 16 + l4 * 4 + e;
        logitsP[((size_t)row * NHEAD + hA) * 2] = sA;
        if (hA < 3) logitsP[((size_t)row * NHEAD + hA + 1) * 2 + 1] = sB;
      }
    }
    return;
  }

  // overflow fallback (rare): direct atomics
  if (nseg > 32) {
#pragma unroll
    for (int rt = 0; rt < 2; rt++)
#pragma unroll
    for (int e = 0; e < 4; e++) {
      int rl = wrow0 + rt * 16 + l4 * 4 + e;
      int dd = dsts[rl];
#pragma unroll
      for (int ct = 0; ct < 8; ct++) {
        int col = col0 + ct * 16 + l15;
        if (col < DIM) atomicAdd(&outbuf[(size_t)dd * DIM + col], g[rt][ct][e]);
      }
    }
    return;
  }

  // write M^T [col][edge] bf16 into sm_ab (overwrites GEMM1 operands)
  __syncthreads();
#pragma unroll
  for (int rt = 0; rt < 2; rt++)
#pragma unroll
  for (int ct = 0; ct < 8; ct++) {
    int cc = ct * 16 + l15;
    int ebase = wrow0 + rt * 16 + l4 * 4;
    ushort4 pk;
    pk.x = f2bfu(g[rt][ct][0]); pk.y = f2bfu(g[rt][ct][1]);
    pk.z = f2bfu(g[rt][ct][2]); pk.w = f2bfu(g[rt][ct][3]);
    *(ushort4*)(sm_ab + ((cc * 256 + ebase * 2) ^ ((cc & 7) << 4))) = pk;
  }
  __syncthreads();

  // GEMM3: part[seg][col] = S^T @ M ; wave wv owns cols [wv*32, wv*32+32)
  f4v p[2][2];
  p[0][0] = z4; p[0][1] = z4; p[1][0] = z4; p[1][1] = z4;
#pragma unroll
  for (int ks = 0; ks < 4; ks++) {
    int k0 = ks * 32 + l4 * 8;
    bf8v a0, a1;
#pragma unroll
    for (int e2 = 0; e2 < 8; e2++) {
      int sg = segidL[k0 + e2];
      a0[e2] = (sg == l15)      ? (short)0x3F80 : (short)0;
      a1[e2] = (sg == l15 + 16) ? (short)0x3F80 : (short)0;
    }
#pragma unroll
    for (int c2 = 0; c2 < 2; c2++) {
      int cc = (wv * 2 + c2) * 16 + l15;
      bf8v bm = *(const bf8v*)(sm_ab + ((cc * 256 + k0 * 2) ^ ((cc & 7) << 4)));
      p[0][c2] = __builtin_amdgcn_mfma_f32_16x16x32_bf16(a0, bm, p[0][c2], 0, 0, 0);
      p[1][c2] = __builtin_amdgcn_mfma_f32_16x16x32_bf16(a1, bm, p[1][c2], 0, 0, 0);
    }
  }
#pragma unroll
  for (int rt = 0; rt < 2; rt++)
#pragma unroll
  for (int c2 = 0; c2 < 2; c2++)
#pragma unroll
  for (int e = 0; e < 4; e++) {
    int seg = rt * 16 + l4 * 4 + e;
    int col = col0 + (wv * 2 + c2) * 16 + l15;
    if (seg < nseg && col < DIM) {
      float v = p[rt][c2][e];
      float* ptr = outbuf + (size_t)seg_dstL[seg] * DIM + col;
      if (seg == 0 || seg == nseg - 1) atomicAdd(ptr, v);
      else if (MODE == 1) *ptr = v;
      else *ptr += v;
    }
  }
}

// ---------------- segment softmax (reads 2-slot logit partials) ----------------
__global__ void k_alpha(const int* __restrict__ row_ptr, const float* __restrict__ logitsP,
                        float* __restrict__ alpha)
{
  int i = blockIdx.x * 256 + threadIdx.x;
  if (i >= NN * NHEAD) return;
  int d = i >> 2, h = i & 3;
  int beg = row_ptr[d], end = row_ptr[d+1];
  if (beg == end) return;
  float m = -1e30f;
  for (int j = beg; j < end; j++) {
    float L = logitsP[((size_t)j*NHEAD + h)*2] + logitsP[((size_t)j*NHEAD + h)*2 + 1];
    m = fmaxf(m, L);
  }
  float s = 0.f;
  for (int j = beg; j < end; j++) {
    float L = logitsP[((size_t)j*NHEAD + h)*2] + logitsP[((size_t)j*NHEAD + h)*2 + 1];
    float ex = __expf(L - m);
    alpha[(size_t)j*NHEAD + h] = ex;
    s += ex;
  }
  float inv = 1.f / (s + 1e-9f);
  for (int j = beg; j < end; j++) alpha[(size_t)j*NHEAD + h] *= inv;
}

// ---------------- x init: atom embedding gather ----------------
__global__ void k_init_x(const int* __restrict__ z, const float* __restrict__ emb,
                         float* __restrict__ x)
{
  int i = blockIdx.x * 256 + threadIdx.x;
  if (i >= NN * DIM) return;
  int n = i / DIM, c = i - n * DIM;
  x[i] = emb[(size_t)z[n]*DIM + c];
}

// ---------------- final scatter over molecules ----------------
__global__ void k_scatter(const float* __restrict__ h, const int* __restrict__ batch,
                          float* __restrict__ out)
{
  int i = blockIdx.x * 256 + threadIdx.x;
  if (i >= NN * NS) return;
  int n = i >> 7;
  atomicAdd(&out[(size_t)batch[n]*NS + (i & 127)], h[i] * 0.23570226039551584f);
}

extern "C" void kernel_launch(void* const* d_in, const int* in_sizes, int n_in,
                              void* d_out, int out_size, void* d_ws, size_t ws_size,
                              hipStream_t stream)
{
  const int*   z        = (const int*)  d_in[0];
  const float* pos      = (const float*)d_in[1];
  const int*   batch    = (const int*)  d_in[2];
  const int*   esrc     = (const int*)  d_in[3];
  const int*   edst     = (const int*)  d_in[4];
  const float* atom_emb = (const float*)d_in[5];
  const float* W_deg_sh = (const float*)d_in[6];
  const float* deg_w1   = (const float*)d_in[7];
  const float* deg_w2   = (const float*)d_in[8];
  const float* deg_w3   = (const float*)d_in[9];
  const float* Wv       = (const float*)d_in[10];
  const float* Wsh      = (const float*)d_in[11];
  const float* rad_w1   = (const float*)d_in[12];
  const float* rad_w2   = (const float*)d_in[13];
  const float* rad_w3   = (const float*)d_in[14];
  const float* attn_a   = (const float*)d_in[15];
  const float* Wo       = (const float*)d_in[16];
  const float* ffn_w1   = (const float*)d_in[17];
  const float* ffn_w2   = (const float*)d_in[18];
  const float* head_w1  = (const float*)d_in[19];
  const float* head_w2  = (const float*)d_in[20];
  float* out = (float*)d_out;

  // workspace (~102 MB)
  float* x      = (float*)d_ws;                        // [NN][480]
  float* statsb = x      + (size_t)NN * DIM;           // [NN][2]
  float* agg    = statsb + (size_t)NN * 2;             // [NN][480]
  float* tmp    = agg    + (size_t)NN * DIM;           // [NN][128]
  float* distp  = tmp    + (size_t)NN * NS;            // [NE]
  float* logitsP= distp  + (size_t)NE;                 // [NE][4][2]
  float* alphab = logitsP+ (size_t)NE * NHEAD * 2;     // [NE][4]
  __hip_bfloat16* yb    = (__hip_bfloat16*)(alphab + (size_t)NE * NHEAD);  // [NN][480]
  __hip_bfloat16* h2b   = yb + (size_t)NN * DIM;       // [NE][64]
  __hip_bfloat16* shb16 = h2b + (size_t)NE * FCH;      // [NE][16]
  __hip_bfloat16* w3Tb  = shb16 + (size_t)NE * 16;     // [7][512][64]
  __hip_bfloat16* bigWT = w3Tb + (size_t)7 * 512 * 64; // [24][512][480] + [2][128][128]
  int* cnt      = (int*)(bigWT + (size_t)24*512*480 + 2*128*128);
  int* row_ptr  = cnt + NN;
  int* csr      = row_ptr + NN + 1;
  int* cursor   = csr + NE;
  int* esrcp    = cursor + NN;
  int* edstp    = esrcp + NE;

  dim3 b256(256);
  // CSR build (dst-sorted edge permutation)
  k_zero_int<<<(NN+255)/256, b256, 0, stream>>>(cnt, NN);
  k_count<<<(NE+255)/256, b256, 0, stream>>>(edst, cnt);
  k_scan<<<1, 1024, 0, stream>>>(cnt, row_ptr);
  k_zero_int<<<(NN+255)/256, b256, 0, stream>>>(cursor, NN);
  k_fill<<<(NE+255)/256, b256, 0, stream>>>(edst, row_ptr, cursor, csr);
  k_geom_p<<<(NE+255)/256, b256, 0, stream>>>(pos, esrc, edst, csr, shb16, distp, esrcp, edstp);
  k_prep<<<(7*512*64 + 255)/256, b256, 0, stream>>>(deg_w3, rad_w3, w3Tb);
  k_prepw<<<(24*512*480 + 2*128*128 + 255)/256, b256, 0, stream>>>(Wv, Wo, ffn_w1, ffn_w2,
      head_w1, head_w2, bigWT);
  hipMemsetAsync(logitsP, 0, (size_t)NE * NHEAD * 2 * sizeof(float), stream);

  // degree embedding: x = emb[z] + (1/16) * segsum(sw * gate)
  k_radial<<<NE/64, b256, 0, stream>>>(distp, deg_w1, deg_w2, h2b);
  k_init_x<<<(NN*DIM+255)/256, b256, 0, stream>>>(z, atom_emb, x);
  k_msgm<2><<<5000, b256, 0, stream>>>(h2b, shb16, esrcp, edstp, w3Tb, W_deg_sh,
      nullptr, nullptr, nullptr, x, nullptr);

  dim3 gemm_grid(79, 4);
  dim3 head_grid(79, 1);
  for (int l = 0; l < NL; l++) {
    const float* w1_l  = rad_w1 + (size_t)l*NBASIS*FCH;
    const float* w2_l  = rad_w2 + (size_t)l*FCH*FCH;
    const float* wsh_l = Wsh + (size_t)l*NSH*DIM;
    const float* aa_l  = attn_a + (size_t)l*NHEAD*HDIM;
    const __hip_bfloat16* w3T_l = w3Tb + (size_t)(l+1)*512*64;
    const __hip_bfloat16* WvT_l = bigWT + (size_t)(0+l)*512*480;
    const __hip_bfloat16* WoT_l = bigWT + (size_t)(6+l)*512*480;
    const __hip_bfloat16* F1T_l = bigWT + (size_t)(12+l)*512*480;
    const __hip_bfloat16* F2T_l = bigWT + (size_t)(18+l)*512*480;

    k_stats<<<(NN+3)/4, b256, 0, stream>>>(x, statsb, NN, DIM, DIM);
    k_gemmm<0,0,1,1><<<gemm_grid, b256, 0, stream>>>(x, WvT_l, nullptr, yb, statsb,
        NN, DIM, DIM, DIM);                             // yb = LN(x) @ Wv (bf16)
    k_radial<<<NE/64, b256, 0, stream>>>(distp, w1_l, w2_l, h2b);
    k_msgm<0><<<5000, b256, 0, stream>>>(h2b, shb16, esrcp, edstp, w3T_l, wsh_l,
        aa_l, yb, nullptr, nullptr, logitsP);
    k_alpha<<<(NN*NHEAD+255)/256, b256, 0, stream>>>(row_ptr, logitsP, alphab);
    hipMemsetAsync(agg, 0, (size_t)NN * DIM * sizeof(float), stream);
    k_msgm<1><<<5000, b256, 0, stream>>>(h2b, shb16, esrcp, edstp, w3T_l, wsh_l,
        nullptr, yb, alphab, agg, nullptr);
    k_gemmm<1,0,0,0><<<gemm_grid, b256, 0, stream>>>(agg, WoT_l, x, nullptr, nullptr,
        NN, DIM, DIM, DIM);                             // x += agg @ Wo
    k_stats<<<(NN+3)/4, b256, 0, stream>>>(x, statsb, NN, DIM, DIM);
    k_gemmm<0,1,1,0><<<gemm_grid, b256, 0, stream>>>(x, F1T_l, agg, nullptr, statsb,
        NN, DIM, DIM, DIM);                             // agg = silu(LN(x) @ W1)
    k_gemmm<1,0,0,0><<<gemm_grid, b256, 0, stream>>>(agg, F2T_l, x, nullptr, nullptr,
        NN, DIM, DIM, DIM);                             // x += agg @ W2
  }

  // output head
  const __hip_bfloat16* H1T = bigWT + (size_t)24*512*480;
  const __hip_bfloat16* H2T = H1T + 128*128;
  k_stats<<<(NN+3)/4, b256, 0, stream>>>(x, statsb, NN, NS, DIM);
  k_gemmm<0,1,1,0><<<head_grid, b256, 0, stream>>>(x, H1T, agg, nullptr, statsb,
      NN, NS, NS, DIM);
  k_gemmm<0,0,0,0><<<head_grid, b256, 0, stream>>>(agg, H2T, tmp, nullptr, nullptr,
      NN, NS, NS, NS);
  hipMemsetAsync(d_out, 0, (size_t)NG * NS * sizeof(float), stream);
  k_scatter<<<(NN*NS+255)/256, b256, 0, stream>>>(tmp, batch, out);
}

// Round 11
// 3713.234 us; speedup vs baseline: 1.3190x; 1.2080x over previous
//
#include <hip/hip_runtime.h>
#include <hip/hip_bf16.h>
#include <math.h>

#define NN 10000
#define NE 160000
#define DIM 480
#define NSH 9
#define NBASIS 128
#define NHEAD 4
#define HDIM 120
#define NL 6
#define NG 256
#define NS 128
#define FCH 64
#define CUTOFF 5.0f

typedef __attribute__((ext_vector_type(8))) short bf8v;
typedef __attribute__((ext_vector_type(4))) float f4v;

__device__ __forceinline__ float silu_f(float v) { return v / (1.0f + __expf(-v)); }
__device__ __forceinline__ float bf2f(ushort u) { return __uint_as_float(((unsigned)u) << 16); }
__device__ __forceinline__ ushort f2bfu(float f) {
  __hip_bfloat16 h = __float2bfloat16(f);
  return *reinterpret_cast<ushort*>(&h);
}

struct bf16x4 { __hip_bfloat16 v[4]; };

// ---------------- CSR build ----------------
__global__ void k_zero_int(int* p, int n)
{
  int i = blockIdx.x * 256 + threadIdx.x;
  if (i < n) p[i] = 0;
}

__global__ void k_count(const int* __restrict__ edst, int* __restrict__ cnt)
{
  int e = blockIdx.x * 256 + threadIdx.x;
  if (e < NE) atomicAdd(&cnt[edst[e]], 1);
}

__global__ __launch_bounds__(1024)
void k_scan(const int* __restrict__ cnt, int* __restrict__ row_ptr)
{
  __shared__ int part[1024];
  int tid = threadIdx.x;
  const int per = 10;
  int base = tid * per;
  int s = 0;
  for (int i = 0; i < per; i++) { int idx = base + i; if (idx < NN) s += cnt[idx]; }
  part[tid] = s; __syncthreads();
  for (int off = 1; off < 1024; off <<= 1) {
    int v = (tid >= off) ? part[tid - off] : 0;
    __syncthreads();
    part[tid] += v;
    __syncthreads();
  }
  int run = (tid > 0) ? part[tid - 1] : 0;
  for (int i = 0; i < per; i++) {
    int idx = base + i;
    if (idx < NN) { row_ptr[idx] = run; run += cnt[idx]; }
  }
  if (tid == 1023) row_ptr[NN] = part[1023];
}

__global__ void k_fill(const int* __restrict__ edst, const int* __restrict__ row_ptr,
                       int* __restrict__ cursor, int* __restrict__ csr)
{
  int e = blockIdx.x * 256 + threadIdx.x;
  if (e >= NE) return;
  int d = edst[e];
  int p = atomicAdd(&cursor[d], 1);
  csr[row_ptr[d] + p] = e;
}

// ---------------- geometry in permuted (CSR) order; sh as bf16 [NE][16] padded ----
__global__ void k_geom_p(const float* __restrict__ pos, const int* __restrict__ esrc,
                         const int* __restrict__ edst, const int* __restrict__ csr,
                         __hip_bfloat16* __restrict__ shb, float* __restrict__ distp,
                         int* __restrict__ esrcp, int* __restrict__ edstp)
{
  int j = blockIdx.x * 256 + threadIdx.x;
  if (j >= NE) return;
  int e = csr[j];
  int s = esrc[e], d = edst[e];
  esrcp[j] = s;
  edstp[j] = d;
  float vx = pos[s*3+0] - pos[d*3+0];
  float vy = pos[s*3+1] - pos[d*3+1];
  float vz = pos[s*3+2] - pos[d*3+2];
  float r = sqrtf(vx*vx + vy*vy + vz*vz);
  distp[j] = r;
  float inv = 1.0f / (r + 1e-9f);
  float x = vx*inv, y = vy*inv, z = vz*inv;
  const float s3 = 1.7320508075688772f;
  const float s15 = 3.872983346207417f;
  const float s5 = 2.23606797749979f;
  float sv[9];
  sv[0] = 1.0f;
  sv[1] = s3*x; sv[2] = s3*y; sv[3] = s3*z;
  sv[4] = s15*x*y; sv[5] = s15*y*z; sv[6] = 0.5f*s5*(3.0f*z*z - 1.0f);
  sv[7] = s15*x*z; sv[8] = 0.5f*s15*(x*x - y*y);
  __hip_bfloat16* o = shb + (size_t)j * 16;
#pragma unroll
  for (int q = 0; q < 9; q++) o[q] = __float2bfloat16(sv[q]);
#pragma unroll
  for (int q = 9; q < 16; q++) o[q] = __float2bfloat16(0.f);
}

// ---------------- prep: w3T [7][512][64] bf16 ----------------
__global__ void k_prep(const float* __restrict__ deg_w3, const float* __restrict__ rad_w3,
                       __hip_bfloat16* __restrict__ w3T)
{
  int i = blockIdx.x * 256 + threadIdx.x;
  if (i >= 7*512*64) return;
  int l = i / (512*64); int r = i - l*512*64; int col = r >> 6; int k = r & 63;
  float v = 0.f;
  if (col < DIM) {
    const float* src = (l == 0) ? deg_w3 : rad_w3 + (size_t)(l-1)*FCH*DIM;
    v = src[k*DIM + col];
  }
  w3T[i] = __float2bfloat16(v);
}

// ---------------- prep: node-GEMM weights transposed bf16 ----------------
__global__ void k_prepw(const float* __restrict__ Wv, const float* __restrict__ Wo,
                        const float* __restrict__ f1, const float* __restrict__ f2,
                        const float* __restrict__ h1, const float* __restrict__ h2w,
                        __hip_bfloat16* __restrict__ WT)
{
  int i = blockIdx.x * 256 + threadIdx.x;
  const int big = 24*512*480;
  if (i < big) {
    int m = i / (512*480); int r = i - m*(512*480); int col = r / 480; int k = r - col*480;
    int l = m % 6; int t = m / 6;
    const float* src = (t==0 ? Wv : t==1 ? Wo : t==2 ? f1 : f2) + (size_t)l*DIM*DIM;
    float v = (col < DIM) ? src[k*DIM + col] : 0.f;
    WT[i] = __float2bfloat16(v);
  } else if (i < big + 2*128*128) {
    int j = i - big; int m = j / (128*128); int r = j - m*(128*128);
    int col = r >> 7; int k = r & 127;
    const float* src = m ? h2w : h1;
    WT[i] = __float2bfloat16(src[k*128 + col]);
  }
}

// ---------------- radial MLP -> h2 bf16 [E,64] ----------------
__global__ __launch_bounds__(256)
void k_radial(const float* __restrict__ dist, const float* __restrict__ w1,
              const float* __restrict__ w2, __hip_bfloat16* __restrict__ h2out)
{
  __shared__ float rbs[NBASIS][65];
  __shared__ float wsm[NBASIS * FCH];
  __shared__ float ds[64];
  int tid = threadIdx.x;
  int e0 = blockIdx.x * 64;
  if (tid < 64) ds[tid] = dist[e0 + tid];
  for (int i = tid; i < NBASIS * FCH; i += 256) wsm[i] = w1[i];
  __syncthreads();
  const float invw = (float)NBASIS / CUTOFF;
  for (int i = tid; i < NBASIS * 64; i += 256) {
    int k = i >> 6, e = i & 63;
    float c = k * (CUTOFF / 127.0f);
    float tt = (ds[e] - c) * invw;
    rbs[k][e] = __expf(-0.5f * tt * tt);
  }
  __syncthreads();
  int ty = tid >> 4, tx = tid & 15;
  float acc1[4][4] = {};
  for (int k = 0; k < NBASIS; k++) {
    float b[4];
#pragma unroll
    for (int j = 0; j < 4; j++) b[j] = wsm[k*FCH + tx*4 + j];
#pragma unroll
    for (int i = 0; i < 4; i++) {
      float a = rbs[k][ty*4 + i];
#pragma unroll
      for (int j = 0; j < 4; j++) acc1[i][j] = fmaf(a, b[j], acc1[i][j]);
    }
  }
  __syncthreads();
#pragma unroll
  for (int i = 0; i < 4; i++)
#pragma unroll
    for (int j = 0; j < 4; j++)
      rbs[tx*4 + j][ty*4 + i] = silu_f(acc1[i][j]);
  for (int i = tid; i < FCH * FCH; i += 256) wsm[i] = w2[i];
  __syncthreads();
  float acc2[4][4] = {};
  for (int k = 0; k < FCH; k++) {
    float b[4];
#pragma unroll
    for (int j = 0; j < 4; j++) b[j] = wsm[k*FCH + tx*4 + j];
#pragma unroll
    for (int i = 0; i < 4; i++) {
      float a = rbs[k][ty*4 + i];
#pragma unroll
      for (int j = 0; j < 4; j++) acc2[i][j] = fmaf(a, b[j], acc2[i][j]);
    }
  }
#pragma unroll
  for (int i = 0; i < 4; i++) {
    int e = e0 + ty*4 + i;
    bf16x4 p;
#pragma unroll
    for (int j = 0; j < 4; j++) p.v[j] = __float2bfloat16(silu_f(acc2[i][j]));
    *(bf16x4*)(h2out + (size_t)e*FCH + tx*4) = p;
  }
}

// ---------------- per-row LN stats (mu, rstd) ----------------
__global__ __launch_bounds__(256)
void k_stats(const float* __restrict__ in, float* __restrict__ st,
             int n, int cols, int stride)
{
  int row = blockIdx.x * 4 + (threadIdx.x >> 6);
  int lane = threadIdx.x & 63;
  if (row >= n) return;
  const float* r = in + (size_t)row * stride;
  float s = 0.f, ss = 0.f;
  for (int c = lane; c < cols; c += 64) { float v = r[c]; s += v; ss += v*v; }
  for (int off = 32; off > 0; off >>= 1) { s += __shfl_down(s, off); ss += __shfl_down(ss, off); }
  if (lane == 0) {
    float mu = s / cols;
    float var = ss / cols - mu * mu;
    st[row*2]   = mu;
    st[row*2+1] = rsqrtf(fmaxf(var, 0.f) + 1e-5f);
  }
}

// ---------------- MFMA node GEMM ----------------
template<int ADD, int SILU, int LNA, int OBF16>
__global__ __launch_bounds__(256)
void k_gemmm(const float* __restrict__ A, const __hip_bfloat16* __restrict__ BT,
             float* __restrict__ C, __hip_bfloat16* __restrict__ Cb,
             const float* __restrict__ st, int M, int K, int Nc, int lda)
{
  __shared__ __align__(16) char smA[8192];
  __shared__ __align__(16) char smB[8192];
  __shared__ float smu[128], srs[128];
  int tid = threadIdx.x;
  int lane = tid & 63;
  int wv = tid >> 6;
  int l15 = lane & 15, l4 = lane >> 4;
  int row0 = blockIdx.x * 128;
  int col0 = blockIdx.y * 128;
  if (LNA && tid < 128) {
    int gr = row0 + tid;
    float m2 = 0.f, r2 = 1.f;
    if (gr < M) { m2 = st[gr*2]; r2 = st[gr*2+1]; }
    smu[tid] = m2; srs[tid] = r2;
  }
  f4v z4 = {0.f,0.f,0.f,0.f};
  f4v acc[2][8];
#pragma unroll
  for (int rt = 0; rt < 2; rt++)
#pragma unroll
  for (int ct = 0; ct < 8; ct++) acc[rt][ct] = z4;

  int sr = tid >> 1;
  int skq = (tid & 1) * 16;
  for (int k0 = 0; k0 < K; k0 += 32) {
    __syncthreads();
    {
      int grow = row0 + sr;
      float f[16];
      if (grow < M) {
        const float* ap = A + (size_t)grow * lda + k0 + skq;
#pragma unroll
        for (int q = 0; q < 4; q++) {
          float4 v = *(const float4*)(ap + q*4);
          f[q*4+0]=v.x; f[q*4+1]=v.y; f[q*4+2]=v.z; f[q*4+3]=v.w;
        }
      } else {
#pragma unroll
        for (int q = 0; q < 16; q++) f[q] = 0.f;
      }
      if (LNA) {
        float mu = smu[sr], rs = srs[sr];
#pragma unroll
        for (int q = 0; q < 16; q++) f[q] = (f[q] - mu) * rs;
      }
      unsigned u[8];
#pragma unroll
      for (int q = 0; q < 8; q++)
        u[q] = (unsigned)f2bfu(f[2*q]) | ((unsigned)f2bfu(f[2*q+1]) << 16);
      int base = sr*64 + skq*2;
      *(uint4*)(smA + (base ^ ((sr&7)<<4))) = make_uint4(u[0],u[1],u[2],u[3]);
      *(uint4*)(smA + ((base+16) ^ ((sr&7)<<4))) = make_uint4(u[4],u[5],u[6],u[7]);
    }
    {
      const ushort* bp = (const ushort*)BT + (size_t)(col0 + sr) * K + k0 + skq;
      uint4 v0 = *(const uint4*)bp;
      uint4 v1 = *(const uint4*)(bp + 8);
      int base = sr*64 + skq*2;
      *(uint4*)(smB + (base ^ ((sr&7)<<4))) = v0;
      *(uint4*)(smB + ((base+16) ^ ((sr&7)<<4))) = v1;
    }
    __syncthreads();
    int r0 = wv*32 + l15, r1 = r0 + 16;
    bf8v a0 = *(const bf8v*)(smA + ((r0*64 + l4*16) ^ ((r0&7)<<4)));
    bf8v a1 = *(const bf8v*)(smA + ((r1*64 + l4*16) ^ ((r1&7)<<4)));
#pragma unroll
    for (int ct = 0; ct < 8; ct++) {
      int cc = ct*16 + l15;
      bf8v b = *(const bf8v*)(smB + ((cc*64 + l4*16) ^ ((cc&7)<<4)));
      acc[0][ct] = __builtin_amdgcn_mfma_f32_16x16x32_bf16(a0, b, acc[0][ct], 0, 0, 0);
      acc[1][ct] = __builtin_amdgcn_mfma_f32_16x16x32_bf16(a1, b, acc[1][ct], 0, 0, 0);
    }
  }
#pragma unroll
  for (int rt = 0; rt < 2; rt++)
#pragma unroll
  for (int ct = 0; ct < 8; ct++)
#pragma unroll
  for (int e = 0; e < 4; e++) {
    int row = row0 + wv*32 + rt*16 + l4*4 + e;
    int col = col0 + ct*16 + l15;
    if (row < M && col < Nc) {
      float v = acc[rt][ct][e];
      if (SILU) v = silu_f(v);
      if (OBF16) Cb[(size_t)row * Nc + col] = __float2bfloat16(v);
      else {
        float* p = C + (size_t)row * Nc + col;
        if (ADD) *p += v; else *p = v;
      }
    }
  }
}

// ---------------- MFMA msg kernel ----------------
// MODE 0: logits partials (plain stores); STOREM=1 additionally dumps the
//         swizzled M^T tile (32KB) to msgb (tile-major, raw bytes).
// MODE 1: alpha-weighted segment-sum -> agg (fallback path only).
// MODE 2: (1/16)-weighted segment-sum -> x.
template<int MODE, int STOREM>
__global__ __launch_bounds__(256)
void k_msgm(const __hip_bfloat16* __restrict__ h2, const __hip_bfloat16* __restrict__ shb,
            const int* __restrict__ esrcp, const int* __restrict__ edstp,
            const __hip_bfloat16* __restrict__ w3T, const float* __restrict__ wsh,
            const float* __restrict__ aa, const __hip_bfloat16* __restrict__ y,
            const float* __restrict__ alpha, float* __restrict__ outbuf,
            float* __restrict__ logitsP, __hip_bfloat16* __restrict__ msgb)
{
  __shared__ __align__(16) char sm_ab[32768];     // h2s[128][64] + w3T[128][64] bf16; reused as MT
  __shared__ __align__(16) ushort shsu[128*16];
  __shared__ ushort wshsu[9*128];
  __shared__ int srcs[(MODE<=1)?128:1];
  __shared__ int dsts[(MODE>=1)?128:1];
  __shared__ int segidL[(MODE>=1)?128:1];
  __shared__ int seg_dstL[(MODE>=1)?32:1];
  __shared__ int cnt0s;

  int bid = blockIdx.x;
  int swzb = (bid & 7) * 625 + (bid >> 3);       // 5000 = 8 XCD chunks x 625
  int e0   = (swzb >> 2) * 128;
  int col0 = (swzb & 3) * 128;
  int tid = threadIdx.x;
  int lane = tid & 63;
  int wv = tid >> 6;
  int l15 = lane & 15, l4 = lane >> 4;
  int wrow0 = wv * 32;

  for (int c = tid; c < 1024; c += 256) {
    int r = c >> 3, s = c & 7;
    uint4 v = *(const uint4*)((const char*)h2 + (size_t)(e0 + r) * 128 + s * 16);
    *(uint4*)(sm_ab + ((r * 128 + s * 16) ^ ((r & 7) << 4))) = v;
  }
  for (int c = tid; c < 1024; c += 256) {
    int r = c >> 3, s = c & 7;
    uint4 v = *(const uint4*)((const char*)w3T + (size_t)(col0 + r) * 128 + s * 16);
    *(uint4*)(sm_ab + 16384 + ((r * 128 + s * 16) ^ ((r & 7) << 4))) = v;
  }
  {
    int el = tid >> 1, half = tid & 1;
    *(uint4*)(shsu + el * 16 + half * 8) =
        *(const uint4*)((const ushort*)shb + (size_t)(e0 + el) * 16 + half * 8);
  }
  for (int idx = tid; idx < 9 * 128; idx += 256) {
    int q = idx >> 7, c = idx & 127;
    int col = col0 + c;
    wshsu[idx] = (col < DIM) ? f2bfu(wsh[q * DIM + col]) : (ushort)0;
  }
  if (tid < 128) {
    if (MODE <= 1) srcs[tid] = esrcp[e0 + tid];
    if (MODE >= 1) dsts[tid] = edstp[e0 + tid];
  }
  __syncthreads();

  int nseg = 0;
  bool flag = false;
  if (MODE >= 1) {
    if (tid < 128) {
      flag = (tid == 0) || (dsts[tid] != dsts[tid - 1]);
      unsigned long long m = __ballot(flag ? 1 : 0);
      if (tid == 0) cnt0s = __popcll(m);
      unsigned long long below = m & (~0ull >> (63 - (tid & 63)));
      segidL[tid] = __popcll(below);
    }
    __syncthreads();
    if (tid < 128) {
      int sg = segidL[tid] - 1 + (tid >= 64 ? cnt0s : 0);
      segidL[tid] = sg;
      if (flag && sg < 32) seg_dstL[sg] = dsts[tid];
    }
    __syncthreads();
    nseg = segidL[127] + 1;
  }

  f4v z4 = {0.f, 0.f, 0.f, 0.f};
  f4v g[2][8];
#pragma unroll
  for (int rt = 0; rt < 2; rt++)
#pragma unroll
  for (int ct = 0; ct < 8; ct++) g[rt][ct] = z4;

  // GEMM1: gate = h2 @ w3
#pragma unroll
  for (int ks = 0; ks < 2; ks++) {
    int k0b = (ks * 32 + l4 * 8) * 2;
    int r0 = wrow0 + l15;
    int r1 = r0 + 16;
    bf8v a0 = *(const bf8v*)(sm_ab + ((r0 * 128 + k0b) ^ ((r0 & 7) << 4)));
    bf8v a1 = *(const bf8v*)(sm_ab + ((r1 * 128 + k0b) ^ ((r1 & 7) << 4)));
#pragma unroll
    for (int ct = 0; ct < 8; ct++) {
      int cc = ct * 16 + l15;
      bf8v b = *(const bf8v*)(sm_ab + 16384 + ((cc * 128 + k0b) ^ ((cc & 7) << 4)));
      g[0][ct] = __builtin_amdgcn_mfma_f32_16x16x32_bf16(a0, b, g[0][ct], 0, 0, 0);
      g[1][ct] = __builtin_amdgcn_mfma_f32_16x16x32_bf16(a1, b, g[1][ct], 0, 0, 0);
    }
  }

  // m = y * (sh@wsh) * gate
  const ushort* yus = (const ushort*)y;
#pragma unroll
  for (int rt = 0; rt < 2; rt++)
#pragma unroll
  for (int e = 0; e < 4; e++) {
    int rl = wrow0 + rt * 16 + l4 * 4 + e;
    int src = 0;
    if (MODE <= 1) src = srcs[rl];
    float4 al = make_float4(0.f, 0.f, 0.f, 0.f);
    if (MODE == 1) al = *(const float4*)(alpha + (size_t)(e0 + rl) * 4);
    float sh9[9];
#pragma unroll
    for (int q = 0; q < 9; q++) sh9[q] = bf2f(shsu[rl * 16 + q]);
#pragma unroll
    for (int ct = 0; ct < 8; ct++) {
      int colL = ct * 16 + l15;
      int col = col0 + colL;
      float swv = 0.f;
#pragma unroll
      for (int q = 0; q < 9; q++) swv = fmaf(sh9[q], bf2f(wshsu[q * 128 + colL]), swv);
      float yv;
      if (MODE == 2) yv = 1.f;
      else yv = (col < DIM) ? bf2f(yus[(size_t)src * DIM + col]) : 0.f;
      float mv = yv * swv * g[rt][ct][e];
      if (MODE == 1) {
        float av = (col < 120) ? al.x : (col < 240) ? al.y : (col < 360) ? al.z : al.w;
        mv *= av;
      }
      if (MODE == 2) mv *= (1.0f / 16.0f);
      g[rt][ct][e] = mv;
    }
  }

  if (MODE == 0) {
    int hA = col0 / 120;
    float aav[8];
#pragma unroll
    for (int ct = 0; ct < 8; ct++) {
      int col = col0 + ct * 16 + l15;
      aav[ct] = (col < DIM) ? aa[col] : 0.f;
    }
#pragma unroll
    for (int rt = 0; rt < 2; rt++)
#pragma unroll
    for (int e = 0; e < 4; e++) {
      float sA = 0.f, sB = 0.f;
#pragma unroll
      for (int ct = 0; ct < 8; ct++) {
        int col = col0 + ct * 16 + l15;
        float mv = g[rt][ct][e];
        float lv = (mv > 0.f) ? mv : 0.2f * mv;
        float c = lv * aav[ct];
        if (col / 120 == hA) sA += c; else sB += c;
      }
#pragma unroll
      for (int off = 1; off < 16; off <<= 1) {
        sA += __shfl_xor(sA, off, 16);
        sB += __shfl_xor(sB, off, 16);
      }
      if (l15 == 0) {
        int row = e0 + wrow0 + rt * 16 + l4 * 4 + e;
        logitsP[((size_t)row * NHEAD + hA) * 2] = sA;
        if (hA < 3) logitsP[((size_t)row * NHEAD + hA + 1) * 2 + 1] = sB;
      }
    }
    if (STOREM) {
      // write M^T [col][edge] bf16 (swizzled) then raw-dump 32KB coalesced
      __syncthreads();
#pragma unroll
      for (int rt = 0; rt < 2; rt++)
#pragma unroll
      for (int ct = 0; ct < 8; ct++) {
        int cc = ct * 16 + l15;
        int ebase = wrow0 + rt * 16 + l4 * 4;
        ushort4 pk;
        pk.x = f2bfu(g[rt][ct][0]); pk.y = f2bfu(g[rt][ct][1]);
        pk.z = f2bfu(g[rt][ct][2]); pk.w = f2bfu(g[rt][ct][3]);
        *(ushort4*)(sm_ab + ((cc * 256 + ebase * 2) ^ ((cc & 7) << 4))) = pk;
      }
      __syncthreads();
      char* gdst = (char*)msgb + (size_t)swzb * 32768;
#pragma unroll
      for (int k = 0; k < 8; k++) {
        int o = tid * 16 + k * 4096;
        *(uint4*)(gdst + o) = *(const uint4*)(sm_ab + o);
      }
    }
    return;
  }

  // overflow fallback (rare): direct atomics
  if (nseg > 32) {
#pragma unroll
    for (int rt = 0; rt < 2; rt++)
#pragma unroll
    for (int e = 0; e < 4; e++) {
      int rl = wrow0 + rt * 16 + l4 * 4 + e;
      int dd = dsts[rl];
#pragma unroll
      for (int ct = 0; ct < 8; ct++) {
        int col = col0 + ct * 16 + l15;
        if (col < DIM) atomicAdd(&outbuf[(size_t)dd * DIM + col], g[rt][ct][e]);
      }
    }
    return;
  }

  // write M^T and GEMM3 segment-sum
  __syncthreads();
#pragma unroll
  for (int rt = 0; rt < 2; rt++)
#pragma unroll
  for (int ct = 0; ct < 8; ct++) {
    int cc = ct * 16 + l15;
    int ebase = wrow0 + rt * 16 + l4 * 4;
    ushort4 pk;
    pk.x = f2bfu(g[rt][ct][0]); pk.y = f2bfu(g[rt][ct][1]);
    pk.z = f2bfu(g[rt][ct][2]); pk.w = f2bfu(g[rt][ct][3]);
    *(ushort4*)(sm_ab + ((cc * 256 + ebase * 2) ^ ((cc & 7) << 4))) = pk;
  }
  __syncthreads();

  f4v p[2][2];
  p[0][0] = z4; p[0][1] = z4; p[1][0] = z4; p[1][1] = z4;
#pragma unroll
  for (int ks = 0; ks < 4; ks++) {
    int k0 = ks * 32 + l4 * 8;
    bf8v a0, a1;
#pragma unroll
    for (int e2 = 0; e2 < 8; e2++) {
      int sg = segidL[k0 + e2];
      a0[e2] = (sg == l15)      ? (short)0x3F80 : (short)0;
      a1[e2] = (sg == l15 + 16) ? (short)0x3F80 : (short)0;
    }
#pragma unroll
    for (int c2 = 0; c2 < 2; c2++) {
      int cc = (wv * 2 + c2) * 16 + l15;
      bf8v bm = *(const bf8v*)(sm_ab + ((cc * 256 + k0 * 2) ^ ((cc & 7) << 4)));
      p[0][c2] = __builtin_amdgcn_mfma_f32_16x16x32_bf16(a0, bm, p[0][c2], 0, 0, 0);
      p[1][c2] = __builtin_amdgcn_mfma_f32_16x16x32_bf16(a1, bm, p[1][c2], 0, 0, 0);
    }
  }
#pragma unroll
  for (int rt = 0; rt < 2; rt++)
#pragma unroll
  for (int c2 = 0; c2 < 2; c2++)
#pragma unroll
  for (int e = 0; e < 4; e++) {
    int seg = rt * 16 + l4 * 4 + e;
    int col = col0 + (wv * 2 + c2) * 16 + l15;
    if (seg < nseg && col < DIM) {
      float v = p[rt][c2][e];
      float* ptr = outbuf + (size_t)seg_dstL[seg] * DIM + col;
      if (seg == 0 || seg == nseg - 1) atomicAdd(ptr, v);
      else if (MODE == 1) *ptr = v;
      else *ptr += v;
    }
  }
}

// ---------------- pass B (fast path): read msgb tile, alpha-weight, segment-sum ----
__global__ __launch_bounds__(256)
void k_aggm(const __hip_bfloat16* __restrict__ msgb, const int* __restrict__ edstp,
            const float* __restrict__ alpha, float* __restrict__ agg)
{
  __shared__ __align__(16) char smM[32768];
  __shared__ __align__(16) float alsq[128][4];
  __shared__ int dsts[128];
  __shared__ int segidL[128];
  __shared__ int seg_dstL[32];
  __shared__ int cnt0s;

  int bid = blockIdx.x;
  int swzb = (bid & 7) * 625 + (bid >> 3);
  int e0   = (swzb >> 2) * 128;
  int col0 = (swzb & 3) * 128;
  int tid = threadIdx.x;
  int lane = tid & 63;
  int wv = tid >> 6;
  int l15 = lane & 15, l4 = lane >> 4;

  if (tid < 128) {
    dsts[tid] = edstp[e0 + tid];
    *(float4*)&alsq[tid][0] = *(const float4*)(alpha + (size_t)(e0 + tid) * 4);
  }
  __syncthreads();

  // segment scan
  int nseg = 0;
  bool flag = false;
  if (tid < 128) {
    flag = (tid == 0) || (dsts[tid] != dsts[tid - 1]);
    unsigned long long m = __ballot(flag ? 1 : 0);
    if (tid == 0) cnt0s = __popcll(m);
    unsigned long long below = m & (~0ull >> (63 - (tid & 63)));
    segidL[tid] = __popcll(below);
  }
  __syncthreads();
  if (tid < 128) {
    int sg = segidL[tid] - 1 + (tid >= 64 ? cnt0s : 0);
    segidL[tid] = sg;
    if (flag && sg < 32) seg_dstL[sg] = dsts[tid];
  }
  __syncthreads();
  nseg = segidL[127] + 1;

  // load tile (raw, swizzle-preserved), alpha-weight, write LDS
  const char* gsrc = (const char*)msgb + (size_t)swzb * 32768;
  uint4 vv[8];
#pragma unroll
  for (int k = 0; k < 8; k++) {
    int o = tid * 16 + k * 4096;
    uint4 v = *(const uint4*)(gsrc + o);
    int cc = o >> 8;
    int col = col0 + cc;
    int h = (col < DIM) ? (col / 120) : 3;
    int be = ((o & 255) ^ ((cc & 7) << 4)) >> 1;   // logical edge base (multiple of 8)
    unsigned w[4] = {v.x, v.y, v.z, v.w};
#pragma unroll
    for (int q = 0; q < 4; q++) {
      float lo = bf2f((ushort)(w[q] & 0xffffu)) * alsq[be + 2*q][h];
      float hi = bf2f((ushort)(w[q] >> 16))     * alsq[be + 2*q + 1][h];
      w[q] = (unsigned)f2bfu(lo) | ((unsigned)f2bfu(hi) << 16);
    }
    vv[k] = make_uint4(w[0], w[1], w[2], w[3]);
    *(uint4*)(smM + o) = vv[k];
  }
  __syncthreads();

  if (nseg > 32) {   // rare fallback: direct atomics from weighted values
#pragma unroll
    for (int k = 0; k < 8; k++) {
      int o = tid * 16 + k * 4096;
      int cc = o >> 8;
      int col = col0 + cc;
      if (col >= DIM) continue;
      int be = ((o & 255) ^ ((cc & 7) << 4)) >> 1;
      unsigned w[4] = {vv[k].x, vv[k].y, vv[k].z, vv[k].w};
#pragma unroll
      for (int q = 0; q < 4; q++) {
        atomicAdd(&agg[(size_t)dsts[be + 2*q]   * DIM + col], bf2f((ushort)(w[q] & 0xffffu)));
        atomicAdd(&agg[(size_t)dsts[be + 2*q+1] * DIM + col], bf2f((ushort)(w[q] >> 16)));
      }
    }
    return;
  }

  f4v z4 = {0.f,0.f,0.f,0.f};
  f4v p[2][2];
  p[0][0] = z4; p[0][1] = z4; p[1][0] = z4; p[1][1] = z4;
#pragma unroll
  for (int ks = 0; ks < 4; ks++) {
    int k0 = ks * 32 + l4 * 8;
    bf8v a0, a1;
#pragma unroll
    for (int e2 = 0; e2 < 8; e2++) {
      int sg = segidL[k0 + e2];
      a0[e2] = (sg == l15)      ? (short)0x3F80 : (short)0;
      a1[e2] = (sg == l15 + 16) ? (short)0x3F80 : (short)0;
    }
#pragma unroll
    for (int c2 = 0; c2 < 2; c2++) {
      int cc = (wv * 2 + c2) * 16 + l15;
      bf8v bm = *(const bf8v*)(smM + ((cc * 256 + k0 * 2) ^ ((cc & 7) << 4)));
      p[0][c2] = __builtin_amdgcn_mfma_f32_16x16x32_bf16(a0, bm, p[0][c2], 0, 0, 0);
      p[1][c2] = __builtin_amdgcn_mfma_f32_16x16x32_bf16(a1, bm, p[1][c2], 0, 0, 0);
    }
  }
#pragma unroll
  for (int rt = 0; rt < 2; rt++)
#pragma unroll
  for (int c2 = 0; c2 < 2; c2++)
#pragma unroll
  for (int e = 0; e < 4; e++) {
    int seg = rt * 16 + l4 * 4 + e;
    int col = col0 + (wv * 2 + c2) * 16 + l15;
    if (seg < nseg && col < DIM) {
      float v = p[rt][c2][e];
      float* ptr = agg + (size_t)seg_dstL[seg] * DIM + col;
      if (seg == 0 || seg == nseg - 1) atomicAdd(ptr, v);
      else *ptr = v;
    }
  }
}

// ---------------- segment softmax (reads 2-slot logit partials) ----------------
__global__ void k_alpha(const int* __restrict__ row_ptr, const float* __restrict__ logitsP,
                        float* __restrict__ alpha)
{
  int i = blockIdx.x * 256 + threadIdx.x;
  if (i >= NN * NHEAD) return;
  int d = i >> 2, h = i & 3;
  int beg = row_ptr[d], end = row_ptr[d+1];
  if (beg == end) return;
  float m = -1e30f;
  for (int j = beg; j < end; j++) {
    float L = logitsP[((size_t)j*NHEAD + h)*2] + logitsP[((size_t)j*NHEAD + h)*2 + 1];
    m = fmaxf(m, L);
  }
  float s = 0.f;
  for (int j = beg; j < end; j++) {
    float L = logitsP[((size_t)j*NHEAD + h)*2] + logitsP[((size_t)j*NHEAD + h)*2 + 1];
    float ex = __expf(L - m);
    alpha[(size_t)j*NHEAD + h] = ex;
    s += ex;
  }
  float inv = 1.f / (s + 1e-9f);
  for (int j = beg; j < end; j++) alpha[(size_t)j*NHEAD + h] *= inv;
}

// ---------------- x init ----------------
__global__ void k_init_x(const int* __restrict__ z, const float* __restrict__ emb,
                         float* __restrict__ x)
{
  int i = blockIdx.x * 256 + threadIdx.x;
  if (i >= NN * DIM) return;
  int n = i / DIM, c = i - n * DIM;
  x[i] = emb[(size_t)z[n]*DIM + c];
}

// ---------------- final scatter ----------------
__global__ void k_scatter(const float* __restrict__ h, const int* __restrict__ batch,
                          float* __restrict__ out)
{
  int i = blockIdx.x * 256 + threadIdx.x;
  if (i >= NN * NS) return;
  int n = i >> 7;
  atomicAdd(&out[(size_t)batch[n]*NS + (i & 127)], h[i] * 0.23570226039551584f);
}

extern "C" void kernel_launch(void* const* d_in, const int* in_sizes, int n_in,
                              void* d_out, int out_size, void* d_ws, size_t ws_size,
                              hipStream_t stream)
{
  const int*   z        = (const int*)  d_in[0];
  const float* pos      = (const float*)d_in[1];
  const int*   batch    = (const int*)  d_in[2];
  const int*   esrc     = (const int*)  d_in[3];
  const int*   edst     = (const int*)  d_in[4];
  const float* atom_emb = (const float*)d_in[5];
  const float* W_deg_sh = (const float*)d_in[6];
  const float* deg_w1   = (const float*)d_in[7];
  const float* deg_w2   = (const float*)d_in[8];
  const float* deg_w3   = (const float*)d_in[9];
  const float* Wv       = (const float*)d_in[10];
  const float* Wsh      = (const float*)d_in[11];
  const float* rad_w1   = (const float*)d_in[12];
  const float* rad_w2   = (const float*)d_in[13];
  const float* rad_w3   = (const float*)d_in[14];
  const float* attn_a   = (const float*)d_in[15];
  const float* Wo       = (const float*)d_in[16];
  const float* ffn_w1   = (const float*)d_in[17];
  const float* ffn_w2   = (const float*)d_in[18];
  const float* head_w1  = (const float*)d_in[19];
  const float* head_w2  = (const float*)d_in[20];
  float* out = (float*)d_out;

  // workspace layout (~96.4 MB base; + 163.8 MB msgb fast path)
  float* x      = (float*)d_ws;                        // [NN][480]
  float* statsb = x      + (size_t)NN * DIM;           // [NN][2]
  float* agg    = statsb + (size_t)NN * 2;             // [NN][480]
  float* distp  = agg    + (size_t)NN * DIM;           // [NE]
  float* logitsP= distp  + (size_t)NE;                 // [NE][4][2]  (reused as head tmp)
  float* alphab = logitsP+ (size_t)NE * NHEAD * 2;     // [NE][4]
  __hip_bfloat16* yb    = (__hip_bfloat16*)(alphab + (size_t)NE * NHEAD);  // [NN][480]
  __hip_bfloat16* h2b   = yb + (size_t)NN * DIM;       // [NE][64]
  __hip_bfloat16* shb16 = h2b + (size_t)NE * FCH;      // [NE][16]
  __hip_bfloat16* w3Tb  = shb16 + (size_t)NE * 16;     // [7][512][64]
  __hip_bfloat16* bigWT = w3Tb + (size_t)7 * 512 * 64; // [24][512][480] + [2][128][128]
  int* cnt      = (int*)(bigWT + (size_t)24*512*480 + 2*128*128);
  int* row_ptr  = cnt + NN;
  int* csr      = row_ptr + NN + 1;
  int* cursor   = csr + NE;
  int* esrcp    = cursor + NN;
  int* edstp    = esrcp + NE;
  __hip_bfloat16* msgb = (__hip_bfloat16*)(edstp + NE);  // [5000][16384] tiles
  float* tmp = logitsP;                                   // head tmp overlays logitsP

  size_t needed = (size_t)((char*)(msgb + (size_t)5000 * 16384) - (char*)d_ws);
  bool fast = ws_size >= needed;

  dim3 b256(256);
  k_zero_int<<<(NN+255)/256, b256, 0, stream>>>(cnt, NN);
  k_count<<<(NE+255)/256, b256, 0, stream>>>(edst, cnt);
  k_scan<<<1, 1024, 0, stream>>>(cnt, row_ptr);
  k_zero_int<<<(NN+255)/256, b256, 0, stream>>>(cursor, NN);
  k_fill<<<(NE+255)/256, b256, 0, stream>>>(edst, row_ptr, cursor, csr);
  k_geom_p<<<(NE+255)/256, b256, 0, stream>>>(pos, esrc, edst, csr, shb16, distp, esrcp, edstp);
  k_prep<<<(7*512*64 + 255)/256, b256, 0, stream>>>(deg_w3, rad_w3, w3Tb);
  k_prepw<<<(24*512*480 + 2*128*128 + 255)/256, b256, 0, stream>>>(Wv, Wo, ffn_w1, ffn_w2,
      head_w1, head_w2, bigWT);
  hipMemsetAsync(logitsP, 0, (size_t)NE * NHEAD * 2 * sizeof(float), stream);

  // degree embedding
  k_radial<<<NE/64, b256, 0, stream>>>(distp, deg_w1, deg_w2, h2b);
  k_init_x<<<(NN*DIM+255)/256, b256, 0, stream>>>(z, atom_emb, x);
  k_msgm<2,0><<<5000, b256, 0, stream>>>(h2b, shb16, esrcp, edstp, w3Tb, W_deg_sh,
      nullptr, nullptr, nullptr, x, nullptr, nullptr);

  dim3 gemm_grid(79, 4);
  dim3 head_grid(79, 1);
  for (int l = 0; l < NL; l++) {
    const float* w1_l  = rad_w1 + (size_t)l*NBASIS*FCH;
    const float* w2_l  = rad_w2 + (size_t)l*FCH*FCH;
    const float* wsh_l = Wsh + (size_t)l*NSH*DIM;
    const float* aa_l  = attn_a + (size_t)l*NHEAD*HDIM;
    const __hip_bfloat16* w3T_l = w3Tb + (size_t)(l+1)*512*64;
    const __hip_bfloat16* WvT_l = bigWT + (size_t)(0+l)*512*480;
    const __hip_bfloat16* WoT_l = bigWT + (size_t)(6+l)*512*480;
    const __hip_bfloat16* F1T_l = bigWT + (size_t)(12+l)*512*480;
    const __hip_bfloat16* F2T_l = bigWT + (size_t)(18+l)*512*480;

    k_stats<<<(NN+3)/4, b256, 0, stream>>>(x, statsb, NN, DIM, DIM);
    k_gemmm<0,0,1,1><<<gemm_grid, b256, 0, stream>>>(x, WvT_l, nullptr, yb, statsb,
        NN, DIM, DIM, DIM);
    k_radial<<<NE/64, b256, 0, stream>>>(distp, w1_l, w2_l, h2b);
    if (fast) {
      k_msgm<0,1><<<5000, b256, 0, stream>>>(h2b, shb16, esrcp, edstp, w3T_l, wsh_l,
          aa_l, yb, nullptr, nullptr, logitsP, msgb);
      k_alpha<<<(NN*NHEAD+255)/256, b256, 0, stream>>>(row_ptr, logitsP, alphab);
      hipMemsetAsync(agg, 0, (size_t)NN * DIM * sizeof(float), stream);
      k_aggm<<<5000, b256, 0, stream>>>(msgb, edstp, alphab, agg);
    } else {
      k_msgm<0,0><<<5000, b256, 0, stream>>>(h2b, shb16, esrcp, edstp, w3T_l, wsh_l,
          aa_l, yb, nullptr, nullptr, logitsP, nullptr);
      k_alpha<<<(NN*NHEAD+255)/256, b256, 0, stream>>>(row_ptr, logitsP, alphab);
      hipMemsetAsync(agg, 0, (size_t)NN * DIM * sizeof(float), stream);
      k_msgm<1,0><<<5000, b256, 0, stream>>>(h2b, shb16, esrcp, edstp, w3T_l, wsh_l,
          nullptr, yb, alphab, agg, nullptr, nullptr);
    }
    k_gemmm<1,0,0,0><<<gemm_grid, b256, 0, stream>>>(agg, WoT_l, x, nullptr, nullptr,
        NN, DIM, DIM, DIM);
    k_stats<<<(NN+3)/4, b256, 0, stream>>>(x, statsb, NN, DIM, DIM);
    k_gemmm<0,1,1,0><<<gemm_grid, b256, 0, stream>>>(x, F1T_l, agg, nullptr, statsb,
        NN, DIM, DIM, DIM);
    k_gemmm<1,0,0,0><<<gemm_grid, b256, 0, stream>>>(agg, F2T_l, x, nullptr, nullptr,
        NN, DIM, DIM, DIM);
  }

  // output head
  const __hip_bfloat16* H1T = bigWT + (size_t)24*512*480;
  const __hip_bfloat16* H2T = H1T + 128*128;
  k_stats<<<(NN+3)/4, b256, 0, stream>>>(x, statsb, NN, NS, DIM);
  k_gemmm<0,1,1,0><<<head_grid, b256, 0, stream>>>(x, H1T, agg, nullptr, statsb,
      NN, NS, NS, DIM);
  k_gemmm<0,0,0,0><<<head_grid, b256, 0, stream>>>(agg, H2T, tmp, nullptr, nullptr,
      NN, NS, NS, NS);
  hipMemsetAsync(d_out, 0, (size_t)NG * NS * sizeof(float), stream);
  k_scatter<<<(NN*NS+255)/256, b256, 0, stream>>>(tmp, batch, out);
}

// Round 12
// 3000.905 us; speedup vs baseline: 1.6321x; 1.2374x over previous
//
#include <hip/hip_runtime.h>
#include <hip/hip_bf16.h>
#include <math.h>

#define NN 10000
#define NE 160000
#define DIM 480
#define NSH 9
#define NBASIS 128
#define NHEAD 4
#define HDIM 120
#define NL 6
#define NG 256
#define NS 128
#define FCH 64
#define CUTOFF 5.0f

typedef __attribute__((ext_vector_type(8))) short bf8v;
typedef __attribute__((ext_vector_type(4))) float f4v;

__device__ __forceinline__ float silu_f(float v) { return v / (1.0f + __expf(-v)); }
__device__ __forceinline__ float bf2f(ushort u) { return __uint_as_float(((unsigned)u) << 16); }
__device__ __forceinline__ ushort f2bfu(float f) {
  __hip_bfloat16 h = __float2bfloat16(f);
  return *reinterpret_cast<ushort*>(&h);
}

struct bf16x4 { __hip_bfloat16 v[4]; };

// ---------------- CSR build ----------------
__global__ void k_zero_int(int* p, int n)
{
  int i = blockIdx.x * 256 + threadIdx.x;
  if (i < n) p[i] = 0;
}

__global__ void k_count(const int* __restrict__ edst, int* __restrict__ cnt)
{
  int e = blockIdx.x * 256 + threadIdx.x;
  if (e < NE) atomicAdd(&cnt[edst[e]], 1);
}

__global__ __launch_bounds__(1024)
void k_scan(const int* __restrict__ cnt, int* __restrict__ row_ptr)
{
  __shared__ int part[1024];
  int tid = threadIdx.x;
  const int per = 10;
  int base = tid * per;
  int s = 0;
  for (int i = 0; i < per; i++) { int idx = base + i; if (idx < NN) s += cnt[idx]; }
  part[tid] = s; __syncthreads();
  for (int off = 1; off < 1024; off <<= 1) {
    int v = (tid >= off) ? part[tid - off] : 0;
    __syncthreads();
    part[tid] += v;
    __syncthreads();
  }
  int run = (tid > 0) ? part[tid - 1] : 0;
  for (int i = 0; i < per; i++) {
    int idx = base + i;
    if (idx < NN) { row_ptr[idx] = run; run += cnt[idx]; }
  }
  if (tid == 1023) row_ptr[NN] = part[1023];
}

__global__ void k_fill(const int* __restrict__ edst, const int* __restrict__ row_ptr,
                       int* __restrict__ cursor, int* __restrict__ csr)
{
  int e = blockIdx.x * 256 + threadIdx.x;
  if (e >= NE) return;
  int d = edst[e];
  int p = atomicAdd(&cursor[d], 1);
  csr[row_ptr[d] + p] = e;
}

// ---------------- geometry in permuted (CSR) order; sh as bf16 [NE][16] padded ----
__global__ void k_geom_p(const float* __restrict__ pos, const int* __restrict__ esrc,
                         const int* __restrict__ edst, const int* __restrict__ csr,
                         __hip_bfloat16* __restrict__ shb, float* __restrict__ distp,
                         int* __restrict__ esrcp, int* __restrict__ edstp)
{
  int j = blockIdx.x * 256 + threadIdx.x;
  if (j >= NE) return;
  int e = csr[j];
  int s = esrc[e], d = edst[e];
  esrcp[j] = s;
  edstp[j] = d;
  float vx = pos[s*3+0] - pos[d*3+0];
  float vy = pos[s*3+1] - pos[d*3+1];
  float vz = pos[s*3+2] - pos[d*3+2];
  float r = sqrtf(vx*vx + vy*vy + vz*vz);
  distp[j] = r;
  float inv = 1.0f / (r + 1e-9f);
  float x = vx*inv, y = vy*inv, z = vz*inv;
  const float s3 = 1.7320508075688772f;
  const float s15 = 3.872983346207417f;
  const float s5 = 2.23606797749979f;
  float sv[9];
  sv[0] = 1.0f;
  sv[1] = s3*x; sv[2] = s3*y; sv[3] = s3*z;
  sv[4] = s15*x*y; sv[5] = s15*y*z; sv[6] = 0.5f*s5*(3.0f*z*z - 1.0f);
  sv[7] = s15*x*z; sv[8] = 0.5f*s15*(x*x - y*y);
  __hip_bfloat16* o = shb + (size_t)j * 16;
#pragma unroll
  for (int q = 0; q < 9; q++) o[q] = __float2bfloat16(sv[q]);
#pragma unroll
  for (int q = 9; q < 16; q++) o[q] = __float2bfloat16(0.f);
}

// ---------------- prep: w3T [7][512][64] bf16 ----------------
__global__ void k_prep(const float* __restrict__ deg_w3, const float* __restrict__ rad_w3,
                       __hip_bfloat16* __restrict__ w3T)
{
  int i = blockIdx.x * 256 + threadIdx.x;
  if (i >= 7*512*64) return;
  int l = i / (512*64); int r = i - l*512*64; int col = r >> 6; int k = r & 63;
  float v = 0.f;
  if (col < DIM) {
    const float* src = (l == 0) ? deg_w3 : rad_w3 + (size_t)(l-1)*FCH*DIM;
    v = src[k*DIM + col];
  }
  w3T[i] = __float2bfloat16(v);
}

// ---------------- prep: node-GEMM weights transposed bf16 ----------------
__global__ void k_prepw(const float* __restrict__ Wv, const float* __restrict__ Wo,
                        const float* __restrict__ f1, const float* __restrict__ f2,
                        const float* __restrict__ h1, const float* __restrict__ h2w,
                        __hip_bfloat16* __restrict__ WT)
{
  int i = blockIdx.x * 256 + threadIdx.x;
  const int big = 24*512*480;
  if (i < big) {
    int m = i / (512*480); int r = i - m*(512*480); int col = r / 480; int k = r - col*480;
    int l = m % 6; int t = m / 6;
    const float* src = (t==0 ? Wv : t==1 ? Wo : t==2 ? f1 : f2) + (size_t)l*DIM*DIM;
    float v = (col < DIM) ? src[k*DIM + col] : 0.f;
    WT[i] = __float2bfloat16(v);
  } else if (i < big + 2*128*128) {
    int j = i - big; int m = j / (128*128); int r = j - m*(128*128);
    int col = r >> 7; int k = r & 127;
    const float* src = m ? h2w : h1;
    WT[i] = __float2bfloat16(src[k*128 + col]);
  }
}

// ---------------- radial MLP -> h2 bf16 [E,64] ----------------
__global__ __launch_bounds__(256)
void k_radial(const float* __restrict__ dist, const float* __restrict__ w1,
              const float* __restrict__ w2, __hip_bfloat16* __restrict__ h2out)
{
  __shared__ float rbs[NBASIS][65];
  __shared__ float wsm[NBASIS * FCH];
  __shared__ float ds[64];
  int tid = threadIdx.x;
  int e0 = blockIdx.x * 64;
  if (tid < 64) ds[tid] = dist[e0 + tid];
  for (int i = tid; i < NBASIS * FCH; i += 256) wsm[i] = w1[i];
  __syncthreads();
  const float invw = (float)NBASIS / CUTOFF;
  for (int i = tid; i < NBASIS * 64; i += 256) {
    int k = i >> 6, e = i & 63;
    float c = k * (CUTOFF / 127.0f);
    float tt = (ds[e] - c) * invw;
    rbs[k][e] = __expf(-0.5f * tt * tt);
  }
  __syncthreads();
  int ty = tid >> 4, tx = tid & 15;
  float acc1[4][4] = {};
  for (int k = 0; k < NBASIS; k++) {
    float b[4];
#pragma unroll
    for (int j = 0; j < 4; j++) b[j] = wsm[k*FCH + tx*4 + j];
#pragma unroll
    for (int i = 0; i < 4; i++) {
      float a = rbs[k][ty*4 + i];
#pragma unroll
      for (int j = 0; j < 4; j++) acc1[i][j] = fmaf(a, b[j], acc1[i][j]);
    }
  }
  __syncthreads();
#pragma unroll
  for (int i = 0; i < 4; i++)
#pragma unroll
    for (int j = 0; j < 4; j++)
      rbs[tx*4 + j][ty*4 + i] = silu_f(acc1[i][j]);
  for (int i = tid; i < FCH * FCH; i += 256) wsm[i] = w2[i];
  __syncthreads();
  float acc2[4][4] = {};
  for (int k = 0; k < FCH; k++) {
    float b[4];
#pragma unroll
    for (int j = 0; j < 4; j++) b[j] = wsm[k*FCH + tx*4 + j];
#pragma unroll
    for (int i = 0; i < 4; i++) {
      float a = rbs[k][ty*4 + i];
#pragma unroll
      for (int j = 0; j < 4; j++) acc2[i][j] = fmaf(a, b[j], acc2[i][j]);
    }
  }
#pragma unroll
  for (int i = 0; i < 4; i++) {
    int e = e0 + ty*4 + i;
    bf16x4 p;
#pragma unroll
    for (int j = 0; j < 4; j++) p.v[j] = __float2bfloat16(silu_f(acc2[i][j]));
    *(bf16x4*)(h2out + (size_t)e*FCH + tx*4) = p;
  }
}

// ---------------- per-row LN stats (mu, rstd) ----------------
__global__ __launch_bounds__(256)
void k_stats(const float* __restrict__ in, float* __restrict__ st,
             int n, int cols, int stride)
{
  int row = blockIdx.x * 4 + (threadIdx.x >> 6);
  int lane = threadIdx.x & 63;
  if (row >= n) return;
  const float* r = in + (size_t)row * stride;
  float s = 0.f, ss = 0.f;
  for (int c = lane; c < cols; c += 64) { float v = r[c]; s += v; ss += v*v; }
  for (int off = 32; off > 0; off >>= 1) { s += __shfl_down(s, off); ss += __shfl_down(ss, off); }
  if (lane == 0) {
    float mu = s / cols;
    float var = ss / cols - mu * mu;
    st[row*2]   = mu;
    st[row*2+1] = rsqrtf(fmaxf(var, 0.f) + 1e-5f);
  }
}

// ---------------- MFMA node GEMM ----------------
template<int ADD, int SILU, int LNA, int OBF16>
__global__ __launch_bounds__(256)
void k_gemmm(const float* __restrict__ A, const __hip_bfloat16* __restrict__ BT,
             float* __restrict__ C, __hip_bfloat16* __restrict__ Cb,
             const float* __restrict__ st, int M, int K, int Nc, int lda)
{
  __shared__ __align__(16) char smA[8192];
  __shared__ __align__(16) char smB[8192];
  __shared__ float smu[128], srs[128];
  int tid = threadIdx.x;
  int lane = tid & 63;
  int wv = tid >> 6;
  int l15 = lane & 15, l4 = lane >> 4;
  int row0 = blockIdx.x * 128;
  int col0 = blockIdx.y * 128;
  if (LNA && tid < 128) {
    int gr = row0 + tid;
    float m2 = 0.f, r2 = 1.f;
    if (gr < M) { m2 = st[gr*2]; r2 = st[gr*2+1]; }
    smu[tid] = m2; srs[tid] = r2;
  }
  f4v z4 = {0.f,0.f,0.f,0.f};
  f4v acc[2][8];
#pragma unroll
  for (int rt = 0; rt < 2; rt++)
#pragma unroll
  for (int ct = 0; ct < 8; ct++) acc[rt][ct] = z4;

  int sr = tid >> 1;
  int skq = (tid & 1) * 16;
  for (int k0 = 0; k0 < K; k0 += 32) {
    __syncthreads();
    {
      int grow = row0 + sr;
      float f[16];
      if (grow < M) {
        const float* ap = A + (size_t)grow * lda + k0 + skq;
#pragma unroll
        for (int q = 0; q < 4; q++) {
          float4 v = *(const float4*)(ap + q*4);
          f[q*4+0]=v.x; f[q*4+1]=v.y; f[q*4+2]=v.z; f[q*4+3]=v.w;
        }
      } else {
#pragma unroll
        for (int q = 0; q < 16; q++) f[q] = 0.f;
      }
      if (LNA) {
        float mu = smu[sr], rs = srs[sr];
#pragma unroll
        for (int q = 0; q < 16; q++) f[q] = (f[q] - mu) * rs;
      }
      unsigned u[8];
#pragma unroll
      for (int q = 0; q < 8; q++)
        u[q] = (unsigned)f2bfu(f[2*q]) | ((unsigned)f2bfu(f[2*q+1]) << 16);
      int base = sr*64 + skq*2;
      *(uint4*)(smA + (base ^ ((sr&7)<<4))) = make_uint4(u[0],u[1],u[2],u[3]);
      *(uint4*)(smA + ((base+16) ^ ((sr&7)<<4))) = make_uint4(u[4],u[5],u[6],u[7]);
    }
    {
      const ushort* bp = (const ushort*)BT + (size_t)(col0 + sr) * K + k0 + skq;
      uint4 v0 = *(const uint4*)bp;
      uint4 v1 = *(const uint4*)(bp + 8);
      int base = sr*64 + skq*2;
      *(uint4*)(smB + (base ^ ((sr&7)<<4))) = v0;
      *(uint4*)(smB + ((base+16) ^ ((sr&7)<<4))) = v1;
    }
    __syncthreads();
    int r0 = wv*32 + l15, r1 = r0 + 16;
    bf8v a0 = *(const bf8v*)(smA + ((r0*64 + l4*16) ^ ((r0&7)<<4)));
    bf8v a1 = *(const bf8v*)(smA + ((r1*64 + l4*16) ^ ((r1&7)<<4)));
#pragma unroll
    for (int ct = 0; ct < 8; ct++) {
      int cc = ct*16 + l15;
      bf8v b = *(const bf8v*)(smB + ((cc*64 + l4*16) ^ ((cc&7)<<4)));
      acc[0][ct] = __builtin_amdgcn_mfma_f32_16x16x32_bf16(a0, b, acc[0][ct], 0, 0, 0);
      acc[1][ct] = __builtin_amdgcn_mfma_f32_16x16x32_bf16(a1, b, acc[1][ct], 0, 0, 0);
    }
  }
#pragma unroll
  for (int rt = 0; rt < 2; rt++)
#pragma unroll
  for (int ct = 0; ct < 8; ct++)
#pragma unroll
  for (int e = 0; e < 4; e++) {
    int row = row0 + wv*32 + rt*16 + l4*4 + e;
    int col = col0 + ct*16 + l15;
    if (row < M && col < Nc) {
      float v = acc[rt][ct][e];
      if (SILU) v = silu_f(v);
      if (OBF16) Cb[(size_t)row * Nc + col] = __float2bfloat16(v);
      else {
        float* p = C + (size_t)row * Nc + col;
        if (ADD) *p += v; else *p = v;
      }
    }
  }
}

// ---------------- MFMA msg kernel: 64 edges x 128 cols per block ----------------
// MODE 0: logits partials (plain stores); STOREM=1 dumps swizzled M^T tile (16KB).
// MODE 1: alpha-weighted segment-sum -> agg (fallback). MODE 2: (1/16) -> x.
// Grid 10000 = 8 XCD x 1250; 64-edge tile keeps VGPR <= 128 (round 11: 156 VGPR
// pinned occupancy at 2 waves/SIMD).
template<int MODE, int STOREM>
__global__ __launch_bounds__(256)
void k_msgm(const __hip_bfloat16* __restrict__ h2, const __hip_bfloat16* __restrict__ shb,
            const int* __restrict__ esrcp, const int* __restrict__ edstp,
            const __hip_bfloat16* __restrict__ w3T, const float* __restrict__ wsh,
            const float* __restrict__ aa, const __hip_bfloat16* __restrict__ y,
            const float* __restrict__ alpha, float* __restrict__ outbuf,
            float* __restrict__ logitsP, __hip_bfloat16* __restrict__ msgb)
{
  __shared__ __align__(16) char sm_ab[24576];  // h2s[64][64]bf16(8K) + w3T[128][64]bf16(16K); MT reuses [0,16K)
  __shared__ __align__(16) ushort shsu[64*16]; // 2KB
  __shared__ ushort wshsu[9*128];              // 2.25KB
  __shared__ int srcs[(MODE<=1)?64:1];
  __shared__ int dsts[(MODE>=1)?64:1];
  __shared__ int segidL[(MODE>=1)?64:1];
  __shared__ int seg_dstL[(MODE>=1)?32:1];

  int bid = blockIdx.x;
  int swzb = (bid & 7) * 1250 + (bid >> 3);    // 10000 = 8 XCD chunks x 1250
  int e0   = (swzb >> 2) * 64;
  int col0 = (swzb & 3) * 128;
  int tid = threadIdx.x;
  int lane = tid & 63;
  int wv = tid >> 6;
  int l15 = lane & 15, l4 = lane >> 4;
  int wrow0 = wv * 16;

  for (int c = tid; c < 512; c += 256) {       // h2: 64 rows x 128B
    int r = c >> 3, s = c & 7;
    uint4 v = *(const uint4*)((const char*)h2 + (size_t)(e0 + r) * 128 + s * 16);
    *(uint4*)(sm_ab + ((r * 128 + s * 16) ^ ((r & 7) << 4))) = v;
  }
  for (int c = tid; c < 1024; c += 256) {      // w3T: 128 cols x 128B at offset 8192
    int r = c >> 3, s = c & 7;
    uint4 v = *(const uint4*)((const char*)w3T + (size_t)(col0 + r) * 128 + s * 16);
    *(uint4*)(sm_ab + 8192 + ((r * 128 + s * 16) ^ ((r & 7) << 4))) = v;
  }
  if (tid < 128) {                             // sh: 64 rows x 32B
    int el = tid >> 1, half = tid & 1;
    *(uint4*)(shsu + el * 16 + half * 8) =
        *(const uint4*)((const ushort*)shb + (size_t)(e0 + el) * 16 + half * 8);
  }
  for (int idx = tid; idx < 9 * 128; idx += 256) {
    int q = idx >> 7, c = idx & 127;
    int col = col0 + c;
    wshsu[idx] = (col < DIM) ? f2bfu(wsh[q * DIM + col]) : (ushort)0;
  }
  if (tid < 64) {
    if (MODE <= 1) srcs[tid] = esrcp[e0 + tid];
    if (MODE >= 1) dsts[tid] = edstp[e0 + tid];
  }
  __syncthreads();

  // single-wave ballot segment scan over 64 dst-sorted edges
  int nseg = 0;
  if (MODE >= 1) {
    if (tid < 64) {
      bool flag = (tid == 0) || (dsts[tid] != dsts[tid - 1]);
      unsigned long long m = __ballot(flag ? 1 : 0);
      unsigned long long below = m & (~0ull >> (63 - tid));
      int sg = __popcll(below) - 1;
      segidL[tid] = sg;
      if (flag && sg < 32) seg_dstL[sg] = dsts[tid];
    }
    __syncthreads();
    nseg = segidL[63] + 1;
  }

  f4v z4 = {0.f, 0.f, 0.f, 0.f};
  f4v g[8];
#pragma unroll
  for (int ct = 0; ct < 8; ct++) g[ct] = z4;

  // GEMM1: gate = h2 @ w3  (wave wv owns rows [wv*16, wv*16+16))
#pragma unroll
  for (int ks = 0; ks < 2; ks++) {
    int k0b = (ks * 32 + l4 * 8) * 2;
    int r0 = wrow0 + l15;
    bf8v a0 = *(const bf8v*)(sm_ab + ((r0 * 128 + k0b) ^ ((r0 & 7) << 4)));
#pragma unroll
    for (int ct = 0; ct < 8; ct++) {
      int cc = ct * 16 + l15;
      bf8v b = *(const bf8v*)(sm_ab + 8192 + ((cc * 128 + k0b) ^ ((cc & 7) << 4)));
      g[ct] = __builtin_amdgcn_mfma_f32_16x16x32_bf16(a0, b, g[ct], 0, 0, 0);
    }
  }

  // m = y * (sh@wsh) * gate (+ alpha / scale)
  const ushort* yus = (const ushort*)y;
#pragma unroll
  for (int e = 0; e < 4; e++) {
    int rl = wrow0 + l4 * 4 + e;
    int src = 0;
    if (MODE <= 1) src = srcs[rl];
    float4 al = make_float4(0.f, 0.f, 0.f, 0.f);
    if (MODE == 1) al = *(const float4*)(alpha + (size_t)(e0 + rl) * 4);
    float sh9[9];
#pragma unroll
    for (int q = 0; q < 9; q++) sh9[q] = bf2f(shsu[rl * 16 + q]);
#pragma unroll
    for (int ct = 0; ct < 8; ct++) {
      int colL = ct * 16 + l15;
      int col = col0 + colL;
      float swv = 0.f;
#pragma unroll
      for (int q = 0; q < 9; q++) swv = fmaf(sh9[q], bf2f(wshsu[q * 128 + colL]), swv);
      float yv;
      if (MODE == 2) yv = 1.f;
      else yv = (col < DIM) ? bf2f(yus[(size_t)src * DIM + col]) : 0.f;
      float mv = yv * swv * g[ct][e];
      if (MODE == 1) {
        float av = (col < 120) ? al.x : (col < 240) ? al.y : (col < 360) ? al.z : al.w;
        mv *= av;
      }
      if (MODE == 2) mv *= (1.0f / 16.0f);
      g[ct][e] = mv;
    }
  }

  if (MODE == 0) {
    int hA = col0 / 120;
    float aav[8];
#pragma unroll
    for (int ct = 0; ct < 8; ct++) {
      int col = col0 + ct * 16 + l15;
      aav[ct] = (col < DIM) ? aa[col] : 0.f;
    }
#pragma unroll
    for (int e = 0; e < 4; e++) {
      float sA = 0.f, sB = 0.f;
#pragma unroll
      for (int ct = 0; ct < 8; ct++) {
        int col = col0 + ct * 16 + l15;
        float mv = g[ct][e];
        float lv = (mv > 0.f) ? mv : 0.2f * mv;
        float c = lv * aav[ct];
        if (col / 120 == hA) sA += c; else sB += c;
      }
#pragma unroll
      for (int off = 1; off < 16; off <<= 1) {
        sA += __shfl_xor(sA, off, 16);
        sB += __shfl_xor(sB, off, 16);
      }
      if (l15 == 0) {
        int row = e0 + wrow0 + l4 * 4 + e;
        logitsP[((size_t)row * NHEAD + hA) * 2] = sA;
        if (hA < 3) logitsP[((size_t)row * NHEAD + hA + 1) * 2 + 1] = sB;
      }
    }
    if (STOREM) {
      __syncthreads();
#pragma unroll
      for (int ct = 0; ct < 8; ct++) {
        int cc = ct * 16 + l15;
        int ebase = wrow0 + l4 * 4;
        ushort4 pk;
        pk.x = f2bfu(g[ct][0]); pk.y = f2bfu(g[ct][1]);
        pk.z = f2bfu(g[ct][2]); pk.w = f2bfu(g[ct][3]);
        *(ushort4*)(sm_ab + ((cc * 128 + ebase * 2) ^ ((cc & 7) << 4))) = pk;
      }
      __syncthreads();
      char* gdst = (char*)msgb + (size_t)swzb * 16384;
#pragma unroll
      for (int k = 0; k < 4; k++) {
        int o = tid * 16 + k * 4096;
        *(uint4*)(gdst + o) = *(const uint4*)(sm_ab + o);
      }
    }
    return;
  }

  if (nseg > 32) {   // rare fallback
#pragma unroll
    for (int e = 0; e < 4; e++) {
      int rl = wrow0 + l4 * 4 + e;
      int dd = dsts[rl];
#pragma unroll
      for (int ct = 0; ct < 8; ct++) {
        int col = col0 + ct * 16 + l15;
        if (col < DIM) atomicAdd(&outbuf[(size_t)dd * DIM + col], g[ct][e]);
      }
    }
    return;
  }

  // write M^T [col][edge] bf16 into sm_ab[0,16K) then GEMM3 segment-sum
  __syncthreads();
#pragma unroll
  for (int ct = 0; ct < 8; ct++) {
    int cc = ct * 16 + l15;
    int ebase = wrow0 + l4 * 4;
    ushort4 pk;
    pk.x = f2bfu(g[ct][0]); pk.y = f2bfu(g[ct][1]);
    pk.z = f2bfu(g[ct][2]); pk.w = f2bfu(g[ct][3]);
    *(ushort4*)(sm_ab + ((cc * 128 + ebase * 2) ^ ((cc & 7) << 4))) = pk;
  }
  __syncthreads();

  f4v p[2][2];
  p[0][0] = z4; p[0][1] = z4; p[1][0] = z4; p[1][1] = z4;
#pragma unroll
  for (int ks = 0; ks < 2; ks++) {
    int k0 = ks * 32 + l4 * 8;
    bf8v a0, a1;
#pragma unroll
    for (int e2 = 0; e2 < 8; e2++) {
      int sg = segidL[k0 + e2];
      a0[e2] = (sg == l15)      ? (short)0x3F80 : (short)0;
      a1[e2] = (sg == l15 + 16) ? (short)0x3F80 : (short)0;
    }
#pragma unroll
    for (int c2 = 0; c2 < 2; c2++) {
      int cc = (wv * 2 + c2) * 16 + l15;
      bf8v bm = *(const bf8v*)(sm_ab + ((cc * 128 + k0 * 2) ^ ((cc & 7) << 4)));
      p[0][c2] = __builtin_amdgcn_mfma_f32_16x16x32_bf16(a0, bm, p[0][c2], 0, 0, 0);
      p[1][c2] = __builtin_amdgcn_mfma_f32_16x16x32_bf16(a1, bm, p[1][c2], 0, 0, 0);
    }
  }
#pragma unroll
  for (int rt = 0; rt < 2; rt++)
#pragma unroll
  for (int c2 = 0; c2 < 2; c2++)
#pragma unroll
  for (int e = 0; e < 4; e++) {
    int seg = rt * 16 + l4 * 4 + e;
    int col = col0 + (wv * 2 + c2) * 16 + l15;
    if (seg < nseg && col < DIM) {
      float v = p[rt][c2][e];
      float* ptr = outbuf + (size_t)seg_dstL[seg] * DIM + col;
      if (seg == 0 || seg == nseg - 1) atomicAdd(ptr, v);
      else if (MODE == 1) *ptr = v;
      else *ptr += v;
    }
  }
}

// ---------------- pass B (fast path): read msgb tile, alpha-weight, segment-sum ----
__global__ __launch_bounds__(256)
void k_aggm(const __hip_bfloat16* __restrict__ msgb, const int* __restrict__ edstp,
            const float* __restrict__ alpha, float* __restrict__ agg)
{
  __shared__ __align__(16) char smM[16384];
  __shared__ __align__(16) float alsq[64][4];
  __shared__ int dsts[64];
  __shared__ int segidL[64];
  __shared__ int seg_dstL[32];

  int bid = blockIdx.x;
  int swzb = (bid & 7) * 1250 + (bid >> 3);
  int e0   = (swzb >> 2) * 64;
  int col0 = (swzb & 3) * 128;
  int tid = threadIdx.x;
  int lane = tid & 63;
  int wv = tid >> 6;
  int l15 = lane & 15, l4 = lane >> 4;

  if (tid < 64) {
    dsts[tid] = edstp[e0 + tid];
    *(float4*)&alsq[tid][0] = *(const float4*)(alpha + (size_t)(e0 + tid) * 4);
  }
  __syncthreads();

  int nseg = 0;
  if (tid < 64) {
    bool flag = (tid == 0) || (dsts[tid] != dsts[tid - 1]);
    unsigned long long m = __ballot(flag ? 1 : 0);
    unsigned long long below = m & (~0ull >> (63 - tid));
    int sg = __popcll(below) - 1;
    segidL[tid] = sg;
    if (flag && sg < 32) seg_dstL[sg] = dsts[tid];
  }
  __syncthreads();
  nseg = segidL[63] + 1;

  const char* gsrc = (const char*)msgb + (size_t)swzb * 16384;
  uint4 vv[4];
#pragma unroll
  for (int k = 0; k < 4; k++) {
    int o = tid * 16 + k * 4096;
    uint4 v = *(const uint4*)(gsrc + o);
    int cc = o >> 7;
    int col = col0 + cc;
    int h = (col < DIM) ? (col / 120) : 3;
    int be = ((o & 127) ^ ((cc & 7) << 4)) >> 1;
    unsigned w[4] = {v.x, v.y, v.z, v.w};
#pragma unroll
    for (int q = 0; q < 4; q++) {
      float lo = bf2f((ushort)(w[q] & 0xffffu)) * alsq[be + 2*q][h];
      float hi = bf2f((ushort)(w[q] >> 16))     * alsq[be + 2*q + 1][h];
      w[q] = (unsigned)f2bfu(lo) | ((unsigned)f2bfu(hi) << 16);
    }
    vv[k] = make_uint4(w[0], w[1], w[2], w[3]);
    *(uint4*)(smM + o) = vv[k];
  }
  __syncthreads();

  if (nseg > 32) {
#pragma unroll
    for (int k = 0; k < 4; k++) {
      int o = tid * 16 + k * 4096;
      int cc = o >> 7;
      int col = col0 + cc;
      if (col >= DIM) continue;
      int be = ((o & 127) ^ ((cc & 7) << 4)) >> 1;
      unsigned w[4] = {vv[k].x, vv[k].y, vv[k].z, vv[k].w};
#pragma unroll
      for (int q = 0; q < 4; q++) {
        atomicAdd(&agg[(size_t)dsts[be + 2*q]   * DIM + col], bf2f((ushort)(w[q] & 0xffffu)));
        atomicAdd(&agg[(size_t)dsts[be + 2*q+1] * DIM + col], bf2f((ushort)(w[q] >> 16)));
      }
    }
    return;
  }

  f4v z4 = {0.f,0.f,0.f,0.f};
  f4v p[2][2];
  p[0][0] = z4; p[0][1] = z4; p[1][0] = z4; p[1][1] = z4;
#pragma unroll
  for (int ks = 0; ks < 2; ks++) {
    int k0 = ks * 32 + l4 * 8;
    bf8v a0, a1;
#pragma unroll
    for (int e2 = 0; e2 < 8; e2++) {
      int sg = segidL[k0 + e2];
      a0[e2] = (sg == l15)      ? (short)0x3F80 : (short)0;
      a1[e2] = (sg == l15 + 16) ? (short)0x3F80 : (short)0;
    }
#pragma unroll
    for (int c2 = 0; c2 < 2; c2++) {
      int cc = (wv * 2 + c2) * 16 + l15;
      bf8v bm = *(const bf8v*)(smM + ((cc * 128 + k0 * 2) ^ ((cc & 7) << 4)));
      p[0][c2] = __builtin_amdgcn_mfma_f32_16x16x32_bf16(a0, bm, p[0][c2], 0, 0, 0);
      p[1][c2] = __builtin_amdgcn_mfma_f32_16x16x32_bf16(a1, bm, p[1][c2], 0, 0, 0);
    }
  }
#pragma unroll
  for (int rt = 0; rt < 2; rt++)
#pragma unroll
  for (int c2 = 0; c2 < 2; c2++)
#pragma unroll
  for (int e = 0; e < 4; e++) {
    int seg = rt * 16 + l4 * 4 + e;
    int col = col0 + (wv * 2 + c2) * 16 + l15;
    if (seg < nseg && col < DIM) {
      float v = p[rt][c2][e];
      float* ptr = agg + (size_t)seg_dstL[seg] * DIM + col;
      if (seg == 0 || seg == nseg - 1) atomicAdd(ptr, v);
      else *ptr = v;
    }
  }
}

// ---------------- segment softmax (reads 2-slot logit partials) ----------------
__global__ void k_alpha(const int* __restrict__ row_ptr, const float* __restrict__ logitsP,
                        float* __restrict__ alpha)
{
  int i = blockIdx.x * 256 + threadIdx.x;
  if (i >= NN * NHEAD) return;
  int d = i >> 2, h = i & 3;
  int beg = row_ptr[d], end = row_ptr[d+1];
  if (beg == end) return;
  float m = -1e30f;
  for (int j = beg; j < end; j++) {
    float L = logitsP[((size_t)j*NHEAD + h)*2] + logitsP[((size_t)j*NHEAD + h)*2 + 1];
    m = fmaxf(m, L);
  }
  float s = 0.f;
  for (int j = beg; j < end; j++) {
    float L = logitsP[((size_t)j*NHEAD + h)*2] + logitsP[((size_t)j*NHEAD + h)*2 + 1];
    float ex = __expf(L - m);
    alpha[(size_t)j*NHEAD + h] = ex;
    s += ex;
  }
  float inv = 1.f / (s + 1e-9f);
  for (int j = beg; j < end; j++) alpha[(size_t)j*NHEAD + h] *= inv;
}

// ---------------- x init ----------------
__global__ void k_init_x(const int* __restrict__ z, const float* __restrict__ emb,
                         float* __restrict__ x)
{
  int i = blockIdx.x * 256 + threadIdx.x;
  if (i >= NN * DIM) return;
  int n = i / DIM, c = i - n * DIM;
  x[i] = emb[(size_t)z[n]*DIM + c];
}

// ---------------- final scatter ----------------
__global__ void k_scatter(const float* __restrict__ h, const int* __restrict__ batch,
                          float* __restrict__ out)
{
  int i = blockIdx.x * 256 + threadIdx.x;
  if (i >= NN * NS) return;
  int n = i >> 7;
  atomicAdd(&out[(size_t)batch[n]*NS + (i & 127)], h[i] * 0.23570226039551584f);
}

extern "C" void kernel_launch(void* const* d_in, const int* in_sizes, int n_in,
                              void* d_out, int out_size, void* d_ws, size_t ws_size,
                              hipStream_t stream)
{
  const int*   z        = (const int*)  d_in[0];
  const float* pos      = (const float*)d_in[1];
  const int*   batch    = (const int*)  d_in[2];
  const int*   esrc     = (const int*)  d_in[3];
  const int*   edst     = (const int*)  d_in[4];
  const float* atom_emb = (const float*)d_in[5];
  const float* W_deg_sh = (const float*)d_in[6];
  const float* deg_w1   = (const float*)d_in[7];
  const float* deg_w2   = (const float*)d_in[8];
  const float* deg_w3   = (const float*)d_in[9];
  const float* Wv       = (const float*)d_in[10];
  const float* Wsh      = (const float*)d_in[11];
  const float* rad_w1   = (const float*)d_in[12];
  const float* rad_w2   = (const float*)d_in[13];
  const float* rad_w3   = (const float*)d_in[14];
  const float* attn_a   = (const float*)d_in[15];
  const float* Wo       = (const float*)d_in[16];
  const float* ffn_w1   = (const float*)d_in[17];
  const float* ffn_w2   = (const float*)d_in[18];
  const float* head_w1  = (const float*)d_in[19];
  const float* head_w2  = (const float*)d_in[20];
  float* out = (float*)d_out;

  // workspace layout (~96.4 MB base; + 163.8 MB msgb fast path)
  float* x      = (float*)d_ws;
  float* statsb = x      + (size_t)NN * DIM;
  float* agg    = statsb + (size_t)NN * 2;
  float* distp  = agg    + (size_t)NN * DIM;
  float* logitsP= distp  + (size_t)NE;
  float* alphab = logitsP+ (size_t)NE * NHEAD * 2;
  __hip_bfloat16* yb    = (__hip_bfloat16*)(alphab + (size_t)NE * NHEAD);
  __hip_bfloat16* h2b   = yb + (size_t)NN * DIM;
  __hip_bfloat16* shb16 = h2b + (size_t)NE * FCH;
  __hip_bfloat16* w3Tb  = shb16 + (size_t)NE * 16;
  __hip_bfloat16* bigWT = w3Tb + (size_t)7 * 512 * 64;
  int* cnt      = (int*)(bigWT + (size_t)24*512*480 + 2*128*128);
  int* row_ptr  = cnt + NN;
  int* csr      = row_ptr + NN + 1;
  int* cursor   = csr + NE;
  int* esrcp    = cursor + NN;
  int* edstp    = esrcp + NE;
  __hip_bfloat16* msgb = (__hip_bfloat16*)(edstp + NE);  // [10000][8192] bf16 tiles (16KB each)
  float* tmp = logitsP;

  size_t needed = (size_t)((char*)msgb + (size_t)10000 * 16384 - (char*)d_ws);
  bool fast = ws_size >= needed;

  dim3 b256(256);
  k_zero_int<<<(NN+255)/256, b256, 0, stream>>>(cnt, NN);
  k_count<<<(NE+255)/256, b256, 0, stream>>>(edst, cnt);
  k_scan<<<1, 1024, 0, stream>>>(cnt, row_ptr);
  k_zero_int<<<(NN+255)/256, b256, 0, stream>>>(cursor, NN);
  k_fill<<<(NE+255)/256, b256, 0, stream>>>(edst, row_ptr, cursor, csr);
  k_geom_p<<<(NE+255)/256, b256, 0, stream>>>(pos, esrc, edst, csr, shb16, distp, esrcp, edstp);
  k_prep<<<(7*512*64 + 255)/256, b256, 0, stream>>>(deg_w3, rad_w3, w3Tb);
  k_prepw<<<(24*512*480 + 2*128*128 + 255)/256, b256, 0, stream>>>(Wv, Wo, ffn_w1, ffn_w2,
      head_w1, head_w2, bigWT);
  hipMemsetAsync(logitsP, 0, (size_t)NE * NHEAD * 2 * sizeof(float), stream);

  // degree embedding
  k_radial<<<NE/64, b256, 0, stream>>>(distp, deg_w1, deg_w2, h2b);
  k_init_x<<<(NN*DIM+255)/256, b256, 0, stream>>>(z, atom_emb, x);
  k_msgm<2,0><<<10000, b256, 0, stream>>>(h2b, shb16, esrcp, edstp, w3Tb, W_deg_sh,
      nullptr, nullptr, nullptr, x, nullptr, nullptr);

  dim3 gemm_grid(79, 4);
  dim3 head_grid(79, 1);
  for (int l = 0; l < NL; l++) {
    const float* w1_l  = rad_w1 + (size_t)l*NBASIS*FCH;
    const float* w2_l  = rad_w2 + (size_t)l*FCH*FCH;
    const float* wsh_l = Wsh + (size_t)l*NSH*DIM;
    const float* aa_l  = attn_a + (size_t)l*NHEAD*HDIM;
    const __hip_bfloat16* w3T_l = w3Tb + (size_t)(l+1)*512*64;
    const __hip_bfloat16* WvT_l = bigWT + (size_t)(0+l)*512*480;
    const __hip_bfloat16* WoT_l = bigWT + (size_t)(6+l)*512*480;
    const __hip_bfloat16* F1T_l = bigWT + (size_t)(12+l)*512*480;
    const __hip_bfloat16* F2T_l = bigWT + (size_t)(18+l)*512*480;

    k_stats<<<(NN+3)/4, b256, 0, stream>>>(x, statsb, NN, DIM, DIM);
    k_gemmm<0,0,1,1><<<gemm_grid, b256, 0, stream>>>(x, WvT_l, nullptr, yb, statsb,
        NN, DIM, DIM, DIM);
    k_radial<<<NE/64, b256, 0, stream>>>(distp, w1_l, w2_l, h2b);
    if (fast) {
      k_msgm<0,1><<<10000, b256, 0, stream>>>(h2b, shb16, esrcp, edstp, w3T_l, wsh_l,
          aa_l, yb, nullptr, nullptr, logitsP, msgb);
      k_alpha<<<(NN*NHEAD+255)/256, b256, 0, stream>>>(row_ptr, logitsP, alphab);
      hipMemsetAsync(agg, 0, (size_t)NN * DIM * sizeof(float), stream);
      k_aggm<<<10000, b256, 0, stream>>>(msgb, edstp, alphab, agg);
    } else {
      k_msgm<0,0><<<10000, b256, 0, stream>>>(h2b, shb16, esrcp, edstp, w3T_l, wsh_l,
          aa_l, yb, nullptr, nullptr, logitsP, nullptr);
      k_alpha<<<(NN*NHEAD+255)/256, b256, 0, stream>>>(row_ptr, logitsP, alphab);
      hipMemsetAsync(agg, 0, (size_t)NN * DIM * sizeof(float), stream);
      k_msgm<1,0><<<10000, b256, 0, stream>>>(h2b, shb16, esrcp, edstp, w3T_l, wsh_l,
          nullptr, yb, alphab, agg, nullptr, nullptr);
    }
    k_gemmm<1,0,0,0><<<gemm_grid, b256, 0, stream>>>(agg, WoT_l, x, nullptr, nullptr,
        NN, DIM, DIM, DIM);
    k_stats<<<(NN+3)/4, b256, 0, stream>>>(x, statsb, NN, DIM, DIM);
    k_gemmm<0,1,1,0><<<gemm_grid, b256, 0, stream>>>(x, F1T_l, agg, nullptr, statsb,
        NN, DIM, DIM, DIM);
    k_gemmm<1,0,0,0><<<gemm_grid, b256, 0, stream>>>(agg, F2T_l, x, nullptr, nullptr,
        NN, DIM, DIM, DIM);
  }

  // output head
  const __hip_bfloat16* H1T = bigWT + (size_t)24*512*480;
  const __hip_bfloat16* H2T = H1T + 128*128;
  k_stats<<<(NN+3)/4, b256, 0, stream>>>(x, statsb, NN, NS, DIM);
  k_gemmm<0,1,1,0><<<head_grid, b256, 0, stream>>>(x, H1T, agg, nullptr, statsb,
      NN, NS, NS, DIM);
  k_gemmm<0,0,0,0><<<head_grid, b256, 0, stream>>>(agg, H2T, tmp, nullptr, nullptr,
      NN, NS, NS, NS);
  hipMemsetAsync(d_out, 0, (size_t)NG * NS * sizeof(float), stream);
  k_scatter<<<(NN*NS+255)/256, b256, 0, stream>>>(tmp, batch, out);
}

// Round 14
// 2591.022 us; speedup vs baseline: 1.8902x; 1.1582x over previous
//
#include <hip/hip_runtime.h>
#include <hip/hip_bf16.h>
#include <math.h>

#define NN 10000
#define NE 160000
#define DIM 480
#define NSH 9
#define NBASIS 128
#define NHEAD 4
#define HDIM 120
#define NL 6
#define NG 256
#define NS 128
#define FCH 64
#define CUTOFF 5.0f

typedef __attribute__((ext_vector_type(8))) short bf8v;
typedef __attribute__((ext_vector_type(4))) float f4v;

__device__ __forceinline__ float silu_f(float v) { return v / (1.0f + __expf(-v)); }
__device__ __forceinline__ float bf2f(ushort u) { return __uint_as_float(((unsigned)u) << 16); }
__device__ __forceinline__ ushort f2bfu(float f) {
  __hip_bfloat16 h = __float2bfloat16(f);
  return *reinterpret_cast<ushort*>(&h);
}

struct bf16x4 { __hip_bfloat16 v[4]; };

// ---------------- CSR build ----------------
__global__ void k_zero_int(int* p, int n)
{
  int i = blockIdx.x * 256 + threadIdx.x;
  if (i < n) p[i] = 0;
}

__global__ void k_count(const int* __restrict__ edst, int* __restrict__ cnt)
{
  int e = blockIdx.x * 256 + threadIdx.x;
  if (e < NE) atomicAdd(&cnt[edst[e]], 1);
}

__global__ __launch_bounds__(1024)
void k_scan(const int* __restrict__ cnt, int* __restrict__ row_ptr)
{
  __shared__ int part[1024];
  int tid = threadIdx.x;
  const int per = 10;
  int base = tid * per;
  int s = 0;
  for (int i = 0; i < per; i++) { int idx = base + i; if (idx < NN) s += cnt[idx]; }
  part[tid] = s; __syncthreads();
  for (int off = 1; off < 1024; off <<= 1) {
    int v = (tid >= off) ? part[tid - off] : 0;
    __syncthreads();
    part[tid] += v;
    __syncthreads();
  }
  int run = (tid > 0) ? part[tid - 1] : 0;
  for (int i = 0; i < per; i++) {
    int idx = base + i;
    if (idx < NN) { row_ptr[idx] = run; run += cnt[idx]; }
  }
  if (tid == 1023) row_ptr[NN] = part[1023];
}

__global__ void k_fill(const int* __restrict__ edst, const int* __restrict__ row_ptr,
                       int* __restrict__ cursor, int* __restrict__ csr)
{
  int e = blockIdx.x * 256 + threadIdx.x;
  if (e >= NE) return;
  int d = edst[e];
  int p = atomicAdd(&cursor[d], 1);
  csr[row_ptr[d] + p] = e;
}

// ---------------- geometry in permuted (CSR) order; sh as bf16 [NE][16] padded ----
__global__ void k_geom_p(const float* __restrict__ pos, const int* __restrict__ esrc,
                         const int* __restrict__ edst, const int* __restrict__ csr,
                         __hip_bfloat16* __restrict__ shb, float* __restrict__ distp,
                         int* __restrict__ esrcp, int* __restrict__ edstp)
{
  int j = blockIdx.x * 256 + threadIdx.x;
  if (j >= NE) return;
  int e = csr[j];
  int s = esrc[e], d = edst[e];
  esrcp[j] = s;
  edstp[j] = d;
  float vx = pos[s*3+0] - pos[d*3+0];
  float vy = pos[s*3+1] - pos[d*3+1];
  float vz = pos[s*3+2] - pos[d*3+2];
  float r = sqrtf(vx*vx + vy*vy + vz*vz);
  distp[j] = r;
  float inv = 1.0f / (r + 1e-9f);
  float x = vx*inv, y = vy*inv, z = vz*inv;
  const float s3 = 1.7320508075688772f;
  const float s15 = 3.872983346207417f;
  const float s5 = 2.23606797749979f;
  float sv[9];
  sv[0] = 1.0f;
  sv[1] = s3*x; sv[2] = s3*y; sv[3] = s3*z;
  sv[4] = s15*x*y; sv[5] = s15*y*z; sv[6] = 0.5f*s5*(3.0f*z*z - 1.0f);
  sv[7] = s15*x*z; sv[8] = 0.5f*s15*(x*x - y*y);
  __hip_bfloat16* o = shb + (size_t)j * 16;
#pragma unroll
  for (int q = 0; q < 9; q++) o[q] = __float2bfloat16(sv[q]);
#pragma unroll
  for (int q = 9; q < 16; q++) o[q] = __float2bfloat16(0.f);
}

// ---------------- prep: w3T [7][512][64] + wshT [7][512][32] bf16 ----------------
__global__ void k_prep(const float* __restrict__ deg_w3, const float* __restrict__ rad_w3,
                       const float* __restrict__ W_deg_sh, const float* __restrict__ Wsh,
                       __hip_bfloat16* __restrict__ w3T, __hip_bfloat16* __restrict__ wshT)
{
  int i = blockIdx.x * 256 + threadIdx.x;
  if (i < 7*512*64) {
    int l = i / (512*64); int r = i - l*512*64; int col = r >> 6; int k = r & 63;
    float v = 0.f;
    if (col < DIM) {
      const float* src = (l == 0) ? deg_w3 : rad_w3 + (size_t)(l-1)*FCH*DIM;
      v = src[k*DIM + col];
    }
    w3T[i] = __float2bfloat16(v);
  }
  int j = i - 7*512*64;
  if (j >= 0 && j < 7*512*32) {
    int l = j / (512*32); int r = j - l*512*32; int col = r >> 5; int q = r & 31;
    float v = 0.f;
    if (col < DIM && q < 9) {
      const float* src = (l == 0) ? W_deg_sh : Wsh + (size_t)(l-1)*NSH*DIM;
      v = src[q*DIM + col];
    }
    wshT[j] = __float2bfloat16(v);
  }
}

// ---------------- prep: node-GEMM weights transposed bf16 ----------------
__global__ void k_prepw(const float* __restrict__ Wv, const float* __restrict__ Wo,
                        const float* __restrict__ f1, const float* __restrict__ f2,
                        const float* __restrict__ h1, const float* __restrict__ h2w,
                        __hip_bfloat16* __restrict__ WT)
{
  int i = blockIdx.x * 256 + threadIdx.x;
  const int big = 24*512*480;
  if (i < big) {
    int m = i / (512*480); int r = i - m*(512*480); int col = r / 480; int k = r - col*480;
    int l = m % 6; int t = m / 6;
    const float* src = (t==0 ? Wv : t==1 ? Wo : t==2 ? f1 : f2) + (size_t)l*DIM*DIM;
    float v = (col < DIM) ? src[k*DIM + col] : 0.f;
    WT[i] = __float2bfloat16(v);
  } else if (i < big + 2*128*128) {
    int j = i - big; int m = j / (128*128); int r = j - m*(128*128);
    int col = r >> 7; int k = r & 127;
    const float* src = m ? h2w : h1;
    WT[i] = __float2bfloat16(src[k*128 + col]);
  }
}

// ---------------- radial MLP -> h2 bf16 [E,64] ----------------
__global__ __launch_bounds__(256)
void k_radial(const float* __restrict__ dist, const float* __restrict__ w1,
              const float* __restrict__ w2, __hip_bfloat16* __restrict__ h2out)
{
  __shared__ float rbs[NBASIS][65];
  __shared__ float wsm[NBASIS * FCH];
  __shared__ float ds[64];
  int tid = threadIdx.x;
  int e0 = blockIdx.x * 64;
  if (tid < 64) ds[tid] = dist[e0 + tid];
  for (int i = tid; i < NBASIS * FCH; i += 256) wsm[i] = w1[i];
  __syncthreads();
  const float invw = (float)NBASIS / CUTOFF;
  for (int i = tid; i < NBASIS * 64; i += 256) {
    int k = i >> 6, e = i & 63;
    float c = k * (CUTOFF / 127.0f);
    float tt = (ds[e] - c) * invw;
    rbs[k][e] = __expf(-0.5f * tt * tt);
  }
  __syncthreads();
  int ty = tid >> 4, tx = tid & 15;
  float acc1[4][4] = {};
  for (int k = 0; k < NBASIS; k++) {
    float b[4];
#pragma unroll
    for (int j = 0; j < 4; j++) b[j] = wsm[k*FCH + tx*4 + j];
#pragma unroll
    for (int i = 0; i < 4; i++) {
      float a = rbs[k][ty*4 + i];
#pragma unroll
      for (int j = 0; j < 4; j++) acc1[i][j] = fmaf(a, b[j], acc1[i][j]);
    }
  }
  __syncthreads();
#pragma unroll
  for (int i = 0; i < 4; i++)
#pragma unroll
    for (int j = 0; j < 4; j++)
      rbs[tx*4 + j][ty*4 + i] = silu_f(acc1[i][j]);
  for (int i = tid; i < FCH * FCH; i += 256) wsm[i] = w2[i];
  __syncthreads();
  float acc2[4][4] = {};
  for (int k = 0; k < FCH; k++) {
    float b[4];
#pragma unroll
    for (int j = 0; j < 4; j++) b[j] = wsm[k*FCH + tx*4 + j];
#pragma unroll
    for (int i = 0; i < 4; i++) {
      float a = rbs[k][ty*4 + i];
#pragma unroll
      for (int j = 0; j < 4; j++) acc2[i][j] = fmaf(a, b[j], acc2[i][j]);
    }
  }
#pragma unroll
  for (int i = 0; i < 4; i++) {
    int e = e0 + ty*4 + i;
    bf16x4 p;
#pragma unroll
    for (int j = 0; j < 4; j++) p.v[j] = __float2bfloat16(silu_f(acc2[i][j]));
    *(bf16x4*)(h2out + (size_t)e*FCH + tx*4) = p;
  }
}

// ---------------- per-row LN stats (mu, rstd) ----------------
__global__ __launch_bounds__(256)
void k_stats(const float* __restrict__ in, float* __restrict__ st,
             int n, int cols, int stride)
{
  int row = blockIdx.x * 4 + (threadIdx.x >> 6);
  int lane = threadIdx.x & 63;
  if (row >= n) return;
  const float* r = in + (size_t)row * stride;
  float s = 0.f, ss = 0.f;
  for (int c = lane; c < cols; c += 64) { float v = r[c]; s += v; ss += v*v; }
  for (int off = 32; off > 0; off >>= 1) { s += __shfl_down(s, off); ss += __shfl_down(ss, off); }
  if (lane == 0) {
    float mu = s / cols;
    float var = ss / cols - mu * mu;
    st[row*2]   = mu;
    st[row*2+1] = rsqrtf(fmaxf(var, 0.f) + 1e-5f);
  }
}

// ---------------- MFMA node GEMM: 64 rows x 128 cols per block ----------------
template<int ADD, int SILU, int LNA, int OBF16>
__global__ __launch_bounds__(256)
void k_gemmm(const float* __restrict__ A, const __hip_bfloat16* __restrict__ BT,
             float* __restrict__ C, __hip_bfloat16* __restrict__ Cb,
             const float* __restrict__ st, int M, int K, int Nc, int lda)
{
  __shared__ __align__(16) char smA[4096];   // [64][32] bf16, XOR-swizzled
  __shared__ __align__(16) char smB[8192];   // [128][32] bf16
  __shared__ float smu[64], srs[64];
  int tid = threadIdx.x;
  int lane = tid & 63;
  int wv = tid >> 6;
  int l15 = lane & 15, l4 = lane >> 4;
  int row0 = blockIdx.x * 64;
  int col0 = blockIdx.y * 128;
  if (LNA && tid < 64) {
    int gr = row0 + tid;
    float m2 = 0.f, r2 = 1.f;
    if (gr < M) { m2 = st[gr*2]; r2 = st[gr*2+1]; }
    smu[tid] = m2; srs[tid] = r2;
  }
  f4v z4 = {0.f,0.f,0.f,0.f};
  f4v acc[8];
#pragma unroll
  for (int ct = 0; ct < 8; ct++) acc[ct] = z4;

  int arow = tid >> 2, aq = tid & 3;   // A: row, 8-float quarter
  int bcol = tid >> 1, bh = tid & 1;   // B: col, 16-elem half
  for (int k0 = 0; k0 < K; k0 += 32) {
    __syncthreads();
    {   // stage A (f32 -> LN -> bf16): 8 floats/thread
      int grow = row0 + arow;
      float f[8];
      if (grow < M) {
        const float* ap = A + (size_t)grow * lda + k0 + aq*8;
        float4 v0 = *(const float4*)ap;
        float4 v1 = *(const float4*)(ap + 4);
        f[0]=v0.x; f[1]=v0.y; f[2]=v0.z; f[3]=v0.w;
        f[4]=v1.x; f[5]=v1.y; f[6]=v1.z; f[7]=v1.w;
      } else {
#pragma unroll
        for (int q = 0; q < 8; q++) f[q] = 0.f;
      }
      if (LNA) {
        float mu = smu[arow], rs = srs[arow];
#pragma unroll
        for (int q = 0; q < 8; q++) f[q] = (f[q] - mu) * rs;
      }
      unsigned u[4];
#pragma unroll
      for (int q = 0; q < 4; q++)
        u[q] = (unsigned)f2bfu(f[2*q]) | ((unsigned)f2bfu(f[2*q+1]) << 16);
      int base = arow*64 + aq*16;
      *(uint4*)(smA + (base ^ ((arow&7)<<4))) = make_uint4(u[0],u[1],u[2],u[3]);
    }
    {   // stage B from pre-transposed bf16: 16 elems/thread
      const ushort* bp = (const ushort*)BT + (size_t)(col0 + bcol) * K + k0 + bh*16;
      uint4 v0 = *(const uint4*)bp;
      uint4 v1 = *(const uint4*)(bp + 8);
      int base = bcol*64 + bh*32;
      *(uint4*)(smB + (base ^ ((bcol&7)<<4))) = v0;
      *(uint4*)(smB + ((base+16) ^ ((bcol&7)<<4))) = v1;
    }
    __syncthreads();
    int r0 = wv*16 + l15;
    bf8v a0 = *(const bf8v*)(smA + ((r0*64 + l4*16) ^ ((r0&7)<<4)));
#pragma unroll
    for (int ct = 0; ct < 8; ct++) {
      int cc = ct*16 + l15;
      bf8v b = *(const bf8v*)(smB + ((cc*64 + l4*16) ^ ((cc&7)<<4)));
      acc[ct] = __builtin_amdgcn_mfma_f32_16x16x32_bf16(a0, b, acc[ct], 0, 0, 0);
    }
  }
#pragma unroll
  for (int ct = 0; ct < 8; ct++)
#pragma unroll
  for (int e = 0; e < 4; e++) {
    int row = row0 + wv*16 + l4*4 + e;
    int col = col0 + ct*16 + l15;
    if (row < M && col < Nc) {
      float v = acc[ct][e];
      if (SILU) v = silu_f(v);
      if (OBF16) Cb[(size_t)row * Nc + col] = __float2bfloat16(v);
      else {
        float* p = C + (size_t)row * Nc + col;
        if (ADD) *p += v; else *p = v;
      }
    }
  }
}

// ---------------- MFMA msg kernel: 64 edges x 128 cols per block ----------------
// MODE 0: logits partials (plain stores); STOREM=1 dumps swizzled M^T tile (16KB).
// MODE 1: alpha-weighted segment-sum -> agg (fallback). MODE 2: (1/16) -> x.
// sw = sh @ wsh via MFMA (K=32 zero-padded); fragment layout identical to GEMM1.
// Round-13 crash fix: sm_wsh staged as 512 chunks (r=c>>2,q=c&3, r<128);
// sm_sh staged as 256 chunks with q>=2 zeroed (k=16..31 zero-pad).
template<int MODE, int STOREM>
__global__ __launch_bounds__(256)
void k_msgm(const __hip_bfloat16* __restrict__ h2, const __hip_bfloat16* __restrict__ shb,
            const int* __restrict__ esrcp, const int* __restrict__ edstp,
            const __hip_bfloat16* __restrict__ w3T, const __hip_bfloat16* __restrict__ wshT,
            const float* __restrict__ aa, const __hip_bfloat16* __restrict__ y,
            const float* __restrict__ alpha, float* __restrict__ outbuf,
            float* __restrict__ logitsP, __hip_bfloat16* __restrict__ msgb)
{
  __shared__ __align__(16) char sm_ab[24576];  // h2s[64][64](8K) + w3T[128][64](16K); MT reuses [0,16K)
  __shared__ __align__(16) char sm_sh[4096];   // sh [64][32] bf16 (zero-padded)
  __shared__ __align__(16) char sm_wsh[8192];  // wshT [128][32] bf16
  __shared__ int srcs[(MODE<=1)?64:1];
  __shared__ int dsts[(MODE>=1)?64:1];
  __shared__ int segidL[(MODE>=1)?64:1];
  __shared__ int seg_dstL[(MODE>=1)?32:1];

  int bid = blockIdx.x;
  int swzb = (bid & 7) * 1250 + (bid >> 3);    // 10000 = 8 XCD chunks x 1250
  int e0   = (swzb >> 2) * 64;
  int col0 = (swzb & 3) * 128;
  int tid = threadIdx.x;
  int lane = tid & 63;
  int wv = tid >> 6;
  int l15 = lane & 15, l4 = lane >> 4;
  int wrow0 = wv * 16;

  for (int c = tid; c < 512; c += 256) {       // h2: 64 rows x 128B
    int r = c >> 3, s = c & 7;
    uint4 v = *(const uint4*)((const char*)h2 + (size_t)(e0 + r) * 128 + s * 16);
    *(uint4*)(sm_ab + ((r * 128 + s * 16) ^ ((r & 7) << 4))) = v;
  }
  for (int c = tid; c < 1024; c += 256) {      // w3T: 128 cols x 128B at 8192
    int r = c >> 3, s = c & 7;
    uint4 v = *(const uint4*)((const char*)w3T + (size_t)(col0 + r) * 128 + s * 16);
    *(uint4*)(sm_ab + 8192 + ((r * 128 + s * 16) ^ ((r & 7) << 4))) = v;
  }
  {                                            // sh: 64 rows x 64B (q>=2 zero)
    int r = tid >> 2, q = tid & 3;
    uint4 v = make_uint4(0u, 0u, 0u, 0u);
    if (q < 2)
      v = *(const uint4*)((const ushort*)shb + (size_t)(e0 + r) * 16 + q * 8);
    *(uint4*)(sm_sh + ((r * 64 + q * 16) ^ ((r & 7) << 4))) = v;
  }
  for (int c = tid; c < 512; c += 256) {       // wshT: 128 cols x 64B
    int r = c >> 2, q = c & 3;
    uint4 v = *(const uint4*)((const ushort*)wshT + (size_t)(col0 + r) * 32 + q * 8);
    *(uint4*)(sm_wsh + ((r * 64 + q * 16) ^ ((r & 7) << 4))) = v;
  }
  if (tid < 64) {
    if (MODE <= 1) srcs[tid] = esrcp[e0 + tid];
    if (MODE >= 1) dsts[tid] = edstp[e0 + tid];
  }
  __syncthreads();

  // single-wave ballot segment scan
  int nseg = 0;
  if (MODE >= 1) {
    if (tid < 64) {
      bool flag = (tid == 0) || (dsts[tid] != dsts[tid - 1]);
      unsigned long long m = __ballot(flag ? 1 : 0);
      unsigned long long below = m & (~0ull >> (63 - tid));
      int sg = __popcll(below) - 1;
      segidL[tid] = sg;
      if (flag && sg < 32) seg_dstL[sg] = dsts[tid];
    }
    __syncthreads();
    nseg = segidL[63] + 1;
  }

  f4v z4 = {0.f, 0.f, 0.f, 0.f};
  f4v g[8];
#pragma unroll
  for (int ct = 0; ct < 8; ct++) g[ct] = z4;

  // GEMM1: gate = h2 @ w3
#pragma unroll
  for (int ks = 0; ks < 2; ks++) {
    int k0b = (ks * 32 + l4 * 8) * 2;
    int r0 = wrow0 + l15;
    bf8v a0 = *(const bf8v*)(sm_ab + ((r0 * 128 + k0b) ^ ((r0 & 7) << 4)));
#pragma unroll
    for (int ct = 0; ct < 8; ct++) {
      int cc = ct * 16 + l15;
      bf8v b = *(const bf8v*)(sm_ab + 8192 + ((cc * 128 + k0b) ^ ((cc & 7) << 4)));
      g[ct] = __builtin_amdgcn_mfma_f32_16x16x32_bf16(a0, b, g[ct], 0, 0, 0);
    }
  }

  // epilogue: m = y * (sh@wsh via MFMA) * gate  (+ alpha / scale)
  const ushort* yus = (const ushort*)y;
  int srcs4[4];
  float4 al4[4];
#pragma unroll
  for (int e = 0; e < 4; e++) {
    int rl = wrow0 + l4 * 4 + e;
    if (MODE <= 1) srcs4[e] = srcs[rl];
    if (MODE == 1) al4[e] = *(const float4*)(alpha + (size_t)(e0 + rl) * 4);
  }
  {
    int r0 = wrow0 + l15;
    bf8v shA = *(const bf8v*)(sm_sh + ((r0 * 64 + l4 * 16) ^ ((r0 & 7) << 4)));
#pragma unroll
    for (int ct = 0; ct < 8; ct++) {
      int cc = ct * 16 + l15;
      int col = col0 + cc;
      bf8v wB = *(const bf8v*)(sm_wsh + ((cc * 64 + l4 * 16) ^ ((cc & 7) << 4)));
      f4v sw4 = __builtin_amdgcn_mfma_f32_16x16x32_bf16(shA, wB, z4, 0, 0, 0);
#pragma unroll
      for (int e = 0; e < 4; e++) {
        float yv;
        if (MODE == 2) yv = 1.f;
        else yv = (col < DIM) ? bf2f(yus[(size_t)srcs4[e] * DIM + col]) : 0.f;
        float mv = yv * sw4[e] * g[ct][e];
        if (MODE == 1) {
          float av = (col < 120) ? al4[e].x : (col < 240) ? al4[e].y
                   : (col < 360) ? al4[e].z : al4[e].w;
          mv *= av;
        }
        if (MODE == 2) mv *= (1.0f / 16.0f);
        g[ct][e] = mv;
      }
    }
  }

  if (MODE == 0) {
    int hA = col0 / 120;
    float aav[8];
#pragma unroll
    for (int ct = 0; ct < 8; ct++) {
      int col = col0 + ct * 16 + l15;
      aav[ct] = (col < DIM) ? aa[col] : 0.f;
    }
#pragma unroll
    for (int e = 0; e < 4; e++) {
      float sA = 0.f, sB = 0.f;
#pragma unroll
      for (int ct = 0; ct < 8; ct++) {
        int col = col0 + ct * 16 + l15;
        float mv = g[ct][e];
        float lv = (mv > 0.f) ? mv : 0.2f * mv;
        float c = lv * aav[ct];
        if (col / 120 == hA) sA += c; else sB += c;
      }
#pragma unroll
      for (int off = 1; off < 16; off <<= 1) {
        sA += __shfl_xor(sA, off, 16);
        sB += __shfl_xor(sB, off, 16);
      }
      if (l15 == 0) {
        int row = e0 + wrow0 + l4 * 4 + e;
        logitsP[((size_t)row * NHEAD + hA) * 2] = sA;
        if (hA < 3) logitsP[((size_t)row * NHEAD + hA + 1) * 2 + 1] = sB;
      }
    }
    if (STOREM) {
      __syncthreads();
#pragma unroll
      for (int ct = 0; ct < 8; ct++) {
        int cc = ct * 16 + l15;
        int ebase = wrow0 + l4 * 4;
        ushort4 pk;
        pk.x = f2bfu(g[ct][0]); pk.y = f2bfu(g[ct][1]);
        pk.z = f2bfu(g[ct][2]); pk.w = f2bfu(g[ct][3]);
        *(ushort4*)(sm_ab + ((cc * 128 + ebase * 2) ^ ((cc & 7) << 4))) = pk;
      }
      __syncthreads();
      char* gdst = (char*)msgb + (size_t)swzb * 16384;
#pragma unroll
      for (int k = 0; k < 4; k++) {
        int o = tid * 16 + k * 4096;
        *(uint4*)(gdst + o) = *(const uint4*)(sm_ab + o);
      }
    }
    return;
  }

  if (nseg > 32) {   // rare fallback
#pragma unroll
    for (int e = 0; e < 4; e++) {
      int rl = wrow0 + l4 * 4 + e;
      int dd = dsts[rl];
#pragma unroll
      for (int ct = 0; ct < 8; ct++) {
        int col = col0 + ct * 16 + l15;
        if (col < DIM) atomicAdd(&outbuf[(size_t)dd * DIM + col], g[ct][e]);
      }
    }
    return;
  }

  // write M^T then GEMM3 segment-sum
  __syncthreads();
#pragma unroll
  for (int ct = 0; ct < 8; ct++) {
    int cc = ct * 16 + l15;
    int ebase = wrow0 + l4 * 4;
    ushort4 pk;
    pk.x = f2bfu(g[ct][0]); pk.y = f2bfu(g[ct][1]);
    pk.z = f2bfu(g[ct][2]); pk.w = f2bfu(g[ct][3]);
    *(ushort4*)(sm_ab + ((cc * 128 + ebase * 2) ^ ((cc & 7) << 4))) = pk;
  }
  __syncthreads();

  f4v p[2][2];
  p[0][0] = z4; p[0][1] = z4; p[1][0] = z4; p[1][1] = z4;
#pragma unroll
  for (int ks = 0; ks < 2; ks++) {
    int k0 = ks * 32 + l4 * 8;
    bf8v a0, a1;
#pragma unroll
    for (int e2 = 0; e2 < 8; e2++) {
      int sg = segidL[k0 + e2];
      a0[e2] = (sg == l15)      ? (short)0x3F80 : (short)0;
      a1[e2] = (sg == l15 + 16) ? (short)0x3F80 : (short)0;
    }
#pragma unroll
    for (int c2 = 0; c2 < 2; c2++) {
      int cc = (wv * 2 + c2) * 16 + l15;
      bf8v bm = *(const bf8v*)(sm_ab + ((cc * 128 + k0 * 2) ^ ((cc & 7) << 4)));
      p[0][c2] = __builtin_amdgcn_mfma_f32_16x16x32_bf16(a0, bm, p[0][c2], 0, 0, 0);
      p[1][c2] = __builtin_amdgcn_mfma_f32_16x16x32_bf16(a1, bm, p[1][c2], 0, 0, 0);
    }
  }
#pragma unroll
  for (int rt = 0; rt < 2; rt++)
#pragma unroll
  for (int c2 = 0; c2 < 2; c2++)
#pragma unroll
  for (int e = 0; e < 4; e++) {
    int seg = rt * 16 + l4 * 4 + e;
    int col = col0 + (wv * 2 + c2) * 16 + l15;
    if (seg < nseg && col < DIM) {
      float v = p[rt][c2][e];
      float* ptr = outbuf + (size_t)seg_dstL[seg] * DIM + col;
      if (seg == 0 || seg == nseg - 1) atomicAdd(ptr, v);
      else if (MODE == 1) *ptr = v;
      else *ptr += v;
    }
  }
}

// ---------------- pass B (fast path): read msgb tile, alpha-weight, segment-sum ----
__global__ __launch_bounds__(256)
void k_aggm(const __hip_bfloat16* __restrict__ msgb, const int* __restrict__ edstp,
            const float* __restrict__ alpha, float* __restrict__ agg)
{
  __shared__ __align__(16) char smM[16384];
  __shared__ __align__(16) float alsq[64][4];
  __shared__ int dsts[64];
  __shared__ int segidL[64];
  __shared__ int seg_dstL[32];

  int bid = blockIdx.x;
  int swzb = (bid & 7) * 1250 + (bid >> 3);
  int e0   = (swzb >> 2) * 64;
  int col0 = (swzb & 3) * 128;
  int tid = threadIdx.x;
  int lane = tid & 63;
  int wv = tid >> 6;
  int l15 = lane & 15, l4 = lane >> 4;

  if (tid < 64) {
    dsts[tid] = edstp[e0 + tid];
    *(float4*)&alsq[tid][0] = *(const float4*)(alpha + (size_t)(e0 + tid) * 4);
  }
  __syncthreads();

  int nseg = 0;
  if (tid < 64) {
    bool flag = (tid == 0) || (dsts[tid] != dsts[tid - 1]);
    unsigned long long m = __ballot(flag ? 1 : 0);
    unsigned long long below = m & (~0ull >> (63 - tid));
    int sg = __popcll(below) - 1;
    segidL[tid] = sg;
    if (flag && sg < 32) seg_dstL[sg] = dsts[tid];
  }
  __syncthreads();
  nseg = segidL[63] + 1;

  const char* gsrc = (const char*)msgb + (size_t)swzb * 16384;
  uint4 vv[4];
#pragma unroll
  for (int k = 0; k < 4; k++) {
    int o = tid * 16 + k * 4096;
    uint4 v = *(const uint4*)(gsrc + o);
    int cc = o >> 7;
    int col = col0 + cc;
    int h = (col < DIM) ? (col / 120) : 3;
    int be = ((o & 127) ^ ((cc & 7) << 4)) >> 1;
    unsigned w[4] = {v.x, v.y, v.z, v.w};
#pragma unroll
    for (int q = 0; q < 4; q++) {
      float lo = bf2f((ushort)(w[q] & 0xffffu)) * alsq[be + 2*q][h];
      float hi = bf2f((ushort)(w[q] >> 16))     * alsq[be + 2*q + 1][h];
      w[q] = (unsigned)f2bfu(lo) | ((unsigned)f2bfu(hi) << 16);
    }
    vv[k] = make_uint4(w[0], w[1], w[2], w[3]);
    *(uint4*)(smM + o) = vv[k];
  }
  __syncthreads();

  if (nseg > 32) {
#pragma unroll
    for (int k = 0; k < 4; k++) {
      int o = tid * 16 + k * 4096;
      int cc = o >> 7;
      int col = col0 + cc;
      if (col >= DIM) continue;
      int be = ((o & 127) ^ ((cc & 7) << 4)) >> 1;
      unsigned w[4] = {vv[k].x, vv[k].y, vv[k].z, vv[k].w};
#pragma unroll
      for (int q = 0; q < 4; q++) {
        atomicAdd(&agg[(size_t)dsts[be + 2*q]   * DIM + col], bf2f((ushort)(w[q] & 0xffffu)));
        atomicAdd(&agg[(size_t)dsts[be + 2*q+1] * DIM + col], bf2f((ushort)(w[q] >> 16)));
      }
    }
    return;
  }

  f4v z4 = {0.f,0.f,0.f,0.f};
  f4v p[2][2];
  p[0][0] = z4; p[0][1] = z4; p[1][0] = z4; p[1][1] = z4;
#pragma unroll
  for (int ks = 0; ks < 2; ks++) {
    int k0 = ks * 32 + l4 * 8;
    bf8v a0, a1;
#pragma unroll
    for (int e2 = 0; e2 < 8; e2++) {
      int sg = segidL[k0 + e2];
      a0[e2] = (sg == l15)      ? (short)0x3F80 : (short)0;
      a1[e2] = (sg == l15 + 16) ? (short)0x3F80 : (short)0;
    }
#pragma unroll
    for (int c2 = 0; c2 < 2; c2++) {
      int cc = (wv * 2 + c2) * 16 + l15;
      bf8v bm = *(const bf8v*)(smM + ((cc * 128 + k0 * 2) ^ ((cc & 7) << 4)));
      p[0][c2] = __builtin_amdgcn_mfma_f32_16x16x32_bf16(a0, bm, p[0][c2], 0, 0, 0);
      p[1][c2] = __builtin_amdgcn_mfma_f32_16x16x32_bf16(a1, bm, p[1][c2], 0, 0, 0);
    }
  }
#pragma unroll
  for (int rt = 0; rt < 2; rt++)
#pragma unroll
  for (int c2 = 0; c2 < 2; c2++)
#pragma unroll
  for (int e = 0; e < 4; e++) {
    int seg = rt * 16 + l4 * 4 + e;
    int col = col0 + (wv * 2 + c2) * 16 + l15;
    if (seg < nseg && col < DIM) {
      float v = p[rt][c2][e];
      float* ptr = agg + (size_t)seg_dstL[seg] * DIM + col;
      if (seg == 0 || seg == nseg - 1) atomicAdd(ptr, v);
      else *ptr = v;
    }
  }
}

// ---------------- segment softmax ----------------
__global__ void k_alpha(const int* __restrict__ row_ptr, const float* __restrict__ logitsP,
                        float* __restrict__ alpha)
{
  int i = blockIdx.x * 256 + threadIdx.x;
  if (i >= NN * NHEAD) return;
  int d = i >> 2, h = i & 3;
  int beg = row_ptr[d], end = row_ptr[d+1];
  if (beg == end) return;
  float m = -1e30f;
  for (int j = beg; j < end; j++) {
    float L = logitsP[((size_t)j*NHEAD + h)*2] + logitsP[((size_t)j*NHEAD + h)*2 + 1];
    m = fmaxf(m, L);
  }
  float s = 0.f;
  for (int j = beg; j < end; j++) {
    float L = logitsP[((size_t)j*NHEAD + h)*2] + logitsP[((size_t)j*NHEAD + h)*2 + 1];
    float ex = __expf(L - m);
    alpha[(size_t)j*NHEAD + h] = ex;
    s += ex;
  }
  float inv = 1.f / (s + 1e-9f);
  for (int j = beg; j < end; j++) alpha[(size_t)j*NHEAD + h] *= inv;
}

// ---------------- x init ----------------
__global__ void k_init_x(const int* __restrict__ z, const float* __restrict__ emb,
                         float* __restrict__ x)
{
  int i = blockIdx.x * 256 + threadIdx.x;
  if (i >= NN * DIM) return;
  int n = i / DIM, c = i - n * DIM;
  x[i] = emb[(size_t)z[n]*DIM + c];
}

// ---------------- final scatter ----------------
__global__ void k_scatter(const float* __restrict__ h, const int* __restrict__ batch,
                          float* __restrict__ out)
{
  int i = blockIdx.x * 256 + threadIdx.x;
  if (i >= NN * NS) return;
  int n = i >> 7;
  atomicAdd(&out[(size_t)batch[n]*NS + (i & 127)], h[i] * 0.23570226039551584f);
}

extern "C" void kernel_launch(void* const* d_in, const int* in_sizes, int n_in,
                              void* d_out, int out_size, void* d_ws, size_t ws_size,
                              hipStream_t stream)
{
  const int*   z        = (const int*)  d_in[0];
  const float* pos      = (const float*)d_in[1];
  const int*   batch    = (const int*)  d_in[2];
  const int*   esrc     = (const int*)  d_in[3];
  const int*   edst     = (const int*)  d_in[4];
  const float* atom_emb = (const float*)d_in[5];
  const float* W_deg_sh = (const float*)d_in[6];
  const float* deg_w1   = (const float*)d_in[7];
  const float* deg_w2   = (const float*)d_in[8];
  const float* deg_w3   = (const float*)d_in[9];
  const float* Wv       = (const float*)d_in[10];
  const float* Wsh      = (const float*)d_in[11];
  const float* rad_w1   = (const float*)d_in[12];
  const float* rad_w2   = (const float*)d_in[13];
  const float* rad_w3   = (const float*)d_in[14];
  const float* attn_a   = (const float*)d_in[15];
  const float* Wo       = (const float*)d_in[16];
  const float* ffn_w1   = (const float*)d_in[17];
  const float* ffn_w2   = (const float*)d_in[18];
  const float* head_w1  = (const float*)d_in[19];
  const float* head_w2  = (const float*)d_in[20];
  float* out = (float*)d_out;

  float* x      = (float*)d_ws;
  float* statsb = x      + (size_t)NN * DIM;
  float* agg    = statsb + (size_t)NN * 2;
  float* distp  = agg    + (size_t)NN * DIM;
  float* logitsP= distp  + (size_t)NE;
  float* alphab = logitsP+ (size_t)NE * NHEAD * 2;
  __hip_bfloat16* yb    = (__hip_bfloat16*)(alphab + (size_t)NE * NHEAD);
  __hip_bfloat16* h2b   = yb + (size_t)NN * DIM;
  __hip_bfloat16* shb16 = h2b + (size_t)NE * FCH;
  __hip_bfloat16* w3Tb  = shb16 + (size_t)NE * 16;
  __hip_bfloat16* wshTb = w3Tb + (size_t)7 * 512 * 64;   // [7][512][32]
  __hip_bfloat16* bigWT = wshTb + (size_t)7 * 512 * 32;
  int* cnt      = (int*)(bigWT + (size_t)24*512*480 + 2*128*128);
  int* row_ptr  = cnt + NN;
  int* csr      = row_ptr + NN + 1;
  int* cursor   = csr + NE;
  int* esrcp    = cursor + NN;
  int* edstp    = esrcp + NE;
  __hip_bfloat16* msgb = (__hip_bfloat16*)(edstp + NE);  // [10000][8192] (16KB tiles)
  float* tmp = logitsP;

  size_t needed = (size_t)((char*)msgb + (size_t)10000 * 16384 - (char*)d_ws);
  bool fast = ws_size >= needed;

  dim3 b256(256);
  k_zero_int<<<(NN+255)/256, b256, 0, stream>>>(cnt, NN);
  k_count<<<(NE+255)/256, b256, 0, stream>>>(edst, cnt);
  k_scan<<<1, 1024, 0, stream>>>(cnt, row_ptr);
  k_zero_int<<<(NN+255)/256, b256, 0, stream>>>(cursor, NN);
  k_fill<<<(NE+255)/256, b256, 0, stream>>>(edst, row_ptr, cursor, csr);
  k_geom_p<<<(NE+255)/256, b256, 0, stream>>>(pos, esrc, edst, csr, shb16, distp, esrcp, edstp);
  k_prep<<<(7*512*64 + 7*512*32 + 255)/256, b256, 0, stream>>>(deg_w3, rad_w3, W_deg_sh, Wsh,
      w3Tb, wshTb);
  k_prepw<<<(24*512*480 + 2*128*128 + 255)/256, b256, 0, stream>>>(Wv, Wo, ffn_w1, ffn_w2,
      head_w1, head_w2, bigWT);
  hipMemsetAsync(logitsP, 0, (size_t)NE * NHEAD * 2 * sizeof(float), stream);

  // degree embedding
  k_radial<<<NE/64, b256, 0, stream>>>(distp, deg_w1, deg_w2, h2b);
  k_init_x<<<(NN*DIM+255)/256, b256, 0, stream>>>(z, atom_emb, x);
  k_msgm<2,0><<<10000, b256, 0, stream>>>(h2b, shb16, esrcp, edstp, w3Tb, wshTb,
      nullptr, nullptr, nullptr, x, nullptr, nullptr);

  dim3 gemm_grid(157, 4);
  dim3 head_grid(157, 1);
  for (int l = 0; l < NL; l++) {
    const float* w1_l  = rad_w1 + (size_t)l*NBASIS*FCH;
    const float* w2_l  = rad_w2 + (size_t)l*FCH*FCH;
    const float* aa_l  = attn_a + (size_t)l*NHEAD*HDIM;
    const __hip_bfloat16* w3T_l  = w3Tb  + (size_t)(l+1)*512*64;
    const __hip_bfloat16* wshT_l = wshTb + (size_t)(l+1)*512*32;
    const __hip_bfloat16* WvT_l = bigWT + (size_t)(0+l)*512*480;
    const __hip_bfloat16* WoT_l = bigWT + (size_t)(6+l)*512*480;
    const __hip_bfloat16* F1T_l = bigWT + (size_t)(12+l)*512*480;
    const __hip_bfloat16* F2T_l = bigWT + (size_t)(18+l)*512*480;

    k_stats<<<(NN+3)/4, b256, 0, stream>>>(x, statsb, NN, DIM, DIM);
    k_gemmm<0,0,1,1><<<gemm_grid, b256, 0, stream>>>(x, WvT_l, nullptr, yb, statsb,
        NN, DIM, DIM, DIM);
    k_radial<<<NE/64, b256, 0, stream>>>(distp, w1_l, w2_l, h2b);
    if (fast) {
      k_msgm<0,1><<<10000, b256, 0, stream>>>(h2b, shb16, esrcp, edstp, w3T_l, wshT_l,
          aa_l, yb, nullptr, nullptr, logitsP, msgb);
      k_alpha<<<(NN*NHEAD+255)/256, b256, 0, stream>>>(row_ptr, logitsP, alphab);
      hipMemsetAsync(agg, 0, (size_t)NN * DIM * sizeof(float), stream);
      k_aggm<<<10000, b256, 0, stream>>>(msgb, edstp, alphab, agg);
    } else {
      k_msgm<0,0><<<10000, b256, 0, stream>>>(h2b, shb16, esrcp, edstp, w3T_l, wshT_l,
          aa_l, yb, nullptr, nullptr, logitsP, nullptr);
      k_alpha<<<(NN*NHEAD+255)/256, b256, 0, stream>>>(row_ptr, logitsP, alphab);
      hipMemsetAsync(agg, 0, (size_t)NN * DIM * sizeof(float), stream);
      k_msgm<1,0><<<10000, b256, 0, stream>>>(h2b, shb16, esrcp, edstp, w3T_l, wshT_l,
          nullptr, yb, alphab, agg, nullptr, nullptr);
    }
    k_gemmm<1,0,0,0><<<gemm_grid, b256, 0, stream>>>(agg, WoT_l, x, nullptr, nullptr,
        NN, DIM, DIM, DIM);
    k_stats<<<(NN+3)/4, b256, 0, stream>>>(x, statsb, NN, DIM, DIM);
    k_gemmm<0,1,1,0><<<gemm_grid, b256, 0, stream>>>(x, F1T_l, agg, nullptr, statsb,
        NN, DIM, DIM, DIM);
    k_gemmm<1,0,0,0><<<gemm_grid, b256, 0, stream>>>(agg, F2T_l, x, nullptr, nullptr,
        NN, DIM, DIM, DIM);
  }

  // output head
  const __hip_bfloat16* H1T = bigWT + (size_t)24*512*480;
  const __hip_bfloat16* H2T = H1T + 128*128;
  k_stats<<<(NN+3)/4, b256, 0, stream>>>(x, statsb, NN, NS, DIM);
  k_gemmm<0,1,1,0><<<head_grid, b256, 0, stream>>>(x, H1T, agg, nullptr, statsb,
      NN, NS, NS, DIM);
  k_gemmm<0,0,0,0><<<head_grid, b256, 0, stream>>>(agg, H2T, tmp, nullptr, nullptr,
      NN, NS, NS, NS);
  hipMemsetAsync(d_out, 0, (size_t)NG * NS * sizeof(float), stream);
  k_scatter<<<(NN*NS+255)/256, b256, 0, stream>>>(tmp, batch, out);
}

// Round 16
// 2570.279 us; speedup vs baseline: 1.9055x; 1.0081x over previous
//
#include <hip/hip_runtime.h>
#include <hip/hip_bf16.h>
#include <math.h>

#define NN 10000
#define NE 160000
#define DIM 480
#define NSH 9
#define NBASIS 128
#define NHEAD 4
#define HDIM 120
#define NL 6
#define NG 256
#define NS 128
#define FCH 64
#define CUTOFF 5.0f

typedef __attribute__((ext_vector_type(8))) short bf8v;
typedef __attribute__((ext_vector_type(4))) float f4v;

__device__ __forceinline__ float silu_f(float v) { return v / (1.0f + __expf(-v)); }
__device__ __forceinline__ float bf2f(ushort u) { return __uint_as_float(((unsigned)u) << 16); }
__device__ __forceinline__ ushort f2bfu(float f) {
  __hip_bfloat16 h = __float2bfloat16(f);
  return *reinterpret_cast<ushort*>(&h);
}

__device__ __forceinline__ void nt_store16(char* dst, uint4 v) {
  unsigned* p = (unsigned*)dst;
  __builtin_nontemporal_store(v.x, p + 0);
  __builtin_nontemporal_store(v.y, p + 1);
  __builtin_nontemporal_store(v.z, p + 2);
  __builtin_nontemporal_store(v.w, p + 3);
}
__device__ __forceinline__ uint4 nt_load16(const char* src) {
  const unsigned* p = (const unsigned*)src;
  uint4 v;
  v.x = __builtin_nontemporal_load(p + 0);
  v.y = __builtin_nontemporal_load(p + 1);
  v.z = __builtin_nontemporal_load(p + 2);
  v.w = __builtin_nontemporal_load(p + 3);
  return v;
}

struct bf16x4 { __hip_bfloat16 v[4]; };

// ---------------- CSR build ----------------
__global__ void k_zero_int(int* p, int n)
{
  int i = blockIdx.x * 256 + threadIdx.x;
  if (i < n) p[i] = 0;
}

__global__ void k_count(const int* __restrict__ edst, int* __restrict__ cnt)
{
  int e = blockIdx.x * 256 + threadIdx.x;
  if (e < NE) atomicAdd(&cnt[edst[e]], 1);
}

__global__ __launch_bounds__(1024)
void k_scan(const int* __restrict__ cnt, int* __restrict__ row_ptr)
{
  __shared__ int part[1024];
  int tid = threadIdx.x;
  const int per = 10;
  int base = tid * per;
  int s = 0;
  for (int i = 0; i < per; i++) { int idx = base + i; if (idx < NN) s += cnt[idx]; }
  part[tid] = s; __syncthreads();
  for (int off = 1; off < 1024; off <<= 1) {
    int v = (tid >= off) ? part[tid - off] : 0;
    __syncthreads();
    part[tid] += v;
    __syncthreads();
  }
  int run = (tid > 0) ? part[tid - 1] : 0;
  for (int i = 0; i < per; i++) {
    int idx = base + i;
    if (idx < NN) { row_ptr[idx] = run; run += cnt[idx]; }
  }
  if (tid == 1023) row_ptr[NN] = part[1023];
}

__global__ void k_fill(const int* __restrict__ edst, const int* __restrict__ row_ptr,
                       int* __restrict__ cursor, int* __restrict__ csr)
{
  int e = blockIdx.x * 256 + threadIdx.x;
  if (e >= NE) return;
  int d = edst[e];
  int p = atomicAdd(&cursor[d], 1);
  csr[row_ptr[d] + p] = e;
}

// ---------------- geometry in permuted (CSR) order; sh as bf16 [NE][16] padded ----
__global__ void k_geom_p(const float* __restrict__ pos, const int* __restrict__ esrc,
                         const int* __restrict__ edst, const int* __restrict__ csr,
                         __hip_bfloat16* __restrict__ shb, float* __restrict__ distp,
                         int* __restrict__ esrcp, int* __restrict__ edstp)
{
  int j = blockIdx.x * 256 + threadIdx.x;
  if (j >= NE) return;
  int e = csr[j];
  int s = esrc[e], d = edst[e];
  esrcp[j] = s;
  edstp[j] = d;
  float vx = pos[s*3+0] - pos[d*3+0];
  float vy = pos[s*3+1] - pos[d*3+1];
  float vz = pos[s*3+2] - pos[d*3+2];
  float r = sqrtf(vx*vx + vy*vy + vz*vz);
  distp[j] = r;
  float inv = 1.0f / (r + 1e-9f);
  float x = vx*inv, y = vy*inv, z = vz*inv;
  const float s3 = 1.7320508075688772f;
  const float s15 = 3.872983346207417f;
  const float s5 = 2.23606797749979f;
  float sv[9];
  sv[0] = 1.0f;
  sv[1] = s3*x; sv[2] = s3*y; sv[3] = s3*z;
  sv[4] = s15*x*y; sv[5] = s15*y*z; sv[6] = 0.5f*s5*(3.0f*z*z - 1.0f);
  sv[7] = s15*x*z; sv[8] = 0.5f*s15*(x*x - y*y);
  __hip_bfloat16* o = shb + (size_t)j * 16;
#pragma unroll
  for (int q = 0; q < 9; q++) o[q] = __float2bfloat16(sv[q]);
#pragma unroll
  for (int q = 9; q < 16; q++) o[q] = __float2bfloat16(0.f);
}

// ---------------- prep: w3T [7][512][64] + wshT [7][512][32] bf16 ----------------
__global__ void k_prep(const float* __restrict__ deg_w3, const float* __restrict__ rad_w3,
                       const float* __restrict__ W_deg_sh, const float* __restrict__ Wsh,
                       __hip_bfloat16* __restrict__ w3T, __hip_bfloat16* __restrict__ wshT)
{
  int i = blockIdx.x * 256 + threadIdx.x;
  if (i < 7*512*64) {
    int l = i / (512*64); int r = i - l*512*64; int col = r >> 6; int k = r & 63;
    float v = 0.f;
    if (col < DIM) {
      const float* src = (l == 0) ? deg_w3 : rad_w3 + (size_t)(l-1)*FCH*DIM;
      v = src[k*DIM + col];
    }
    w3T[i] = __float2bfloat16(v);
  }
  int j = i - 7*512*64;
  if (j >= 0 && j < 7*512*32) {
    int l = j / (512*32); int r = j - l*512*32; int col = r >> 5; int q = r & 31;
    float v = 0.f;
    if (col < DIM && q < 9) {
      const float* src = (l == 0) ? W_deg_sh : Wsh + (size_t)(l-1)*NSH*DIM;
      v = src[q*DIM + col];
    }
    wshT[j] = __float2bfloat16(v);
  }
}

// ---------------- prep: node-GEMM weights transposed bf16 ----------------
__global__ void k_prepw(const float* __restrict__ Wv, const float* __restrict__ Wo,
                        const float* __restrict__ f1, const float* __restrict__ f2,
                        const float* __restrict__ h1, const float* __restrict__ h2w,
                        __hip_bfloat16* __restrict__ WT)
{
  int i = blockIdx.x * 256 + threadIdx.x;
  const int big = 24*512*480;
  if (i < big) {
    int m = i / (512*480); int r = i - m*(512*480); int col = r / 480; int k = r - col*480;
    int l = m % 6; int t = m / 6;
    const float* src = (t==0 ? Wv : t==1 ? Wo : t==2 ? f1 : f2) + (size_t)l*DIM*DIM;
    float v = (col < DIM) ? src[k*DIM + col] : 0.f;
    WT[i] = __float2bfloat16(v);
  } else if (i < big + 2*128*128) {
    int j = i - big; int m = j / (128*128); int r = j - m*(128*128);
    int col = r >> 7; int k = r & 127;
    const float* src = m ? h2w : h1;
    WT[i] = __float2bfloat16(src[k*128 + col]);
  }
}

// ---------------- radial MLP -> h2 bf16 [E,64] ----------------
__global__ __launch_bounds__(256)
void k_radial(const float* __restrict__ dist, const float* __restrict__ w1,
              const float* __restrict__ w2, __hip_bfloat16* __restrict__ h2out)
{
  __shared__ float rbs[NBASIS][65];
  __shared__ float wsm[NBASIS * FCH];
  __shared__ float ds[64];
  int tid = threadIdx.x;
  int e0 = blockIdx.x * 64;
  if (tid < 64) ds[tid] = dist[e0 + tid];
  for (int i = tid; i < NBASIS * FCH; i += 256) wsm[i] = w1[i];
  __syncthreads();
  const float invw = (float)NBASIS / CUTOFF;
  for (int i = tid; i < NBASIS * 64; i += 256) {
    int k = i >> 6, e = i & 63;
    float c = k * (CUTOFF / 127.0f);
    float tt = (ds[e] - c) * invw;
    rbs[k][e] = __expf(-0.5f * tt * tt);
  }
  __syncthreads();
  int ty = tid >> 4, tx = tid & 15;
  float acc1[4][4] = {};
  for (int k = 0; k < NBASIS; k++) {
    float b[4];
#pragma unroll
    for (int j = 0; j < 4; j++) b[j] = wsm[k*FCH + tx*4 + j];
#pragma unroll
    for (int i = 0; i < 4; i++) {
      float a = rbs[k][ty*4 + i];
#pragma unroll
      for (int j = 0; j < 4; j++) acc1[i][j] = fmaf(a, b[j], acc1[i][j]);
    }
  }
  __syncthreads();
#pragma unroll
  for (int i = 0; i < 4; i++)
#pragma unroll
    for (int j = 0; j < 4; j++)
      rbs[tx*4 + j][ty*4 + i] = silu_f(acc1[i][j]);
  for (int i = tid; i < FCH * FCH; i += 256) wsm[i] = w2[i];
  __syncthreads();
  float acc2[4][4] = {};
  for (int k = 0; k < FCH; k++) {
    float b[4];
#pragma unroll
    for (int j = 0; j < 4; j++) b[j] = wsm[k*FCH + tx*4 + j];
#pragma unroll
    for (int i = 0; i < 4; i++) {
      float a = rbs[k][ty*4 + i];
#pragma unroll
      for (int j = 0; j < 4; j++) acc2[i][j] = fmaf(a, b[j], acc2[i][j]);
    }
  }
#pragma unroll
  for (int i = 0; i < 4; i++) {
    int e = e0 + ty*4 + i;
    bf16x4 p;
#pragma unroll
    for (int j = 0; j < 4; j++) p.v[j] = __float2bfloat16(silu_f(acc2[i][j]));
    *(bf16x4*)(h2out + (size_t)e*FCH + tx*4) = p;
  }
}

// ---------------- per-row LN stats (mu, rstd) ----------------
__global__ __launch_bounds__(256)
void k_stats(const float* __restrict__ in, float* __restrict__ st,
             int n, int cols, int stride)
{
  int row = blockIdx.x * 4 + (threadIdx.x >> 6);
  int lane = threadIdx.x & 63;
  if (row >= n) return;
  const float* r = in + (size_t)row * stride;
  float s = 0.f, ss = 0.f;
  for (int c = lane; c < cols; c += 64) { float v = r[c]; s += v; ss += v*v; }
  for (int off = 32; off > 0; off >>= 1) { s += __shfl_down(s, off); ss += __shfl_down(ss, off); }
  if (lane == 0) {
    float mu = s / cols;
    float var = ss / cols - mu * mu;
    st[row*2]   = mu;
    st[row*2+1] = rsqrtf(fmaxf(var, 0.f) + 1e-5f);
  }
}

// ---------------- MFMA node GEMM: 64 rows x 128 cols per block ----------------
template<int ADD, int SILU, int LNA, int OBF16>
__global__ __launch_bounds__(256)
void k_gemmm(const float* __restrict__ A, const __hip_bfloat16* __restrict__ BT,
             float* __restrict__ C, __hip_bfloat16* __restrict__ Cb,
             const float* __restrict__ st, int M, int K, int Nc, int lda)
{
  __shared__ __align__(16) char smA[4096];   // [64][32] bf16, XOR-swizzled
  __shared__ __align__(16) char smB[8192];   // [128][32] bf16
  __shared__ float smu[64], srs[64];
  int tid = threadIdx.x;
  int lane = tid & 63;
  int wv = tid >> 6;
  int l15 = lane & 15, l4 = lane >> 4;
  int row0 = blockIdx.x * 64;
  int col0 = blockIdx.y * 128;
  if (LNA && tid < 64) {
    int gr = row0 + tid;
    float m2 = 0.f, r2 = 1.f;
    if (gr < M) { m2 = st[gr*2]; r2 = st[gr*2+1]; }
    smu[tid] = m2; srs[tid] = r2;
  }
  f4v z4 = {0.f,0.f,0.f,0.f};
  f4v acc[8];
#pragma unroll
  for (int ct = 0; ct < 8; ct++) acc[ct] = z4;

  int arow = tid >> 2, aq = tid & 3;   // A: row, 8-float quarter
  int bcol = tid >> 1, bh = tid & 1;   // B: col, 16-elem half
  for (int k0 = 0; k0 < K; k0 += 32) {
    __syncthreads();
    {   // stage A (f32 -> LN -> bf16): 8 floats/thread
      int grow = row0 + arow;
      float f[8];
      if (grow < M) {
        const float* ap = A + (size_t)grow * lda + k0 + aq*8;
        float4 v0 = *(const float4*)ap;
        float4 v1 = *(const float4*)(ap + 4);
        f[0]=v0.x; f[1]=v0.y; f[2]=v0.z; f[3]=v0.w;
        f[4]=v1.x; f[5]=v1.y; f[6]=v1.z; f[7]=v1.w;
      } else {
#pragma unroll
        for (int q = 0; q < 8; q++) f[q] = 0.f;
      }
      if (LNA) {
        float mu = smu[arow], rs = srs[arow];
#pragma unroll
        for (int q = 0; q < 8; q++) f[q] = (f[q] - mu) * rs;
      }
      unsigned u[4];
#pragma unroll
      for (int q = 0; q < 4; q++)
        u[q] = (unsigned)f2bfu(f[2*q]) | ((unsigned)f2bfu(f[2*q+1]) << 16);
      int base = arow*64 + aq*16;
      *(uint4*)(smA + (base ^ ((arow&7)<<4))) = make_uint4(u[0],u[1],u[2],u[3]);
    }
    {   // stage B from pre-transposed bf16: 16 elems/thread
      const ushort* bp = (const ushort*)BT + (size_t)(col0 + bcol) * K + k0 + bh*16;
      uint4 v0 = *(const uint4*)bp;
      uint4 v1 = *(const uint4*)(bp + 8);
      int base = bcol*64 + bh*32;
      *(uint4*)(smB + (base ^ ((bcol&7)<<4))) = v0;
      *(uint4*)(smB + ((base+16) ^ ((bcol&7)<<4))) = v1;
    }
    __syncthreads();
    int r0 = wv*16 + l15;
    bf8v a0 = *(const bf8v*)(smA + ((r0*64 + l4*16) ^ ((r0&7)<<4)));
#pragma unroll
    for (int ct = 0; ct < 8; ct++) {
      int cc = ct*16 + l15;
      bf8v b = *(const bf8v*)(smB + ((cc*64 + l4*16) ^ ((cc&7)<<4)));
      acc[ct] = __builtin_amdgcn_mfma_f32_16x16x32_bf16(a0, b, acc[ct], 0, 0, 0);
    }
  }
#pragma unroll
  for (int ct = 0; ct < 8; ct++)
#pragma unroll
  for (int e = 0; e < 4; e++) {
    int row = row0 + wv*16 + l4*4 + e;
    int col = col0 + ct*16 + l15;
    if (row < M && col < Nc) {
      float v = acc[ct][e];
      if (SILU) v = silu_f(v);
      if (OBF16) Cb[(size_t)row * Nc + col] = __float2bfloat16(v);
      else {
        float* p = C + (size_t)row * Nc + col;
        if (ADD) *p += v; else *p = v;
      }
    }
  }
}

// ---------------- MFMA msg kernel: 64 edges x 128 cols per block ----------------
// MODE 0: logits partials (plain stores); STOREM=1 dumps swizzled M^T tile (16KB)
//         via NON-TEMPORAL stores (write-once data; round-14 FETCH showed the
//         msgb stream evicting h2/y from L2/L3, forcing 79MB HBM re-fetch).
// MODE 1: alpha-weighted segment-sum -> agg (fallback). MODE 2: (1/16) -> x.
template<int MODE, int STOREM>
__global__ __launch_bounds__(256)
void k_msgm(const __hip_bfloat16* __restrict__ h2, const __hip_bfloat16* __restrict__ shb,
            const int* __restrict__ esrcp, const int* __restrict__ edstp,
            const __hip_bfloat16* __restrict__ w3T, const __hip_bfloat16* __restrict__ wshT,
            const float* __restrict__ aa, const __hip_bfloat16* __restrict__ y,
            const float* __restrict__ alpha, float* __restrict__ outbuf,
            float* __restrict__ logitsP, __hip_bfloat16* __restrict__ msgb)
{
  __shared__ __align__(16) char sm_ab[24576];  // h2s[64][64](8K) + w3T[128][64](16K); MT reuses [0,16K)
  __shared__ __align__(16) char sm_sh[4096];   // sh [64][32] bf16 (zero-padded)
  __shared__ __align__(16) char sm_wsh[8192];  // wshT [128][32] bf16
  __shared__ int srcs[(MODE<=1)?64:1];
  __shared__ int dsts[(MODE>=1)?64:1];
  __shared__ int segidL[(MODE>=1)?64:1];
  __shared__ int seg_dstL[(MODE>=1)?32:1];

  int bid = blockIdx.x;
  int swzb = (bid & 7) * 1250 + (bid >> 3);    // 10000 = 8 XCD chunks x 1250
  int e0   = (swzb >> 2) * 64;
  int col0 = (swzb & 3) * 128;
  int tid = threadIdx.x;
  int lane = tid & 63;
  int wv = tid >> 6;
  int l15 = lane & 15, l4 = lane >> 4;
  int wrow0 = wv * 16;

  for (int c = tid; c < 512; c += 256) {       // h2: 64 rows x 128B
    int r = c >> 3, s = c & 7;
    uint4 v = *(const uint4*)((const char*)h2 + (size_t)(e0 + r) * 128 + s * 16);
    *(uint4*)(sm_ab + ((r * 128 + s * 16) ^ ((r & 7) << 4))) = v;
  }
  for (int c = tid; c < 1024; c += 256) {      // w3T: 128 cols x 128B at 8192
    int r = c >> 3, s = c & 7;
    uint4 v = *(const uint4*)((const char*)w3T + (size_t)(col0 + r) * 128 + s * 16);
    *(uint4*)(sm_ab + 8192 + ((r * 128 + s * 16) ^ ((r & 7) << 4))) = v;
  }
  {                                            // sh: 64 rows x 64B (q>=2 zero)
    int r = tid >> 2, q = tid & 3;
    uint4 v = make_uint4(0u, 0u, 0u, 0u);
    if (q < 2)
      v = *(const uint4*)((const ushort*)shb + (size_t)(e0 + r) * 16 + q * 8);
    *(uint4*)(sm_sh + ((r * 64 + q * 16) ^ ((r & 7) << 4))) = v;
  }
  for (int c = tid; c < 512; c += 256) {       // wshT: 128 cols x 64B
    int r = c >> 2, q = c & 3;
    uint4 v = *(const uint4*)((const ushort*)wshT + (size_t)(col0 + r) * 32 + q * 8);
    *(uint4*)(sm_wsh + ((r * 64 + q * 16) ^ ((r & 7) << 4))) = v;
  }
  if (tid < 64) {
    if (MODE <= 1) srcs[tid] = esrcp[e0 + tid];
    if (MODE >= 1) dsts[tid] = edstp[e0 + tid];
  }
  __syncthreads();

  // single-wave ballot segment scan
  int nseg = 0;
  if (MODE >= 1) {
    if (tid < 64) {
      bool flag = (tid == 0) || (dsts[tid] != dsts[tid - 1]);
      unsigned long long m = __ballot(flag ? 1 : 0);
      unsigned long long below = m & (~0ull >> (63 - tid));
      int sg = __popcll(below) - 1;
      segidL[tid] = sg;
      if (flag && sg < 32) seg_dstL[sg] = dsts[tid];
    }
    __syncthreads();
    nseg = segidL[63] + 1;
  }

  f4v z4 = {0.f, 0.f, 0.f, 0.f};
  f4v g[8];
#pragma unroll
  for (int ct = 0; ct < 8; ct++) g[ct] = z4;

  // GEMM1: gate = h2 @ w3
#pragma unroll
  for (int ks = 0; ks < 2; ks++) {
    int k0b = (ks * 32 + l4 * 8) * 2;
    int r0 = wrow0 + l15;
    bf8v a0 = *(const bf8v*)(sm_ab + ((r0 * 128 + k0b) ^ ((r0 & 7) << 4)));
#pragma unroll
    for (int ct = 0; ct < 8; ct++) {
      int cc = ct * 16 + l15;
      bf8v b = *(const bf8v*)(sm_ab + 8192 + ((cc * 128 + k0b) ^ ((cc & 7) << 4)));
      g[ct] = __builtin_amdgcn_mfma_f32_16x16x32_bf16(a0, b, g[ct], 0, 0, 0);
    }
  }

  // epilogue: m = y * (sh@wsh via MFMA) * gate  (+ alpha / scale)
  const ushort* yus = (const ushort*)y;
  int srcs4[4];
  float4 al4[4];
#pragma unroll
  for (int e = 0; e < 4; e++) {
    int rl = wrow0 + l4 * 4 + e;
    if (MODE <= 1) srcs4[e] = srcs[rl];
    if (MODE == 1) al4[e] = *(const float4*)(alpha + (size_t)(e0 + rl) * 4);
  }
  {
    int r0 = wrow0 + l15;
    bf8v shA = *(const bf8v*)(sm_sh + ((r0 * 64 + l4 * 16) ^ ((r0 & 7) << 4)));
#pragma unroll
    for (int ct = 0; ct < 8; ct++) {
      int cc = ct * 16 + l15;
      int col = col0 + cc;
      bf8v wB = *(const bf8v*)(sm_wsh + ((cc * 64 + l4 * 16) ^ ((cc & 7) << 4)));
      f4v sw4 = __builtin_amdgcn_mfma_f32_16x16x32_bf16(shA, wB, z4, 0, 0, 0);
#pragma unroll
      for (int e = 0; e < 4; e++) {
        float yv;
        if (MODE == 2) yv = 1.f;
        else yv = (col < DIM) ? bf2f(yus[(size_t)srcs4[e] * DIM + col]) : 0.f;
        float mv = yv * sw4[e] * g[ct][e];
        if (MODE == 1) {
          float av = (col < 120) ? al4[e].x : (col < 240) ? al4[e].y
                   : (col < 360) ? al4[e].z : al4[e].w;
          mv *= av;
        }
        if (MODE == 2) mv *= (1.0f / 16.0f);
        g[ct][e] = mv;
      }
    }
  }

  if (MODE == 0) {
    int hA = col0 / 120;
    float aav[8];
#pragma unroll
    for (int ct = 0; ct < 8; ct++) {
      int col = col0 + ct * 16 + l15;
      aav[ct] = (col < DIM) ? aa[col] : 0.f;
    }
#pragma unroll
    for (int e = 0; e < 4; e++) {
      float sA = 0.f, sB = 0.f;
#pragma unroll
      for (int ct = 0; ct < 8; ct++) {
        int col = col0 + ct * 16 + l15;
        float mv = g[ct][e];
        float lv = (mv > 0.f) ? mv : 0.2f * mv;
        float c = lv * aav[ct];
        if (col / 120 == hA) sA += c; else sB += c;
      }
#pragma unroll
      for (int off = 1; off < 16; off <<= 1) {
        sA += __shfl_xor(sA, off, 16);
        sB += __shfl_xor(sB, off, 16);
      }
      if (l15 == 0) {
        int row = e0 + wrow0 + l4 * 4 + e;
        logitsP[((size_t)row * NHEAD + hA) * 2] = sA;
        if (hA < 3) logitsP[((size_t)row * NHEAD + hA + 1) * 2 + 1] = sB;
      }
    }
    if (STOREM) {
      __syncthreads();
#pragma unroll
      for (int ct = 0; ct < 8; ct++) {
        int cc = ct * 16 + l15;
        int ebase = wrow0 + l4 * 4;
        ushort4 pk;
        pk.x = f2bfu(g[ct][0]); pk.y = f2bfu(g[ct][1]);
        pk.z = f2bfu(g[ct][2]); pk.w = f2bfu(g[ct][3]);
        *(ushort4*)(sm_ab + ((cc * 128 + ebase * 2) ^ ((cc & 7) << 4))) = pk;
      }
      __syncthreads();
      char* gdst = (char*)msgb + (size_t)swzb * 16384;
#pragma unroll
      for (int k = 0; k < 4; k++) {
        int o = tid * 16 + k * 4096;
        uint4 v = *(const uint4*)(sm_ab + o);
        nt_store16(gdst + o, v);
      }
    }
    return;
  }

  if (nseg > 32) {   // rare fallback
#pragma unroll
    for (int e = 0; e < 4; e++) {
      int rl = wrow0 + l4 * 4 + e;
      int dd = dsts[rl];
#pragma unroll
      for (int ct = 0; ct < 8; ct++) {
        int col = col0 + ct * 16 + l15;
        if (col < DIM) atomicAdd(&outbuf[(size_t)dd * DIM + col], g[ct][e]);
      }
    }
    return;
  }

  // write M^T then GEMM3 segment-sum
  __syncthreads();
#pragma unroll
  for (int ct = 0; ct < 8; ct++) {
    int cc = ct * 16 + l15;
    int ebase = wrow0 + l4 * 4;
    ushort4 pk;
    pk.x = f2bfu(g[ct][0]); pk.y = f2bfu(g[ct][1]);
    pk.z = f2bfu(g[ct][2]); pk.w = f2bfu(g[ct][3]);
    *(ushort4*)(sm_ab + ((cc * 128 + ebase * 2) ^ ((cc & 7) << 4))) = pk;
  }
  __syncthreads();

  f4v p[2][2];
  p[0][0] = z4; p[0][1] = z4; p[1][0] = z4; p[1][1] = z4;
#pragma unroll
  for (int ks = 0; ks < 2; ks++) {
    int k0 = ks * 32 + l4 * 8;
    bf8v a0, a1;
#pragma unroll
    for (int e2 = 0; e2 < 8; e2++) {
      int sg = segidL[k0 + e2];
      a0[e2] = (sg == l15)      ? (short)0x3F80 : (short)0;
      a1[e2] = (sg == l15 + 16) ? (short)0x3F80 : (short)0;
    }
#pragma unroll
    for (int c2 = 0; c2 < 2; c2++) {
      int cc = (wv * 2 + c2) * 16 + l15;
      bf8v bm = *(const bf8v*)(sm_ab + ((cc * 128 + k0 * 2) ^ ((cc & 7) << 4)));
      p[0][c2] = __builtin_amdgcn_mfma_f32_16x16x32_bf16(a0, bm, p[0][c2], 0, 0, 0);
      p[1][c2] = __builtin_amdgcn_mfma_f32_16x16x32_bf16(a1, bm, p[1][c2], 0, 0, 0);
    }
  }
#pragma unroll
  for (int rt = 0; rt < 2; rt++)
#pragma unroll
  for (int c2 = 0; c2 < 2; c2++)
#pragma unroll
  for (int e = 0; e < 4; e++) {
    int seg = rt * 16 + l4 * 4 + e;
    int col = col0 + (wv * 2 + c2) * 16 + l15;
    if (seg < nseg && col < DIM) {
      float v = p[rt][c2][e];
      float* ptr = outbuf + (size_t)seg_dstL[seg] * DIM + col;
      if (seg == 0 || seg == nseg - 1) atomicAdd(ptr, v);
      else if (MODE == 1) *ptr = v;
      else *ptr += v;
    }
  }
}

// ---------------- pass B (fast path): read msgb tile (non-temporal), alpha-weight,
// segment-sum via S^T @ M MFMA ----
__global__ __launch_bounds__(256)
void k_aggm(const __hip_bfloat16* __restrict__ msgb, const int* __restrict__ edstp,
            const float* __restrict__ alpha, float* __restrict__ agg)
{
  __shared__ __align__(16) char smM[16384];
  __shared__ __align__(16) float alsq[64][4];
  __shared__ int dsts[64];
  __shared__ int segidL[64];
  __shared__ int seg_dstL[32];

  int bid = blockIdx.x;
  int swzb = (bid & 7) * 1250 + (bid >> 3);
  int e0   = (swzb >> 2) * 64;
  int col0 = (swzb & 3) * 128;
  int tid = threadIdx.x;
  int lane = tid & 63;
  int wv = tid >> 6;
  int l15 = lane & 15, l4 = lane >> 4;

  if (tid < 64) {
    dsts[tid] = edstp[e0 + tid];
    *(float4*)&alsq[tid][0] = *(const float4*)(alpha + (size_t)(e0 + tid) * 4);
  }
  __syncthreads();

  int nseg = 0;
  if (tid < 64) {
    bool flag = (tid == 0) || (dsts[tid] != dsts[tid - 1]);
    unsigned long long m = __ballot(flag ? 1 : 0);
    unsigned long long below = m & (~0ull >> (63 - tid));
    int sg = __popcll(below) - 1;
    segidL[tid] = sg;
    if (flag && sg < 32) seg_dstL[sg] = dsts[tid];
  }
  __syncthreads();
  nseg = segidL[63] + 1;

  const char* gsrc = (const char*)msgb + (size_t)swzb * 16384;
  uint4 vv[4];
#pragma unroll
  for (int k = 0; k < 4; k++) {
    int o = tid * 16 + k * 4096;
    uint4 v = nt_load16(gsrc + o);
    int cc = o >> 7;
    int col = col0 + cc;
    int h = (col < DIM) ? (col / 120) : 3;
    int be = ((o & 127) ^ ((cc & 7) << 4)) >> 1;
    unsigned w[4] = {v.x, v.y, v.z, v.w};
#pragma unroll
    for (int q = 0; q < 4; q++) {
      float lo = bf2f((ushort)(w[q] & 0xffffu)) * alsq[be + 2*q][h];
      float hi = bf2f((ushort)(w[q] >> 16))     * alsq[be + 2*q + 1][h];
      w[q] = (unsigned)f2bfu(lo) | ((unsigned)f2bfu(hi) << 16);
    }
    vv[k] = make_uint4(w[0], w[1], w[2], w[3]);
    *(uint4*)(smM + o) = vv[k];
  }
  __syncthreads();

  if (nseg > 32) {
#pragma unroll
    for (int k = 0; k < 4; k++) {
      int o = tid * 16 + k * 4096;
      int cc = o >> 7;
      int col = col0 + cc;
      if (col >= DIM) continue;
      int be = ((o & 127) ^ ((cc & 7) << 4)) >> 1;
      unsigned w[4] = {vv[k].x, vv[k].y, vv[k].z, vv[k].w};
#pragma unroll
      for (int q = 0; q < 4; q++) {
        atomicAdd(&agg[(size_t)dsts[be + 2*q]   * DIM + col], bf2f((ushort)(w[q] & 0xffffu)));
        atomicAdd(&agg[(size_t)dsts[be + 2*q+1] * DIM + col], bf2f((ushort)(w[q] >> 16)));
      }
    }
    return;
  }

  f4v z4 = {0.f,0.f,0.f,0.f};
  f4v p[2][2];
  p[0][0] = z4; p[0][1] = z4; p[1][0] = z4; p[1][1] = z4;
#pragma unroll
  for (int ks = 0; ks < 2; ks++) {
    int k0 = ks * 32 + l4 * 8;
    bf8v a0, a1;
#pragma unroll
    for (int e2 = 0; e2 < 8; e2++) {
      int sg = segidL[k0 + e2];
      a0[e2] = (sg == l15)      ? (short)0x3F80 : (short)0;
      a1[e2] = (sg == l15 + 16) ? (short)0x3F80 : (short)0;
    }
#pragma unroll
    for (int c2 = 0; c2 < 2; c2++) {
      int cc = (wv * 2 + c2) * 16 + l15;
      bf8v bm = *(const bf8v*)(smM + ((cc * 128 + k0 * 2) ^ ((cc & 7) << 4)));
      p[0][c2] = __builtin_amdgcn_mfma_f32_16x16x32_bf16(a0, bm, p[0][c2], 0, 0, 0);
      p[1][c2] = __builtin_amdgcn_mfma_f32_16x16x32_bf16(a1, bm, p[1][c2], 0, 0, 0);
    }
  }
#pragma unroll
  for (int rt = 0; rt < 2; rt++)
#pragma unroll
  for (int c2 = 0; c2 < 2; c2++)
#pragma unroll
  for (int e = 0; e < 4; e++) {
    int seg = rt * 16 + l4 * 4 + e;
    int col = col0 + (wv * 2 + c2) * 16 + l15;
    if (seg < nseg && col < DIM) {
      float v = p[rt][c2][e];
      float* ptr = agg + (size_t)seg_dstL[seg] * DIM + col;
      if (seg == 0 || seg == nseg - 1) atomicAdd(ptr, v);
      else *ptr = v;
    }
  }
}

// ---------------- segment softmax ----------------
__global__ void k_alpha(const int* __restrict__ row_ptr, const float* __restrict__ logitsP,
                        float* __restrict__ alpha)
{
  int i = blockIdx.x * 256 + threadIdx.x;
  if (i >= NN * NHEAD) return;
  int d = i >> 2, h = i & 3;
  int beg = row_ptr[d], end = row_ptr[d+1];
  if (beg == end) return;
  float m = -1e30f;
  for (int j = beg; j < end; j++) {
    float L = logitsP[((size_t)j*NHEAD + h)*2] + logitsP[((size_t)j*NHEAD + h)*2 + 1];
    m = fmaxf(m, L);
  }
  float s = 0.f;
  for (int j = beg; j < end; j++) {
    float L = logitsP[((size_t)j*NHEAD + h)*2] + logitsP[((size_t)j*NHEAD + h)*2 + 1];
    float ex = __expf(L - m);
    alpha[(size_t)j*NHEAD + h] = ex;
    s += ex;
  }
  float inv = 1.f / (s + 1e-9f);
  for (int j = beg; j < end; j++) alpha[(size_t)j*NHEAD + h] *= inv;
}

// ---------------- x init ----------------
__global__ void k_init_x(const int* __restrict__ z, const float* __restrict__ emb,
                         float* __restrict__ x)
{
  int i = blockIdx.x * 256 + threadIdx.x;
  if (i >= NN * DIM) return;
  int n = i / DIM, c = i - n * DIM;
  x[i] = emb[(size_t)z[n]*DIM + c];
}

// ---------------- final scatter ----------------
__global__ void k_scatter(const float* __restrict__ h, const int* __restrict__ batch,
                          float* __restrict__ out)
{
  int i = blockIdx.x * 256 + threadIdx.x;
  if (i >= NN * NS) return;
  int n = i >> 7;
  atomicAdd(&out[(size_t)batch[n]*NS + (i & 127)], h[i] * 0.23570226039551584f);
}

extern "C" void kernel_launch(void* const* d_in, const int* in_sizes, int n_in,
                              void* d_out, int out_size, void* d_ws, size_t ws_size,
                              hipStream_t stream)
{
  const int*   z        = (const int*)  d_in[0];
  const float* pos      = (const float*)d_in[1];
  const int*   batch    = (const int*)  d_in[2];
  const int*   esrc     = (const int*)  d_in[3];
  const int*   edst     = (const int*)  d_in[4];
  const float* atom_emb = (const float*)d_in[5];
  const float* W_deg_sh = (const float*)d_in[6];
  const float* deg_w1   = (const float*)d_in[7];
  const float* deg_w2   = (const float*)d_in[8];
  const float* deg_w3   = (const float*)d_in[9];
  const float* Wv       = (const float*)d_in[10];
  const float* Wsh      = (const float*)d_in[11];
  const float* rad_w1   = (const float*)d_in[12];
  const float* rad_w2   = (const float*)d_in[13];
  const float* rad_w3   = (const float*)d_in[14];
  const float* attn_a   = (const float*)d_in[15];
  const float* Wo       = (const float*)d_in[16];
  const float* ffn_w1   = (const float*)d_in[17];
  const float* ffn_w2   = (const float*)d_in[18];
  const float* head_w1  = (const float*)d_in[19];
  const float* head_w2  = (const float*)d_in[20];
  float* out = (float*)d_out;

  float* x      = (float*)d_ws;
  float* statsb = x      + (size_t)NN * DIM;
  float* agg    = statsb + (size_t)NN * 2;
  float* distp  = agg    + (size_t)NN * DIM;
  float* logitsP= distp  + (size_t)NE;
  float* alphab = logitsP+ (size_t)NE * NHEAD * 2;
  __hip_bfloat16* yb    = (__hip_bfloat16*)(alphab + (size_t)NE * NHEAD);
  __hip_bfloat16* h2b   = yb + (size_t)NN * DIM;
  __hip_bfloat16* shb16 = h2b + (size_t)NE * FCH;
  __hip_bfloat16* w3Tb  = shb16 + (size_t)NE * 16;
  __hip_bfloat16* wshTb = w3Tb + (size_t)7 * 512 * 64;   // [7][512][32]
  __hip_bfloat16* bigWT = wshTb + (size_t)7 * 512 * 32;
  int* cnt      = (int*)(bigWT + (size_t)24*512*480 + 2*128*128);
  int* row_ptr  = cnt + NN;
  int* csr      = row_ptr + NN + 1;
  int* cursor   = csr + NE;
  int* esrcp    = cursor + NN;
  int* edstp    = esrcp + NE;
  __hip_bfloat16* msgb = (__hip_bfloat16*)(edstp + NE);  // [10000][8192] (16KB tiles)
  float* tmp = logitsP;

  size_t needed = (size_t)((char*)msgb + (size_t)10000 * 16384 - (char*)d_ws);
  bool fast = ws_size >= needed;

  dim3 b256(256);
  k_zero_int<<<(NN+255)/256, b256, 0, stream>>>(cnt, NN);
  k_count<<<(NE+255)/256, b256, 0, stream>>>(edst, cnt);
  k_scan<<<1, 1024, 0, stream>>>(cnt, row_ptr);
  k_zero_int<<<(NN+255)/256, b256, 0, stream>>>(cursor, NN);
  k_fill<<<(NE+255)/256, b256, 0, stream>>>(edst, row_ptr, cursor, csr);
  k_geom_p<<<(NE+255)/256, b256, 0, stream>>>(pos, esrc, edst, csr, shb16, distp, esrcp, edstp);
  k_prep<<<(7*512*64 + 7*512*32 + 255)/256, b256, 0, stream>>>(deg_w3, rad_w3, W_deg_sh, Wsh,
      w3Tb, wshTb);
  k_prepw<<<(24*512*480 + 2*128*128 + 255)/256, b256, 0, stream>>>(Wv, Wo, ffn_w1, ffn_w2,
      head_w1, head_w2, bigWT);
  hipMemsetAsync(logitsP, 0, (size_t)NE * NHEAD * 2 * sizeof(float), stream);

  // degree embedding
  k_radial<<<NE/64, b256, 0, stream>>>(distp, deg_w1, deg_w2, h2b);
  k_init_x<<<(NN*DIM+255)/256, b256, 0, stream>>>(z, atom_emb, x);
  k_msgm<2,0><<<10000, b256, 0, stream>>>(h2b, shb16, esrcp, edstp, w3Tb, wshTb,
      nullptr, nullptr, nullptr, x, nullptr, nullptr);

  dim3 gemm_grid(157, 4);
  dim3 head_grid(157, 1);
  for (int l = 0; l < NL; l++) {
    const float* w1_l  = rad_w1 + (size_t)l*NBASIS*FCH;
    const float* w2_l  = rad_w2 + (size_t)l*FCH*FCH;
    const float* aa_l  = attn_a + (size_t)l*NHEAD*HDIM;
    const __hip_bfloat16* w3T_l  = w3Tb  + (size_t)(l+1)*512*64;
    const __hip_bfloat16* wshT_l = wshTb + (size_t)(l+1)*512*32;
    const __hip_bfloat16* WvT_l = bigWT + (size_t)(0+l)*512*480;
    const __hip_bfloat16* WoT_l = bigWT + (size_t)(6+l)*512*480;
    const __hip_bfloat16* F1T_l = bigWT + (size_t)(12+l)*512*480;
    const __hip_bfloat16* F2T_l = bigWT + (size_t)(18+l)*512*480;

    k_stats<<<(NN+3)/4, b256, 0, stream>>>(x, statsb, NN, DIM, DIM);
    k_gemmm<0,0,1,1><<<gemm_grid, b256, 0, stream>>>(x, WvT_l, nullptr, yb, statsb,
        NN, DIM, DIM, DIM);
    k_radial<<<NE/64, b256, 0, stream>>>(distp, w1_l, w2_l, h2b);
    if (fast) {
      k_msgm<0,1><<<10000, b256, 0, stream>>>(h2b, shb16, esrcp, edstp, w3T_l, wshT_l,
          aa_l, yb, nullptr, nullptr, logitsP, msgb);
      k_alpha<<<(NN*NHEAD+255)/256, b256, 0, stream>>>(row_ptr, logitsP, alphab);
      hipMemsetAsync(agg, 0, (size_t)NN * DIM * sizeof(float), stream);
      k_aggm<<<10000, b256, 0, stream>>>(msgb, edstp, alphab, agg);
    } else {
      k_msgm<0,0><<<10000, b256, 0, stream>>>(h2b, shb16, esrcp, edstp, w3T_l, wshT_l,
          aa_l, yb, nullptr, nullptr, logitsP, nullptr);
      k_alpha<<<(NN*NHEAD+255)/256, b256, 0, stream>>>(row_ptr, logitsP, alphab);
      hipMemsetAsync(agg, 0, (size_t)NN * DIM * sizeof(float), stream);
      k_msgm<1,0><<<10000, b256, 0, stream>>>(h2b, shb16, esrcp, edstp, w3T_l, wshT_l,
          nullptr, yb, alphab, agg, nullptr, nullptr);
    }
    k_gemmm<1,0,0,0><<<gemm_grid, b256, 0, stream>>>(agg, WoT_l, x, nullptr, nullptr,
        NN, DIM, DIM, DIM);
    k_stats<<<(NN+3)/4, b256, 0, stream>>>(x, statsb, NN, DIM, DIM);
    k_gemmm<0,1,1,0><<<gemm_grid, b256, 0, stream>>>(x, F1T_l, agg, nullptr, statsb,
        NN, DIM, DIM, DIM);
    k_gemmm<1,0,0,0><<<gemm_grid, b256, 0, stream>>>(agg, F2T_l, x, nullptr, nullptr,
        NN, DIM, DIM, DIM);
  }

  // output head
  const __hip_bfloat16* H1T = bigWT + (size_t)24*512*480;
  const __hip_bfloat16* H2T = H1T + 128*128;
  k_stats<<<(NN+3)/4, b256, 0, stream>>>(x, statsb, NN, NS, DIM);
  k_gemmm<0,1,1,0><<<head_grid, b256, 0, stream>>>(x, H1T, agg, nullptr, statsb,
      NN, NS, NS, DIM);
  k_gemmm<0,0,0,0><<<head_grid, b256, 0, stream>>>(agg, H2T, tmp, nullptr, nullptr,
      NN, NS, NS, NS);
  hipMemsetAsync(d_out, 0, (size_t)NG * NS * sizeof(float), stream);
  k_scatter<<<(NN*NS+255)/256, b256, 0, stream>>>(tmp, batch, out);
}

// Round 17
// 2377.336 us; speedup vs baseline: 2.0601x; 1.0812x over previous
//
#include <hip/hip_runtime.h>
#include <hip/hip_bf16.h>
#include <math.h>

#define NN 10000
#define NE 160000
#define DIM 480
#define NSH 9
#define NBASIS 128
#define NHEAD 4
#define HDIM 120
#define NL 6
#define NG 256
#define NS 128
#define FCH 64
#define CUTOFF 5.0f
#define NEB 2500   // edge blocks (64 edges each)

typedef __attribute__((ext_vector_type(8))) short bf8v;
typedef __attribute__((ext_vector_type(4))) float f4v;

__device__ __forceinline__ float silu_f(float v) { return v / (1.0f + __expf(-v)); }
__device__ __forceinline__ float bf2f(ushort u) { return __uint_as_float(((unsigned)u) << 16); }
__device__ __forceinline__ ushort f2bfu(float f) {
  __hip_bfloat16 h = __float2bfloat16(f);
  return *reinterpret_cast<ushort*>(&h);
}

__device__ __forceinline__ void nt_store16(char* dst, uint4 v) {
  unsigned* p = (unsigned*)dst;
  __builtin_nontemporal_store(v.x, p + 0);
  __builtin_nontemporal_store(v.y, p + 1);
  __builtin_nontemporal_store(v.z, p + 2);
  __builtin_nontemporal_store(v.w, p + 3);
}
__device__ __forceinline__ uint4 nt_load16(const char* src) {
  const unsigned* p = (const unsigned*)src;
  uint4 v;
  v.x = __builtin_nontemporal_load(p + 0);
  v.y = __builtin_nontemporal_load(p + 1);
  v.z = __builtin_nontemporal_load(p + 2);
  v.w = __builtin_nontemporal_load(p + 3);
  return v;
}

struct bf16x4 { __hip_bfloat16 v[4]; };

// ---------------- CSR build ----------------
__global__ void k_zero_int(int* p, int n)
{
  int i = blockIdx.x * 256 + threadIdx.x;
  if (i < n) p[i] = 0;
}

__global__ void k_count(const int* __restrict__ edst, int* __restrict__ cnt)
{
  int e = blockIdx.x * 256 + threadIdx.x;
  if (e < NE) atomicAdd(&cnt[edst[e]], 1);
}

__global__ __launch_bounds__(1024)
void k_scan(const int* __restrict__ cnt, int* __restrict__ row_ptr)
{
  __shared__ int part[1024];
  int tid = threadIdx.x;
  const int per = 10;
  int base = tid * per;
  int s = 0;
  for (int i = 0; i < per; i++) { int idx = base + i; if (idx < NN) s += cnt[idx]; }
  part[tid] = s; __syncthreads();
  for (int off = 1; off < 1024; off <<= 1) {
    int v = (tid >= off) ? part[tid - off] : 0;
    __syncthreads();
    part[tid] += v;
    __syncthreads();
  }
  int run = (tid > 0) ? part[tid - 1] : 0;
  for (int i = 0; i < per; i++) {
    int idx = base + i;
    if (idx < NN) { row_ptr[idx] = run; run += cnt[idx]; }
  }
  if (tid == 1023) row_ptr[NN] = part[1023];
}

__global__ void k_fill(const int* __restrict__ edst, const int* __restrict__ row_ptr,
                       int* __restrict__ cursor, int* __restrict__ csr)
{
  int e = blockIdx.x * 256 + threadIdx.x;
  if (e >= NE) return;
  int d = edst[e];
  int p = atomicAdd(&cursor[d], 1);
  csr[row_ptr[d] + p] = e;
}

// ---------------- geometry in permuted (CSR) order; sh as bf16 [NE][16] padded ----
__global__ void k_geom_p(const float* __restrict__ pos, const int* __restrict__ esrc,
                         const int* __restrict__ edst, const int* __restrict__ csr,
                         __hip_bfloat16* __restrict__ shb, float* __restrict__ distp,
                         int* __restrict__ esrcp, int* __restrict__ edstp)
{
  int j = blockIdx.x * 256 + threadIdx.x;
  if (j >= NE) return;
  int e = csr[j];
  int s = esrc[e], d = edst[e];
  esrcp[j] = s;
  edstp[j] = d;
  float vx = pos[s*3+0] - pos[d*3+0];
  float vy = pos[s*3+1] - pos[d*3+1];
  float vz = pos[s*3+2] - pos[d*3+2];
  float r = sqrtf(vx*vx + vy*vy + vz*vz);
  distp[j] = r;
  float inv = 1.0f / (r + 1e-9f);
  float x = vx*inv, y = vy*inv, z = vz*inv;
  const float s3 = 1.7320508075688772f;
  const float s15 = 3.872983346207417f;
  const float s5 = 2.23606797749979f;
  float sv[9];
  sv[0] = 1.0f;
  sv[1] = s3*x; sv[2] = s3*y; sv[3] = s3*z;
  sv[4] = s15*x*y; sv[5] = s15*y*z; sv[6] = 0.5f*s5*(3.0f*z*z - 1.0f);
  sv[7] = s15*x*z; sv[8] = 0.5f*s15*(x*x - y*y);
  __hip_bfloat16* o = shb + (size_t)j * 16;
#pragma unroll
  for (int q = 0; q < 9; q++) o[q] = __float2bfloat16(sv[q]);
#pragma unroll
  for (int q = 9; q < 16; q++) o[q] = __float2bfloat16(0.f);
}

// ---------------- prep: w3T [7][512][64] + wshT [7][512][32] bf16 ----------------
__global__ void k_prep(const float* __restrict__ deg_w3, const float* __restrict__ rad_w3,
                       const float* __restrict__ W_deg_sh, const float* __restrict__ Wsh,
                       __hip_bfloat16* __restrict__ w3T, __hip_bfloat16* __restrict__ wshT)
{
  int i = blockIdx.x * 256 + threadIdx.x;
  if (i < 7*512*64) {
    int l = i / (512*64); int r = i - l*512*64; int col = r >> 6; int k = r & 63;
    float v = 0.f;
    if (col < DIM) {
      const float* src = (l == 0) ? deg_w3 : rad_w3 + (size_t)(l-1)*FCH*DIM;
      v = src[k*DIM + col];
    }
    w3T[i] = __float2bfloat16(v);
  }
  int j = i - 7*512*64;
  if (j >= 0 && j < 7*512*32) {
    int l = j / (512*32); int r = j - l*512*32; int col = r >> 5; int q = r & 31;
    float v = 0.f;
    if (col < DIM && q < 9) {
      const float* src = (l == 0) ? W_deg_sh : Wsh + (size_t)(l-1)*NSH*DIM;
      v = src[q*DIM + col];
    }
    wshT[j] = __float2bfloat16(v);
  }
}

// ---------------- prep: node-GEMM weights transposed bf16 ----------------
__global__ void k_prepw(const float* __restrict__ Wv, const float* __restrict__ Wo,
                        const float* __restrict__ f1, const float* __restrict__ f2,
                        const float* __restrict__ h1, const float* __restrict__ h2w,
                        __hip_bfloat16* __restrict__ WT)
{
  int i = blockIdx.x * 256 + threadIdx.x;
  const int big = 24*512*480;
  if (i < big) {
    int m = i / (512*480); int r = i - m*(512*480); int col = r / 480; int k = r - col*480;
    int l = m % 6; int t = m / 6;
    const float* src = (t==0 ? Wv : t==1 ? Wo : t==2 ? f1 : f2) + (size_t)l*DIM*DIM;
    float v = (col < DIM) ? src[k*DIM + col] : 0.f;
    WT[i] = __float2bfloat16(v);
  } else if (i < big + 2*128*128) {
    int j = i - big; int m = j / (128*128); int r = j - m*(128*128);
    int col = r >> 7; int k = r & 127;
    const float* src = m ? h2w : h1;
    WT[i] = __float2bfloat16(src[k*128 + col]);
  }
}

// ---------------- radial MLP -> h2 bf16 [E,64] ----------------
__global__ __launch_bounds__(256)
void k_radial(const float* __restrict__ dist, const float* __restrict__ w1,
              const float* __restrict__ w2, __hip_bfloat16* __restrict__ h2out)
{
  __shared__ float rbs[NBASIS][65];
  __shared__ float wsm[NBASIS * FCH];
  __shared__ float ds[64];
  int tid = threadIdx.x;
  int e0 = blockIdx.x * 64;
  if (tid < 64) ds[tid] = dist[e0 + tid];
  for (int i = tid; i < NBASIS * FCH; i += 256) wsm[i] = w1[i];
  __syncthreads();
  const float invw = (float)NBASIS / CUTOFF;
  for (int i = tid; i < NBASIS * 64; i += 256) {
    int k = i >> 6, e = i & 63;
    float c = k * (CUTOFF / 127.0f);
    float tt = (ds[e] - c) * invw;
    rbs[k][e] = __expf(-0.5f * tt * tt);
  }
  __syncthreads();
  int ty = tid >> 4, tx = tid & 15;
  float acc1[4][4] = {};
  for (int k = 0; k < NBASIS; k++) {
    float b[4];
#pragma unroll
    for (int j = 0; j < 4; j++) b[j] = wsm[k*FCH + tx*4 + j];
#pragma unroll
    for (int i = 0; i < 4; i++) {
      float a = rbs[k][ty*4 + i];
#pragma unroll
      for (int j = 0; j < 4; j++) acc1[i][j] = fmaf(a, b[j], acc1[i][j]);
    }
  }
  __syncthreads();
#pragma unroll
  for (int i = 0; i < 4; i++)
#pragma unroll
    for (int j = 0; j < 4; j++)
      rbs[tx*4 + j][ty*4 + i] = silu_f(acc1[i][j]);
  for (int i = tid; i < FCH * FCH; i += 256) wsm[i] = w2[i];
  __syncthreads();
  float acc2[4][4] = {};
  for (int k = 0; k < FCH; k++) {
    float b[4];
#pragma unroll
    for (int j = 0; j < 4; j++) b[j] = wsm[k*FCH + tx*4 + j];
#pragma unroll
    for (int i = 0; i < 4; i++) {
      float a = rbs[k][ty*4 + i];
#pragma unroll
      for (int j = 0; j < 4; j++) acc2[i][j] = fmaf(a, b[j], acc2[i][j]);
    }
  }
#pragma unroll
  for (int i = 0; i < 4; i++) {
    int e = e0 + ty*4 + i;
    bf16x4 p;
#pragma unroll
    for (int j = 0; j < 4; j++) p.v[j] = __float2bfloat16(silu_f(acc2[i][j]));
    *(bf16x4*)(h2out + (size_t)e*FCH + tx*4) = p;
  }
}

// ---------------- per-row LN stats (mu, rstd) ----------------
__global__ __launch_bounds__(256)
void k_stats(const float* __restrict__ in, float* __restrict__ st,
             int n, int cols, int stride)
{
  int row = blockIdx.x * 4 + (threadIdx.x >> 6);
  int lane = threadIdx.x & 63;
  if (row >= n) return;
  const float* r = in + (size_t)row * stride;
  float s = 0.f, ss = 0.f;
  for (int c = lane; c < cols; c += 64) { float v = r[c]; s += v; ss += v*v; }
  for (int off = 32; off > 0; off >>= 1) { s += __shfl_down(s, off); ss += __shfl_down(ss, off); }
  if (lane == 0) {
    float mu = s / cols;
    float var = ss / cols - mu * mu;
    st[row*2]   = mu;
    st[row*2+1] = rsqrtf(fmaxf(var, 0.f) + 1e-5f);
  }
}

// ---------------- MFMA node GEMM: 64 rows x 128 cols per block ----------------
template<int ADD, int SILU, int LNA, int OBF16>
__global__ __launch_bounds__(256)
void k_gemmm(const float* __restrict__ A, const __hip_bfloat16* __restrict__ BT,
             float* __restrict__ C, __hip_bfloat16* __restrict__ Cb,
             const float* __restrict__ st, int M, int K, int Nc, int lda)
{
  __shared__ __align__(16) char smA[4096];   // [64][32] bf16, XOR-swizzled
  __shared__ __align__(16) char smB[8192];   // [128][32] bf16
  __shared__ float smu[64], srs[64];
  int tid = threadIdx.x;
  int lane = tid & 63;
  int wv = tid >> 6;
  int l15 = lane & 15, l4 = lane >> 4;
  int row0 = blockIdx.x * 64;
  int col0 = blockIdx.y * 128;
  if (LNA && tid < 64) {
    int gr = row0 + tid;
    float m2 = 0.f, r2 = 1.f;
    if (gr < M) { m2 = st[gr*2]; r2 = st[gr*2+1]; }
    smu[tid] = m2; srs[tid] = r2;
  }
  f4v z4 = {0.f,0.f,0.f,0.f};
  f4v acc[8];
#pragma unroll
  for (int ct = 0; ct < 8; ct++) acc[ct] = z4;

  int arow = tid >> 2, aq = tid & 3;
  int bcol = tid >> 1, bh = tid & 1;
  for (int k0 = 0; k0 < K; k0 += 32) {
    __syncthreads();
    {
      int grow = row0 + arow;
      float f[8];
      if (grow < M) {
        const float* ap = A + (size_t)grow * lda + k0 + aq*8;
        float4 v0 = *(const float4*)ap;
        float4 v1 = *(const float4*)(ap + 4);
        f[0]=v0.x; f[1]=v0.y; f[2]=v0.z; f[3]=v0.w;
        f[4]=v1.x; f[5]=v1.y; f[6]=v1.z; f[7]=v1.w;
      } else {
#pragma unroll
        for (int q = 0; q < 8; q++) f[q] = 0.f;
      }
      if (LNA) {
        float mu = smu[arow], rs = srs[arow];
#pragma unroll
        for (int q = 0; q < 8; q++) f[q] = (f[q] - mu) * rs;
      }
      unsigned u[4];
#pragma unroll
      for (int q = 0; q < 4; q++)
        u[q] = (unsigned)f2bfu(f[2*q]) | ((unsigned)f2bfu(f[2*q+1]) << 16);
      int base = arow*64 + aq*16;
      *(uint4*)(smA + (base ^ ((arow&7)<<4))) = make_uint4(u[0],u[1],u[2],u[3]);
    }
    {
      const ushort* bp = (const ushort*)BT + (size_t)(col0 + bcol) * K + k0 + bh*16;
      uint4 v0 = *(const uint4*)bp;
      uint4 v1 = *(const uint4*)(bp + 8);
      int base = bcol*64 + bh*32;
      *(uint4*)(smB + (base ^ ((bcol&7)<<4))) = v0;
      *(uint4*)(smB + ((base+16) ^ ((bcol&7)<<4))) = v1;
    }
    __syncthreads();
    int r0 = wv*16 + l15;
    bf8v a0 = *(const bf8v*)(smA + ((r0*64 + l4*16) ^ ((r0&7)<<4)));
#pragma unroll
    for (int ct = 0; ct < 8; ct++) {
      int cc = ct*16 + l15;
      bf8v b = *(const bf8v*)(smB + ((cc*64 + l4*16) ^ ((cc&7)<<4)));
      acc[ct] = __builtin_amdgcn_mfma_f32_16x16x32_bf16(a0, b, acc[ct], 0, 0, 0);
    }
  }
#pragma unroll
  for (int ct = 0; ct < 8; ct++)
#pragma unroll
  for (int e = 0; e < 4; e++) {
    int row = row0 + wv*16 + l4*4 + e;
    int col = col0 + ct*16 + l15;
    if (row < M && col < Nc) {
      float v = acc[ct][e];
      if (SILU) v = silu_f(v);
      if (OBF16) Cb[(size_t)row * Nc + col] = __float2bfloat16(v);
      else {
        float* p = C + (size_t)row * Nc + col;
        if (ADD) *p += v; else *p = v;
      }
    }
  }
}

// ---------------- MFMA msg kernel, col-fused: 64 edges x ALL 480 cols per block ----
// Grid NEB=2500 (bijective XCD swizzle). Stages h2/sh/indices ONCE, loops 4 col
// chunks (unrolled; w3/wsh restaged per chunk; sm_w3 doubles as MT buffer).
// MODE 0: exact logits per row (register accum, no partials/memset);
//         STOREM=1 dumps swizzled M^T tile (16KB) per chunk via NT stores.
// MODE 1: alpha-weighted segment-sum -> agg (slow-path). MODE 2: (1/16) -> x.
template<int MODE, int STOREM>
__global__ __launch_bounds__(256)
void k_msgm(const __hip_bfloat16* __restrict__ h2, const __hip_bfloat16* __restrict__ shb,
            const int* __restrict__ esrcp, const int* __restrict__ edstp,
            const __hip_bfloat16* __restrict__ w3T, const __hip_bfloat16* __restrict__ wshT,
            const float* __restrict__ aa, const __hip_bfloat16* __restrict__ y,
            const float* __restrict__ alpha, float* __restrict__ outbuf,
            float* __restrict__ logits, __hip_bfloat16* __restrict__ msgb)
{
  __shared__ __align__(16) char sm_h2[8192];   // [64][64] bf16 swz (persistent)
  __shared__ __align__(16) char sm_w3[16384];  // chunk w3 [128][64]; reused as MT
  __shared__ __align__(16) char sm_sh[4096];   // [64][32] bf16 swz (persistent)
  __shared__ __align__(16) char sm_wsh[8192];  // chunk wshT [128][32]
  __shared__ int srcs[(MODE<=1)?64:1];
  __shared__ int dsts[(MODE>=1)?64:1];
  __shared__ int segidL[(MODE>=1)?64:1];
  __shared__ int seg_dstL[(MODE>=1)?32:1];

  int bid = blockIdx.x;
  int xcd = bid & 7;
  const int qq = NEB >> 3, rr = NEB & 7;         // 312, 4
  int basee = (xcd < rr) ? xcd * (qq + 1) : rr * (qq + 1) + (xcd - rr) * qq;
  int eblk = basee + (bid >> 3);                 // bijective
  int e0 = eblk * 64;

  int tid = threadIdx.x;
  int lane = tid & 63;
  int wv = tid >> 6;
  int l15 = lane & 15, l4 = lane >> 4;
  int wrow0 = wv * 16;

  for (int c = tid; c < 512; c += 256) {         // h2: 64 rows x 128B
    int r = c >> 3, s = c & 7;
    uint4 v = *(const uint4*)((const char*)h2 + (size_t)(e0 + r) * 128 + s * 16);
    *(uint4*)(sm_h2 + ((r * 128 + s * 16) ^ ((r & 7) << 4))) = v;
  }
  {                                              // sh: 64 rows x 64B (q>=2 zero)
    int r = tid >> 2, q = tid & 3;
    uint4 v = make_uint4(0u, 0u, 0u, 0u);
    if (q < 2)
      v = *(const uint4*)((const ushort*)shb + (size_t)(e0 + r) * 16 + q * 8);
    *(uint4*)(sm_sh + ((r * 64 + q * 16) ^ ((r & 7) << 4))) = v;
  }
  if (tid < 64) {
    if (MODE <= 1) srcs[tid] = esrcp[e0 + tid];
    if (MODE >= 1) dsts[tid] = edstp[e0 + tid];
  }
  __syncthreads();

  // single-wave ballot segment scan (once per block)
  int nseg = 0;
  if (MODE >= 1) {
    if (tid < 64) {
      bool flag = (tid == 0) || (dsts[tid] != dsts[tid - 1]);
      unsigned long long m = __ballot(flag ? 1 : 0);
      unsigned long long below = m & (~0ull >> (63 - tid));
      int sg = __popcll(below) - 1;
      segidL[tid] = sg;
      if (flag && sg < 32) seg_dstL[sg] = dsts[tid];
    }
    __syncthreads();
    nseg = segidL[63] + 1;
  }

  int srcs4[4];
  float4 al4[4];
#pragma unroll
  for (int e = 0; e < 4; e++) {
    int rl = wrow0 + l4 * 4 + e;
    if (MODE <= 1) srcs4[e] = srcs[rl];
    if (MODE == 1) al4[e] = *(const float4*)(alpha + (size_t)(e0 + rl) * 4);
  }

  const ushort* yus = (const ushort*)y;
  f4v z4 = {0.f, 0.f, 0.f, 0.f};
  float lacc[4][4];
  if (MODE == 0) {
#pragma unroll
    for (int e = 0; e < 4; e++)
#pragma unroll
      for (int h = 0; h < 4; h++) lacc[e][h] = 0.f;
  }

#pragma unroll
  for (int ci = 0; ci < 4; ci++) {
    int col0 = ci * 128;
    __syncthreads();                              // prior chunk consumers done
    for (int c = tid; c < 1024; c += 256) {       // w3T chunk: 128 cols x 128B
      int r = c >> 3, s = c & 7;
      uint4 v = *(const uint4*)((const char*)w3T + (size_t)(col0 + r) * 128 + s * 16);
      *(uint4*)(sm_w3 + ((r * 128 + s * 16) ^ ((r & 7) << 4))) = v;
    }
    for (int c = tid; c < 512; c += 256) {        // wshT chunk: 128 cols x 64B
      int r = c >> 2, q = c & 3;
      uint4 v = *(const uint4*)((const ushort*)wshT + (size_t)(col0 + r) * 32 + q * 8);
      *(uint4*)(sm_wsh + ((r * 64 + q * 16) ^ ((r & 7) << 4))) = v;
    }
    __syncthreads();

    f4v g[8];
#pragma unroll
    for (int ct = 0; ct < 8; ct++) g[ct] = z4;

    // GEMM1: gate = h2 @ w3 (chunk)
#pragma unroll
    for (int ks = 0; ks < 2; ks++) {
      int k0b = (ks * 32 + l4 * 8) * 2;
      int r0 = wrow0 + l15;
      bf8v a0 = *(const bf8v*)(sm_h2 + ((r0 * 128 + k0b) ^ ((r0 & 7) << 4)));
#pragma unroll
      for (int ct = 0; ct < 8; ct++) {
        int cc = ct * 16 + l15;
        bf8v b = *(const bf8v*)(sm_w3 + ((cc * 128 + k0b) ^ ((cc & 7) << 4)));
        g[ct] = __builtin_amdgcn_mfma_f32_16x16x32_bf16(a0, b, g[ct], 0, 0, 0);
      }
    }

    // epilogue: m = y * (sh@wsh via MFMA) * gate (+ alpha / scale)
    {
      int r0 = wrow0 + l15;
      bf8v shA = *(const bf8v*)(sm_sh + ((r0 * 64 + l4 * 16) ^ ((r0 & 7) << 4)));
#pragma unroll
      for (int ct = 0; ct < 8; ct++) {
        int cc = ct * 16 + l15;
        int col = col0 + cc;
        bf8v wB = *(const bf8v*)(sm_wsh + ((cc * 64 + l4 * 16) ^ ((cc & 7) << 4)));
        f4v sw4 = __builtin_amdgcn_mfma_f32_16x16x32_bf16(shA, wB, z4, 0, 0, 0);
#pragma unroll
        for (int e = 0; e < 4; e++) {
          float yv;
          if (MODE == 2) yv = 1.f;
          else yv = (col < DIM) ? bf2f(yus[(size_t)srcs4[e] * DIM + col]) : 0.f;
          float mv = yv * sw4[e] * g[ct][e];
          if (MODE == 1) {
            float av = (col < 120) ? al4[e].x : (col < 240) ? al4[e].y
                     : (col < 360) ? al4[e].z : al4[e].w;
            mv *= av;
          }
          if (MODE == 2) mv *= (1.0f / 16.0f);
          g[ct][e] = mv;
        }
      }
    }

    if (MODE == 0) {
      // logits accumulation: chunk ci covers head ci (+ head ci+1 spill)
      float aav[8];
#pragma unroll
      for (int ct = 0; ct < 8; ct++) {
        int col = col0 + ct * 16 + l15;
        aav[ct] = (col < DIM) ? aa[col] : 0.f;
      }
#pragma unroll
      for (int e = 0; e < 4; e++) {
        float sA = 0.f, sB = 0.f;
#pragma unroll
        for (int ct = 0; ct < 8; ct++) {
          int col = col0 + ct * 16 + l15;
          float mv = g[ct][e];
          float lv = (mv > 0.f) ? mv : 0.2f * mv;
          float c = lv * aav[ct];
          if (col / 120 == ci) sA += c; else sB += c;
        }
#pragma unroll
        for (int off = 1; off < 16; off <<= 1) {
          sA += __shfl_xor(sA, off, 16);
          sB += __shfl_xor(sB, off, 16);
        }
        lacc[e][ci] += sA;
        if (ci < 3) lacc[e][ci + 1] += sB;
      }
      if (STOREM) {
        __syncthreads();                          // GEMM1 reads of sm_w3 done
#pragma unroll
        for (int ct = 0; ct < 8; ct++) {
          int cc = ct * 16 + l15;
          int ebase = wrow0 + l4 * 4;
          ushort4 pk;
          pk.x = f2bfu(g[ct][0]); pk.y = f2bfu(g[ct][1]);
          pk.z = f2bfu(g[ct][2]); pk.w = f2bfu(g[ct][3]);
          *(ushort4*)(sm_w3 + ((cc * 128 + ebase * 2) ^ ((cc & 7) << 4))) = pk;
        }
        __syncthreads();
        char* gdst = (char*)msgb + (size_t)(eblk * 4 + ci) * 16384;
#pragma unroll
        for (int k = 0; k < 4; k++) {
          int o = tid * 16 + k * 4096;
          uint4 v = *(const uint4*)(sm_w3 + o);
          nt_store16(gdst + o, v);
        }
      }
    } else if (nseg > 32) {                       // rare fallback
#pragma unroll
      for (int e = 0; e < 4; e++) {
        int rl = wrow0 + l4 * 4 + e;
        int dd = dsts[rl];
#pragma unroll
        for (int ct = 0; ct < 8; ct++) {
          int col = col0 + ct * 16 + l15;
          if (col < DIM) atomicAdd(&outbuf[(size_t)dd * DIM + col], g[ct][e]);
        }
      }
    } else {
      // write M^T then GEMM3 segment-sum (per chunk)
      __syncthreads();
#pragma unroll
      for (int ct = 0; ct < 8; ct++) {
        int cc = ct * 16 + l15;
        int ebase = wrow0 + l4 * 4;
        ushort4 pk;
        pk.x = f2bfu(g[ct][0]); pk.y = f2bfu(g[ct][1]);
        pk.z = f2bfu(g[ct][2]); pk.w = f2bfu(g[ct][3]);
        *(ushort4*)(sm_w3 + ((cc * 128 + ebase * 2) ^ ((cc & 7) << 4))) = pk;
      }
      __syncthreads();
      f4v p[2][2];
      p[0][0] = z4; p[0][1] = z4; p[1][0] = z4; p[1][1] = z4;
#pragma unroll
      for (int ks = 0; ks < 2; ks++) {
        int k0 = ks * 32 + l4 * 8;
        bf8v a0, a1;
#pragma unroll
        for (int e2 = 0; e2 < 8; e2++) {
          int sg = segidL[k0 + e2];
          a0[e2] = (sg == l15)      ? (short)0x3F80 : (short)0;
          a1[e2] = (sg == l15 + 16) ? (short)0x3F80 : (short)0;
        }
#pragma unroll
        for (int c2 = 0; c2 < 2; c2++) {
          int cc = (wv * 2 + c2) * 16 + l15;
          bf8v bm = *(const bf8v*)(sm_w3 + ((cc * 128 + k0 * 2) ^ ((cc & 7) << 4)));
          p[0][c2] = __builtin_amdgcn_mfma_f32_16x16x32_bf16(a0, bm, p[0][c2], 0, 0, 0);
          p[1][c2] = __builtin_amdgcn_mfma_f32_16x16x32_bf16(a1, bm, p[1][c2], 0, 0, 0);
        }
      }
#pragma unroll
      for (int rt = 0; rt < 2; rt++)
#pragma unroll
      for (int c2 = 0; c2 < 2; c2++)
#pragma unroll
      for (int e = 0; e < 4; e++) {
        int seg = rt * 16 + l4 * 4 + e;
        int col = col0 + (wv * 2 + c2) * 16 + l15;
        if (seg < nseg && col < DIM) {
          float v = p[rt][c2][e];
          float* ptr = outbuf + (size_t)seg_dstL[seg] * DIM + col;
          if (seg == 0 || seg == nseg - 1) atomicAdd(ptr, v);
          else if (MODE == 1) *ptr = v;
          else *ptr += v;
        }
      }
    }
  }

  if (MODE == 0) {
#pragma unroll
    for (int e = 0; e < 4; e++) {
      int row = e0 + wrow0 + l4 * 4 + e;
      if (l15 == 0) {
        logits[(size_t)row * 4 + 0] = lacc[e][0];
        logits[(size_t)row * 4 + 1] = lacc[e][1];
        logits[(size_t)row * 4 + 2] = lacc[e][2];
        logits[(size_t)row * 4 + 3] = lacc[e][3];
      }
    }
  }
}

// ---------------- pass B (fast path): read msgb tile (non-temporal), alpha-weight,
// segment-sum via S^T @ M MFMA ----
__global__ __launch_bounds__(256)
void k_aggm(const __hip_bfloat16* __restrict__ msgb, const int* __restrict__ edstp,
            const float* __restrict__ alpha, float* __restrict__ agg)
{
  __shared__ __align__(16) char smM[16384];
  __shared__ __align__(16) float alsq[64][4];
  __shared__ int dsts[64];
  __shared__ int segidL[64];
  __shared__ int seg_dstL[32];

  int bid = blockIdx.x;
  int swzb = (bid & 7) * 1250 + (bid >> 3);
  int e0   = (swzb >> 2) * 64;
  int col0 = (swzb & 3) * 128;
  int tid = threadIdx.x;
  int lane = tid & 63;
  int wv = tid >> 6;
  int l15 = lane & 15, l4 = lane >> 4;

  if (tid < 64) {
    dsts[tid] = edstp[e0 + tid];
    *(float4*)&alsq[tid][0] = *(const float4*)(alpha + (size_t)(e0 + tid) * 4);
  }
  __syncthreads();

  int nseg = 0;
  if (tid < 64) {
    bool flag = (tid == 0) || (dsts[tid] != dsts[tid - 1]);
    unsigned long long m = __ballot(flag ? 1 : 0);
    unsigned long long below = m & (~0ull >> (63 - tid));
    int sg = __popcll(below) - 1;
    segidL[tid] = sg;
    if (flag && sg < 32) seg_dstL[sg] = dsts[tid];
  }
  __syncthreads();
  nseg = segidL[63] + 1;

  const char* gsrc = (const char*)msgb + (size_t)swzb * 16384;
  uint4 vv[4];
#pragma unroll
  for (int k = 0; k < 4; k++) {
    int o = tid * 16 + k * 4096;
    uint4 v = nt_load16(gsrc + o);
    int cc = o >> 7;
    int col = col0 + cc;
    int h = (col < DIM) ? (col / 120) : 3;
    int be = ((o & 127) ^ ((cc & 7) << 4)) >> 1;
    unsigned w[4] = {v.x, v.y, v.z, v.w};
#pragma unroll
    for (int q = 0; q < 4; q++) {
      float lo = bf2f((ushort)(w[q] & 0xffffu)) * alsq[be + 2*q][h];
      float hi = bf2f((ushort)(w[q] >> 16))     * alsq[be + 2*q + 1][h];
      w[q] = (unsigned)f2bfu(lo) | ((unsigned)f2bfu(hi) << 16);
    }
    vv[k] = make_uint4(w[0], w[1], w[2], w[3]);
    *(uint4*)(smM + o) = vv[k];
  }
  __syncthreads();

  if (nseg > 32) {
#pragma unroll
    for (int k = 0; k < 4; k++) {
      int o = tid * 16 + k * 4096;
      int cc = o >> 7;
      int col = col0 + cc;
      if (col >= DIM) continue;
      int be = ((o & 127) ^ ((cc & 7) << 4)) >> 1;
      unsigned w[4] = {vv[k].x, vv[k].y, vv[k].z, vv[k].w};
#pragma unroll
      for (int q = 0; q < 4; q++) {
        atomicAdd(&agg[(size_t)dsts[be + 2*q]   * DIM + col], bf2f((ushort)(w[q] & 0xffffu)));
        atomicAdd(&agg[(size_t)dsts[be + 2*q+1] * DIM + col], bf2f((ushort)(w[q] >> 16)));
      }
    }
    return;
  }

  f4v z4 = {0.f,0.f,0.f,0.f};
  f4v p[2][2];
  p[0][0] = z4; p[0][1] = z4; p[1][0] = z4; p[1][1] = z4;
#pragma unroll
  for (int ks = 0; ks < 2; ks++) {
    int k0 = ks * 32 + l4 * 8;
    bf8v a0, a1;
#pragma unroll
    for (int e2 = 0; e2 < 8; e2++) {
      int sg = segidL[k0 + e2];
      a0[e2] = (sg == l15)      ? (short)0x3F80 : (short)0;
      a1[e2] = (sg == l15 + 16) ? (short)0x3F80 : (short)0;
    }
#pragma unroll
    for (int c2 = 0; c2 < 2; c2++) {
      int cc = (wv * 2 + c2) * 16 + l15;
      bf8v bm = *(const bf8v*)(smM + ((cc * 128 + k0 * 2) ^ ((cc & 7) << 4)));
      p[0][c2] = __builtin_amdgcn_mfma_f32_16x16x32_bf16(a0, bm, p[0][c2], 0, 0, 0);
      p[1][c2] = __builtin_amdgcn_mfma_f32_16x16x32_bf16(a1, bm, p[1][c2], 0, 0, 0);
    }
  }
#pragma unroll
  for (int rt = 0; rt < 2; rt++)
#pragma unroll
  for (int c2 = 0; c2 < 2; c2++)
#pragma unroll
  for (int e = 0; e < 4; e++) {
    int seg = rt * 16 + l4 * 4 + e;
    int col = col0 + (wv * 2 + c2) * 16 + l15;
    if (seg < nseg && col < DIM) {
      float v = p[rt][c2][e];
      float* ptr = agg + (size_t)seg_dstL[seg] * DIM + col;
      if (seg == 0 || seg == nseg - 1) atomicAdd(ptr, v);
      else *ptr = v;
    }
  }
}

// ---------------- segment softmax (single-slot logits) ----------------
__global__ void k_alpha(const int* __restrict__ row_ptr, const float* __restrict__ logits,
                        float* __restrict__ alpha)
{
  int i = blockIdx.x * 256 + threadIdx.x;
  if (i >= NN * NHEAD) return;
  int d = i >> 2, h = i & 3;
  int beg = row_ptr[d], end = row_ptr[d+1];
  if (beg == end) return;
  float m = -1e30f;
  for (int j = beg; j < end; j++) m = fmaxf(m, logits[(size_t)j*NHEAD + h]);
  float s = 0.f;
  for (int j = beg; j < end; j++) {
    float ex = __expf(logits[(size_t)j*NHEAD + h] - m);
    alpha[(size_t)j*NHEAD + h] = ex;
    s += ex;
  }
  float inv = 1.f / (s + 1e-9f);
  for (int j = beg; j < end; j++) alpha[(size_t)j*NHEAD + h] *= inv;
}

// ---------------- x init ----------------
__global__ void k_init_x(const int* __restrict__ z, const float* __restrict__ emb,
                         float* __restrict__ x)
{
  int i = blockIdx.x * 256 + threadIdx.x;
  if (i >= NN * DIM) return;
  int n = i / DIM, c = i - n * DIM;
  x[i] = emb[(size_t)z[n]*DIM + c];
}

// ---------------- final scatter ----------------
__global__ void k_scatter(const float* __restrict__ h, const int* __restrict__ batch,
                          float* __restrict__ out)
{
  int i = blockIdx.x * 256 + threadIdx.x;
  if (i >= NN * NS) return;
  int n = i >> 7;
  atomicAdd(&out[(size_t)batch[n]*NS + (i & 127)], h[i] * 0.23570226039551584f);
}

extern "C" void kernel_launch(void* const* d_in, const int* in_sizes, int n_in,
                              void* d_out, int out_size, void* d_ws, size_t ws_size,
                              hipStream_t stream)
{
  const int*   z        = (const int*)  d_in[0];
  const float* pos      = (const float*)d_in[1];
  const int*   batch    = (const int*)  d_in[2];
  const int*   esrc     = (const int*)  d_in[3];
  const int*   edst     = (const int*)  d_in[4];
  const float* atom_emb = (const float*)d_in[5];
  const float* W_deg_sh = (const float*)d_in[6];
  const float* deg_w1   = (const float*)d_in[7];
  const float* deg_w2   = (const float*)d_in[8];
  const float* deg_w3   = (const float*)d_in[9];
  const float* Wv       = (const float*)d_in[10];
  const float* Wsh      = (const float*)d_in[11];
  const float* rad_w1   = (const float*)d_in[12];
  const float* rad_w2   = (const float*)d_in[13];
  const float* rad_w3   = (const float*)d_in[14];
  const float* attn_a   = (const float*)d_in[15];
  const float* Wo       = (const float*)d_in[16];
  const float* ffn_w1   = (const float*)d_in[17];
  const float* ffn_w2   = (const float*)d_in[18];
  const float* head_w1  = (const float*)d_in[19];
  const float* head_w2  = (const float*)d_in[20];
  float* out = (float*)d_out;

  float* x      = (float*)d_ws;
  float* statsb = x      + (size_t)NN * DIM;
  float* agg    = statsb + (size_t)NN * 2;
  float* distp  = agg    + (size_t)NN * DIM;
  float* logitsb= distp  + (size_t)NE;                // [NE][4] used; NE*8 reserved (tmp overlay)
  float* alphab = logitsb+ (size_t)NE * NHEAD * 2;
  __hip_bfloat16* yb    = (__hip_bfloat16*)(alphab + (size_t)NE * NHEAD);
  __hip_bfloat16* h2b   = yb + (size_t)NN * DIM;
  __hip_bfloat16* shb16 = h2b + (size_t)NE * FCH;
  __hip_bfloat16* w3Tb  = shb16 + (size_t)NE * 16;
  __hip_bfloat16* wshTb = w3Tb + (size_t)7 * 512 * 64;
  __hip_bfloat16* bigWT = wshTb + (size_t)7 * 512 * 32;
  int* cnt      = (int*)(bigWT + (size_t)24*512*480 + 2*128*128);
  int* row_ptr  = cnt + NN;
  int* csr      = row_ptr + NN + 1;
  int* cursor   = csr + NE;
  int* esrcp    = cursor + NN;
  int* edstp    = esrcp + NE;
  __hip_bfloat16* msgb = (__hip_bfloat16*)(edstp + NE);  // [10000][8192] (16KB tiles)
  float* tmp = logitsb;

  size_t needed = (size_t)((char*)msgb + (size_t)10000 * 16384 - (char*)d_ws);
  bool fast = ws_size >= needed;

  dim3 b256(256);
  k_zero_int<<<(NN+255)/256, b256, 0, stream>>>(cnt, NN);
  k_count<<<(NE+255)/256, b256, 0, stream>>>(edst, cnt);
  k_scan<<<1, 1024, 0, stream>>>(cnt, row_ptr);
  k_zero_int<<<(NN+255)/256, b256, 0, stream>>>(cursor, NN);
  k_fill<<<(NE+255)/256, b256, 0, stream>>>(edst, row_ptr, cursor, csr);
  k_geom_p<<<(NE+255)/256, b256, 0, stream>>>(pos, esrc, edst, csr, shb16, distp, esrcp, edstp);
  k_prep<<<(7*512*64 + 7*512*32 + 255)/256, b256, 0, stream>>>(deg_w3, rad_w3, W_deg_sh, Wsh,
      w3Tb, wshTb);
  k_prepw<<<(24*512*480 + 2*128*128 + 255)/256, b256, 0, stream>>>(Wv, Wo, ffn_w1, ffn_w2,
      head_w1, head_w2, bigWT);

  // degree embedding
  k_radial<<<NE/64, b256, 0, stream>>>(distp, deg_w1, deg_w2, h2b);
  k_init_x<<<(NN*DIM+255)/256, b256, 0, stream>>>(z, atom_emb, x);
  k_msgm<2,0><<<NEB, b256, 0, stream>>>(h2b, shb16, esrcp, edstp, w3Tb, wshTb,
      nullptr, nullptr, nullptr, x, nullptr, nullptr);

  dim3 gemm_grid(157, 4);
  dim3 head_grid(157, 1);
  for (int l = 0; l < NL; l++) {
    const float* w1_l  = rad_w1 + (size_t)l*NBASIS*FCH;
    const float* w2_l  = rad_w2 + (size_t)l*FCH*FCH;
    const float* aa_l  = attn_a + (size_t)l*NHEAD*HDIM;
    const __hip_bfloat16* w3T_l  = w3Tb  + (size_t)(l+1)*512*64;
    const __hip_bfloat16* wshT_l = wshTb + (size_t)(l+1)*512*32;
    const __hip_bfloat16* WvT_l = bigWT + (size_t)(0+l)*512*480;
    const __hip_bfloat16* WoT_l = bigWT + (size_t)(6+l)*512*480;
    const __hip_bfloat16* F1T_l = bigWT + (size_t)(12+l)*512*480;
    const __hip_bfloat16* F2T_l = bigWT + (size_t)(18+l)*512*480;

    k_stats<<<(NN+3)/4, b256, 0, stream>>>(x, statsb, NN, DIM, DIM);
    k_gemmm<0,0,1,1><<<gemm_grid, b256, 0, stream>>>(x, WvT_l, nullptr, yb, statsb,
        NN, DIM, DIM, DIM);
    k_radial<<<NE/64, b256, 0, stream>>>(distp, w1_l, w2_l, h2b);
    if (fast) {
      k_msgm<0,1><<<NEB, b256, 0, stream>>>(h2b, shb16, esrcp, edstp, w3T_l, wshT_l,
          aa_l, yb, nullptr, nullptr, logitsb, msgb);
      k_alpha<<<(NN*NHEAD+255)/256, b256, 0, stream>>>(row_ptr, logitsb, alphab);
      hipMemsetAsync(agg, 0, (size_t)NN * DIM * sizeof(float), stream);
      k_aggm<<<10000, b256, 0, stream>>>(msgb, edstp, alphab, agg);
    } else {
      k_msgm<0,0><<<NEB, b256, 0, stream>>>(h2b, shb16, esrcp, edstp, w3T_l, wshT_l,
          aa_l, yb, nullptr, nullptr, logitsb, nullptr);
      k_alpha<<<(NN*NHEAD+255)/256, b256, 0, stream>>>(row_ptr, logitsb, alphab);
      hipMemsetAsync(agg, 0, (size_t)NN * DIM * sizeof(float), stream);
      k_msgm<1,0><<<NEB, b256, 0, stream>>>(h2b, shb16, esrcp, edstp, w3T_l, wshT_l,
          nullptr, yb, alphab, agg, nullptr, nullptr);
    }
    k_gemmm<1,0,0,0><<<gemm_grid, b256, 0, stream>>>(agg, WoT_l, x, nullptr, nullptr,
        NN, DIM, DIM, DIM);
    k_stats<<<(NN+3)/4, b256, 0, stream>>>(x, statsb, NN, DIM, DIM);
    k_gemmm<0,1,1,0><<<gemm_grid, b256, 0, stream>>>(x, F1T_l, agg, nullptr, statsb,
        NN, DIM, DIM, DIM);
    k_gemmm<1,0,0,0><<<gemm_grid, b256, 0, stream>>>(agg, F2T_l, x, nullptr, nullptr,
        NN, DIM, DIM, DIM);
  }

  // output head
  const __hip_bfloat16* H1T = bigWT + (size_t)24*512*480;
  const __hip_bfloat16* H2T = H1T + 128*128;
  k_stats<<<(NN+3)/4, b256, 0, stream>>>(x, statsb, NN, NS, DIM);
  k_gemmm<0,1,1,0><<<head_grid, b256, 0, stream>>>(x, H1T, agg, nullptr, statsb,
      NN, NS, NS, DIM);
  k_gemmm<0,0,0,0><<<head_grid, b256, 0, stream>>>(agg, H2T, tmp, nullptr, nullptr,
      NN, NS, NS, NS);
  hipMemsetAsync(d_out, 0, (size_t)NG * NS * sizeof(float), stream);
  k_scatter<<<(NN*NS+255)/256, b256, 0, stream>>>(tmp, batch, out);
}